// Round 4
// baseline (378.110 us; speedup 1.0000x reference)
//
#include <hip/hip_runtime.h>
#include <math.h>

#define D   1024
#define H   16
#define HD  64
#define SEQ 2048
#define LL  8
#define SCALE 0.125f

typedef __attribute__((ext_vector_type(8))) __bf16 bf16x8;
typedef __attribute__((ext_vector_type(4))) float floatx4;
typedef __attribute__((ext_vector_type(8))) unsigned short ushort8;

__device__ inline unsigned short f32_to_bf16(float f) {
    unsigned int u = __builtin_bit_cast(unsigned int, f);
    u += 0x7FFF + ((u >> 16) & 1);   // round-to-nearest-even
    return (unsigned short)(u >> 16);
}
__device__ inline float bf2f(unsigned short u) {
    unsigned int x = (unsigned int)u << 16;
    return __builtin_bit_cast(float, x);
}
__device__ inline void load_lds16(const void* g, void* l) {
    __builtin_amdgcn_global_load_lds(
        (__attribute__((address_space(1))) void*)g,
        (__attribute__((address_space(3))) void*)l, 16, 0, 0);
}

// XCD-aware swizzle: contiguous grid chunk per XCD -> A-panel L2 reuse.
__device__ inline void xcd_swizzle(int& bx, int& by) {
    const int gx   = gridDim.x;
    const int lin  = blockIdx.y * gx + blockIdx.x;
    const int nblk = gx * gridDim.y;
    const int virt = (lin & 7) * (nblk >> 3) + (lin >> 3);
    bx = virt % gx;
    by = virt / gx;
}

// ---------------------------------------------------------------------------
// prep: LN(reproject(pv)) -> ri_bf  |  f32->bf16 of x, Wqkv|Wcol (->W4), Wout
//       |  bias concat b4 = [bqkv, bcol]
// ---------------------------------------------------------------------------
#define NQ_X    524288
#define NQ_WQKV 786432
#define NQ_WC   262144
#define NQ_WO   262144
#define LN_BLK  16384
#define CVT_BLK 7168          // (NQ_X+NQ_WQKV+NQ_WC+NQ_WO)/256
#define PREP_GRID (LN_BLK + CVT_BLK + 4)

__global__ __launch_bounds__(256) void prep_kernel(
    const float* __restrict__ pv, const float* __restrict__ x,
    const float* __restrict__ Wqkv, const float* __restrict__ Wcol,
    const float* __restrict__ Wout, const float* __restrict__ bqkv,
    const float* __restrict__ bcol,
    unsigned short* __restrict__ ri, unsigned short* __restrict__ xb,
    unsigned short* __restrict__ W4b, unsigned short* __restrict__ Woutb,
    float* __restrict__ b4)
{
    const int b = blockIdx.x;
    const int t = threadIdx.x;
    if (b < LN_BLK) {
        // LayerNorm row r = s*L + l over d=1024
        const int r = b;
        const int s = r >> 3, l = r & 7;
        const int h = t >> 4, e = (t & 15) * 4;
        const size_t src = (size_t)l * (H * SEQ * HD) + (size_t)h * (SEQ * HD)
                         + (size_t)s * HD + e;
        float4 v = *(const float4*)(pv + src);
        float sum = v.x + v.y + v.z + v.w;
        float sq  = v.x * v.x + v.y * v.y + v.z * v.z + v.w * v.w;
#pragma unroll
        for (int off = 32; off; off >>= 1) {
            sum += __shfl_xor(sum, off);
            sq  += __shfl_xor(sq, off);
        }
        __shared__ float red[8];
        if ((t & 63) == 0) { red[(t >> 6) * 2] = sum; red[(t >> 6) * 2 + 1] = sq; }
        __syncthreads();
        sum = red[0] + red[2] + red[4] + red[6];
        sq  = red[1] + red[3] + red[5] + red[7];
        const float mean = sum * (1.f / 1024.f);
        const float var  = sq * (1.f / 1024.f) - mean * mean;
        const float rstd = rsqrtf(var + 1e-5f);
        ushort4 o;
        o.x = f32_to_bf16((v.x - mean) * rstd);
        o.y = f32_to_bf16((v.y - mean) * rstd);
        o.z = f32_to_bf16((v.z - mean) * rstd);
        o.w = f32_to_bf16((v.w - mean) * rstd);
        *(ushort4*)(ri + (size_t)r * D + t * 4) = o;
    } else if (b < LN_BLK + CVT_BLK) {
        const int i = (b - LN_BLK) * 256 + t;
        const float* src; unsigned short* dst; int off;
        if (i < NQ_X)                        { src = x;    dst = xb;    off = i; }
        else if (i < NQ_X + NQ_WQKV)         { src = Wqkv; dst = W4b;   off = i - NQ_X; }
        else if (i < NQ_X + NQ_WQKV + NQ_WC) {
            float4 v = ((const float4*)Wcol)[i - NQ_X - NQ_WQKV];
            ushort4 o;
            o.x = f32_to_bf16(v.x); o.y = f32_to_bf16(v.y);
            o.z = f32_to_bf16(v.z); o.w = f32_to_bf16(v.w);
            ((ushort4*)(W4b))[NQ_WQKV + (i - NQ_X - NQ_WQKV)] = o;
            return;
        }
        else                                 { src = Wout; dst = Woutb; off = i - NQ_X - NQ_WQKV - NQ_WC; }
        float4 v = ((const float4*)src)[off];
        ushort4 o;
        o.x = f32_to_bf16(v.x); o.y = f32_to_bf16(v.y);
        o.z = f32_to_bf16(v.z); o.w = f32_to_bf16(v.w);
        ((ushort4*)dst)[off] = o;
    } else {
        // bias concat: 1024 float4 quads, first 768 from bqkv, rest from bcol
        const int q = (b - LN_BLK - CVT_BLK) * 256 + t;
        float4 v = (q < 768) ? ((const float4*)bqkv)[q] : ((const float4*)bcol)[q - 768];
        ((float4*)b4)[q] = v;
    }
}

// ---------------------------------------------------------------------------
// wkt: WkT[h][c][e] = Wqkv[1024 + h*64 + e][c]  (bf16). Grid 256 = 16h x 16ct.
// ---------------------------------------------------------------------------
__global__ __launch_bounds__(256) void wkt_kernel(
    const float* __restrict__ Wqkv, unsigned short* __restrict__ WkT)
{
    const int h = blockIdx.x >> 4, ct = blockIdx.x & 15;
    const int c0 = ct * 64;
    const int t = threadIdx.x;
    __shared__ float tile[64][68];
    {
        const int e  = t >> 2;            // 0..63
        const int c4 = (t & 3) * 16;      // 0,16,32,48
        const float* src = Wqkv + (size_t)(D + h * HD + e) * D + c0 + c4;
#pragma unroll
        for (int j = 0; j < 4; j++) {
            float4 v = ((const float4*)src)[j];
            *(float4*)&tile[e][c4 + j * 4] = v;
        }
    }
    __syncthreads();
    {
        const int c  = t >> 2;            // local col 0..63
        const int e0 = (t & 3) * 16;      // 0,16,32,48
        ushort8 o0, o1;
#pragma unroll
        for (int j = 0; j < 8; j++) o0[j] = f32_to_bf16(tile[e0 + j][c]);
#pragma unroll
        for (int j = 0; j < 8; j++) o1[j] = f32_to_bf16(tile[e0 + 8 + j][c]);
        unsigned short* dst = WkT + (size_t)h * (D * HD) + (size_t)(c0 + c) * HD + e0;
        *(ushort8*)dst       = o0;
        *(ushort8*)(dst + 8) = o1;
    }
}

// ---------------------------------------------------------------------------
// vtr: VT[h][e][key] = V[key][h*64+e]  (global transpose of the V quarter of
// qkv4). Grid 128 = 16h x 8 key-chunks of 256. LDS-tiled, coalesced both ways.
// ---------------------------------------------------------------------------
__global__ __launch_bounds__(256) void vtr_kernel(
    const unsigned short* __restrict__ qkv4, unsigned short* __restrict__ VT)
{
    const int h = blockIdx.x & 15, kt = blockIdx.x >> 4;
    const int t = threadIdx.x;
    __shared__ unsigned short Vt[64][264];
    const int pr = t & 31, eg = t >> 5;   // key-pair 0..31, e-octet 0..7
#pragma unroll
    for (int sub = 0; sub < 4; sub++) {
        const int j0 = kt * 256 + sub * 64;
        const unsigned short* v0 = qkv4 + (size_t)(j0 + 2 * pr) * 4096 + 2 * D + h * HD + eg * 8;
        ushort8 va = *(const ushort8*)v0;
        ushort8 vb = *(const ushort8*)(v0 + 4096);
#pragma unroll
        for (int j = 0; j < 8; j++) {
            unsigned int pk = (unsigned int)va[j] | ((unsigned int)vb[j] << 16);
            *(unsigned int*)&Vt[eg * 8 + j][sub * 64 + 2 * pr] = pk;
        }
    }
    __syncthreads();
#pragma unroll
    for (int it = 0; it < 8; it++) {
        const int idx = it * 256 + t;
        const int e = idx >> 5, ch = idx & 31;
        ushort8 v = *(const ushort8*)&Vt[e][ch * 8];
        *(ushort8*)(VT + (size_t)h * (HD * SEQ) + (size_t)e * SEQ + kt * 256 + ch * 8) = v;
    }
}

// ---------------------------------------------------------------------------
// bf16 MFMA GEMM: C[M,N] = A[M,K] @ W[N,K]^T (+ bias[N]). CT = float or ushort.
// 128x128 tile, BK=32, 4 waves, 4x4 16x16x32 MFMAs per wave. XCD-swizzled.
// Generalized: lda/ldw/ldc row strides, blockIdx.z batching via element strides.
// ---------------------------------------------------------------------------
template <typename CT, bool HAS_BIAS>
__global__ __launch_bounds__(256) void gemm_bf16_kernel(
    const unsigned short* __restrict__ A, const unsigned short* __restrict__ W,
    const float* __restrict__ bias, CT* __restrict__ C,
    int K, int N, int lda, int ldw, int ldc,
    size_t zsA, size_t zsW, size_t zsC)
{
    A += (size_t)blockIdx.z * zsA;
    W += (size_t)blockIdx.z * zsW;
    C += (size_t)blockIdx.z * zsC;

    __shared__ unsigned short As[128 * 32];
    __shared__ unsigned short Ws[128 * 32];
    const int t    = threadIdx.x;
    const int wave = t >> 6, lane = t & 63;
    const int wm   = wave >> 1, wn = wave & 1;
    int bx, by;
    xcd_swizzle(bx, by);
    const int m0 = by * 128, n0 = bx * 128;

    floatx4 acc[4][4];
#pragma unroll
    for (int i = 0; i < 4; i++)
#pragma unroll
        for (int j = 0; j < 4; j++) acc[i][j] = (floatx4)0.f;

    const int lrow = lane >> 2;
    const int lcol = (lane & 3) * 8;
    const unsigned short* Ag = A + (size_t)(m0 + wave * 32 + lrow) * lda + lcol;
    const unsigned short* Wg = W + (size_t)(n0 + wave * 32 + lrow) * ldw + lcol;
    unsigned short* Asw = &As[wave * 32 * 32];
    unsigned short* Wsw = &Ws[wave * 32 * 32];
    const size_t rowskipA = (size_t)16 * lda;
    const size_t rowskipW = (size_t)16 * ldw;

    const int arow  = lane & 15;
    const int aquad = (lane >> 4) * 8;

    for (int k0 = 0; k0 < K; k0 += 32) {
        load_lds16(Ag + k0,             Asw);
        load_lds16(Ag + k0 + rowskipA,  Asw + 16 * 32);
        load_lds16(Wg + k0,             Wsw);
        load_lds16(Wg + k0 + rowskipW,  Wsw + 16 * 32);
        __syncthreads();

        bf16x8 af[4], wf[4];
#pragma unroll
        for (int mi = 0; mi < 4; mi++)
            af[mi] = *(const bf16x8*)&As[(wm * 64 + mi * 16 + arow) * 32 + aquad];
#pragma unroll
        for (int ni = 0; ni < 4; ni++)
            wf[ni] = *(const bf16x8*)&Ws[(wn * 64 + ni * 16 + arow) * 32 + aquad];
#pragma unroll
        for (int mi = 0; mi < 4; mi++)
#pragma unroll
            for (int ni = 0; ni < 4; ni++)
                acc[mi][ni] = __builtin_amdgcn_mfma_f32_16x16x32_bf16(
                    af[mi], wf[ni], acc[mi][ni], 0, 0, 0);
        __syncthreads();
    }

    const int crow = (lane >> 4) * 4, ccol = lane & 15;
#pragma unroll
    for (int mi = 0; mi < 4; mi++) {
#pragma unroll
        for (int ni = 0; ni < 4; ni++) {
            const int gm = m0 + wm * 64 + mi * 16 + crow;
            const int gn = n0 + wn * 64 + ni * 16 + ccol;
            float bb = 0.f;
            if constexpr (HAS_BIAS) bb = bias[gn];
#pragma unroll
            for (int r = 0; r < 4; r++) {
                float v = acc[mi][ni][r] + bb;
                if constexpr (sizeof(CT) == 2)
                    C[(size_t)(gm + r) * ldc + gn] = (CT)f32_to_bf16(v);
                else
                    C[(size_t)(gm + r) * ldc + gn] = v;
            }
        }
    }
}

// ---------------------------------------------------------------------------
// memsc: mem_scores[s,h,l] = ( U[h,s,:].ri[s,l,:] + qcol[s,h,:].bk[h,:] )*SCALE
// grid = 2048 (one block per s).
// ---------------------------------------------------------------------------
#define RI_STRIDE 1032    // padded ushort row stride: spreads l over banks

__global__ __launch_bounds__(256) void memsc_kernel(
    const unsigned short* __restrict__ U, const unsigned short* __restrict__ ri,
    const unsigned short* __restrict__ qkv4, const float* __restrict__ bqkv,
    float* __restrict__ scores)
{
    const int s = blockIdx.x;
    const int t = threadIdx.x;
    __shared__ unsigned short riS[LL * RI_STRIDE];
    __shared__ float qbS[H];
    // stage ri[s] : 8 rows x 1024
    {
        const unsigned short* src = ri + (size_t)s * (LL * D);
#pragma unroll
        for (int j = 0; j < 4; j++) {
            const int off = (j * 256 + t) * 8;        // 0..8191
            const int l = off >> 10, c = off & 1023;
            ushort8 v = *(const ushort8*)(src + off);
            *(ushort8*)&riS[l * RI_STRIDE + c] = v;
        }
    }
    // qb[h] = qcol[s,h,:] . bk[h,:]
    {
        const int h = t >> 4, sub = t & 15;
        const unsigned short* qc = qkv4 + (size_t)s * 4096 + 3 * D + h * HD + sub * 4;
        const float* bk = bqkv + D + h * HD + sub * 4;
        float acc = 0.f;
#pragma unroll
        for (int j = 0; j < 4; j++) acc += bf2f(qc[j]) * bk[j];
#pragma unroll
        for (int off = 1; off < 16; off <<= 1) acc += __shfl_xor(acc, off);
        if (sub == 0) qbS[h] = acc;
    }
    __syncthreads();
    // 128 (h,l) pairs x 2 half-threads each, 512-wide dot per thread
    const int p = t >> 1, half = t & 1;
    const int h = p >> 3, l = p & 7;
    const unsigned short* Up = U + ((size_t)h * SEQ + s) * D + half * 512;
    const unsigned short* rp = &riS[l * RI_STRIDE + half * 512];
    float acc = 0.f;
#pragma unroll 4
    for (int j = 0; j < 64; j++) {
        ushort8 u = *(const ushort8*)(Up + j * 8);
        ushort8 r = *(const ushort8*)(rp + j * 8);
#pragma unroll
        for (int k = 0; k < 8; k++) acc += bf2f(u[k]) * bf2f(r[k]);
    }
    acc += __shfl_xor(acc, 1);
    if (half == 0)
        scores[((size_t)s * H + h) * LL + l] = (acc + qbS[h]) * SCALE;
}

// ---------------------------------------------------------------------------
// Barrier-free split-K MFMA flash attention (token keys only), 4-way split.
// Per-wave independence: Q pre-scaled in regs; K frags direct global->reg;
// V frags direct from the pre-transposed VT; P round-trip through a wave-
// local LDS slice (no __syncthreads anywhere). LPT: qt = 31 - (lin>>6).
// XCD affinity: inner block order s*16+h puts heads {h, h+8} on one XCD
// (1 MB K+VT working set -> L2-resident).
// Mem-key fold moved entirely to the merge kernel.
// ---------------------------------------------------------------------------
__global__ __launch_bounds__(256, 4) void attn_split_kernel(
    const unsigned short* __restrict__ qkv4, const unsigned short* __restrict__ VT,
    float* __restrict__ Opart, float2* __restrict__ mlpart)
{
    const int t    = threadIdx.x;
    const int w    = t >> 6, lane = t & 63;
    const int lrow = lane & 15;
    const int lk   = (lane >> 4) * 8;
    const int rrow = (lane >> 4) * 4;
    const int lin  = blockIdx.x;
    const int hsp  = lin & 63, g = lin >> 6;
    const int s    = hsp >> 4, h = hsp & 15;
    const int qt   = 31 - g;               // LPT: longest first
    const int q0   = qt * 64;
    const int n    = qt + 1;
    const int lo   = (s * n) >> 2, hi = ((s + 1) * n) >> 2;
    const int part = (h * 32 + qt) * 4 + s;

    __shared__ unsigned short Pb[4][16 * 72];   // per-wave P slice (wave-local)
    unsigned short* Pw = Pb[w];

    // Q fragments in registers, pre-scaled by 1/8 (exact pow-2 in bf16)
    bf16x8 qreg[2];
#pragma unroll
    for (int kst = 0; kst < 2; kst++) {
        ushort8 qu = *(const ushort8*)(qkv4 + (size_t)(q0 + w * 16 + lrow) * 4096
                                       + h * HD + kst * 32 + lk);
        ushort8 qs;
#pragma unroll
        for (int j = 0; j < 8; j++) qs[j] = f32_to_bf16(bf2f(qu[j]) * SCALE);
        qreg[kst] = __builtin_bit_cast(bf16x8, qs);
    }

    const unsigned short* Kbase = qkv4 + D + h * HD;            // + key*4096
    const unsigned short* Vbase = VT + (size_t)h * (HD * SEQ);  // + e*2048 + key

    float m_i[4], l_i[4];
    floatx4 Oacc[4];
#pragma unroll
    for (int r = 0; r < 4; r++) { m_i[r] = -1e30f; l_i[r] = 0.f; }
#pragma unroll
    for (int et = 0; et < 4; et++) Oacc[et] = (floatx4)0.f;

    for (int jt = lo; jt < hi; jt++) {
        const int j0 = jt * 64;

        // S = Q K^T  (K frags straight from global; L2-resident)
        floatx4 S[4];
#pragma unroll
        for (int nt = 0; nt < 4; nt++) S[nt] = (floatx4)0.f;
        __builtin_amdgcn_s_setprio(1);
#pragma unroll
        for (int kst = 0; kst < 2; kst++) {
#pragma unroll
            for (int nt = 0; nt < 4; nt++) {
                bf16x8 bk = *(const bf16x8*)(Kbase
                    + (size_t)(j0 + nt * 16 + lrow) * 4096 + kst * 32 + lk);
                S[nt] = __builtin_amdgcn_mfma_f32_16x16x32_bf16(qreg[kst], bk, S[nt], 0, 0, 0);
            }
        }
        __builtin_amdgcn_s_setprio(0);

        // online softmax; P -> Pw (wave-local, no barrier)
        if (jt != qt) {
            // fully-unmasked tile: no causal mask, defer-max (T13)
#pragma unroll
            for (int r = 0; r < 4; r++) {
                float sc[4];
#pragma unroll
                for (int nt = 0; nt < 4; nt++) sc[nt] = S[nt][r];
                float mx = fmaxf(fmaxf(sc[0], sc[1]), fmaxf(sc[2], sc[3]));
#pragma unroll
                for (int off = 1; off < 16; off <<= 1)
                    mx = fmaxf(mx, __shfl_xor(mx, off));
                const bool keep = __all(mx <= m_i[r] + 8.f);
                const float newm = keep ? m_i[r] : fmaxf(m_i[r], mx);
                float ps = 0.f;
#pragma unroll
                for (int nt = 0; nt < 4; nt++) {
                    float pe = __expf(sc[nt] - newm);
                    ps += pe;
                    Pw[(rrow + r) * 72 + nt * 16 + lrow] = f32_to_bf16(pe);
                }
#pragma unroll
                for (int off = 1; off < 16; off <<= 1)
                    ps += __shfl_xor(ps, off);
                if (keep) {
                    l_i[r] += ps;
                } else {
                    const float alpha = __expf(m_i[r] - newm);
                    m_i[r] = newm;
                    l_i[r] = l_i[r] * alpha + ps;
#pragma unroll
                    for (int et = 0; et < 4; et++) Oacc[et][r] *= alpha;
                }
            }
        } else {
            // diagonal tile: causal masking (every row has >=1 valid key)
#pragma unroll
            for (int r = 0; r < 4; r++) {
                const int qg = q0 + w * 16 + rrow + r;
                float sc[4];
                float mx = -1e30f;
#pragma unroll
                for (int nt = 0; nt < 4; nt++) {
                    sc[nt] = S[nt][r];
                    if (j0 + nt * 16 + lrow > qg) sc[nt] = -1e30f;
                    mx = fmaxf(mx, sc[nt]);
                }
#pragma unroll
                for (int off = 1; off < 16; off <<= 1)
                    mx = fmaxf(mx, __shfl_xor(mx, off));
                const float newm  = fmaxf(m_i[r], mx);
                const float alpha = __expf(m_i[r] - newm);
                m_i[r] = newm;
                float ps = 0.f;
#pragma unroll
                for (int nt = 0; nt < 4; nt++) {
                    float pe = __expf(sc[nt] - newm);
                    ps += pe;
                    Pw[(rrow + r) * 72 + nt * 16 + lrow] = f32_to_bf16(pe);
                }
#pragma unroll
                for (int off = 1; off < 16; off <<= 1)
                    ps += __shfl_xor(ps, off);
                l_i[r] = l_i[r] * alpha + ps;
#pragma unroll
                for (int et = 0; et < 4; et++) Oacc[et][r] *= alpha;
            }
        }

        // O += P @ V  (V frags straight from pre-transposed VT)
        __builtin_amdgcn_s_setprio(1);
#pragma unroll
        for (int kst = 0; kst < 2; kst++) {
            bf16x8 ap = *(const bf16x8*)&Pw[lrow * 72 + kst * 32 + lk];
#pragma unroll
            for (int et = 0; et < 4; et++) {
                bf16x8 bv = *(const bf16x8*)(Vbase
                    + (size_t)(et * 16 + lrow) * SEQ + j0 + kst * 32 + lk);
                Oacc[et] = __builtin_amdgcn_mfma_f32_16x16x32_bf16(ap, bv, Oacc[et], 0, 0, 0);
            }
        }
        __builtin_amdgcn_s_setprio(0);
    }

    // write partials (uniform for all splits; empty split -> m=-1e30, l=0, O=0)
#pragma unroll
    for (int r = 0; r < 4; r++) {
        const int ql = w * 16 + rrow + r;
        if (lrow == 0) mlpart[(size_t)part * 64 + ql] = make_float2(m_i[r], l_i[r]);
#pragma unroll
        for (int et = 0; et < 4; et++)
            Opart[((size_t)part * 64 + ql) * 64 + et * 16 + lrow] = Oacc[et][r];
    }
}

// ---------------------------------------------------------------------------
// merge: combine the four key-split partials per (h, qt) AND the 8 memory-key
// scores in one exact softmax; normalize. Writes token context (f32), final
// normalized mem weights mwf, and Pmem[s,h] = sum_l mwf.
// ---------------------------------------------------------------------------
__global__ __launch_bounds__(256) void attn_merge_kernel(
    const float* __restrict__ Opart, const float2* __restrict__ mlpart,
    const float* __restrict__ scores,
    float* __restrict__ tok, float* __restrict__ mwf, float* __restrict__ Pmem)
{
    const int blk = blockIdx.x;            // h*32 + qt
    const int h = blk >> 5, qt = blk & 31;
    const int q0 = qt * 64;
    const int t = threadIdx.x, tx = t & 15, ty = t >> 4;
    const size_t pb = (size_t)blk * 4;
#pragma unroll
    for (int i = 0; i < 4; i++) {
        const int qi = ty * 4 + i, qg = q0 + qi;
        float2 ml[4];
#pragma unroll
        for (int ps = 0; ps < 4; ps++) ml[ps] = mlpart[(pb + ps) * 64 + qi];
        const float* msp = scores + ((size_t)qg * H + h) * LL;
        float ms[LL];
#pragma unroll
        for (int l = 0; l < LL; l++) ms[l] = msp[l];
        float M = ml[0].x;
#pragma unroll
        for (int ps = 1; ps < 4; ps++) M = fmaxf(M, ml[ps].x);
#pragma unroll
        for (int l = 0; l < LL; l++) M = fmaxf(M, ms[l]);
        float f[4], L = 0.f;
#pragma unroll
        for (int ps = 0; ps < 4; ps++) { f[ps] = __expf(ml[ps].x - M); L += ml[ps].y * f[ps]; }
        float pm[LL];
#pragma unroll
        for (int l = 0; l < LL; l++) { pm[l] = __expf(ms[l] - M); L += pm[l]; }
        const float rl = 1.f / L;
        float4 o = make_float4(0.f, 0.f, 0.f, 0.f);
#pragma unroll
        for (int ps = 0; ps < 4; ps++) {
            const float fs = f[ps] * rl;
            float4 op = *(const float4*)&Opart[((pb + ps) * 64 + qi) * 64 + tx * 4];
            o.x += op.x * fs; o.y += op.y * fs; o.z += op.z * fs; o.w += op.w * fs;
        }
        *(float4*)&tok[(size_t)qg * D + h * HD + tx * 4] = o;
        if (tx == 0) {
            float* mw = mwf + ((size_t)qg * H + h) * LL;
            float psum = 0.f;
#pragma unroll
            for (int l = 0; l < LL; l++) { float v = pm[l] * rl; mw[l] = v; psum += v; }
            Pmem[(size_t)qg * H + h] = psum;
        }
    }
}

// ---------------------------------------------------------------------------
// rbar[h,s,:] = sum_l mwf[s,h,l] * ri[s*8+l,:]   (bf16 out). grid = 2048 (s).
// ---------------------------------------------------------------------------
__global__ __launch_bounds__(256) void rbar_kernel(
    const float* __restrict__ mwf, const unsigned short* __restrict__ ri,
    unsigned short* __restrict__ rbar)
{
    const int s = blockIdx.x, t = threadIdx.x;
    __shared__ unsigned short riS[LL * D];
    __shared__ float wS[H * LL];
    {
        const unsigned short* src = ri + (size_t)s * (LL * D);
#pragma unroll
        for (int j = 0; j < 4; j++) {
            const int off = (j * 256 + t) * 8;
            *(ushort8*)&riS[off] = *(const ushort8*)(src + off);
        }
    }
    if (t < H * LL) wS[t] = mwf[(size_t)s * (H * LL) + t];
    __syncthreads();
    const int c4 = t * 4;
#pragma unroll
    for (int hh = 0; hh < H; hh++) {
        float v0 = 0.f, v1 = 0.f, v2 = 0.f, v3 = 0.f;
#pragma unroll
        for (int l = 0; l < LL; l++) {
            const float wv = wS[hh * LL + l];
            ushort4 rr = *(const ushort4*)&riS[l * D + c4];
            v0 += wv * bf2f(rr.x); v1 += wv * bf2f(rr.y);
            v2 += wv * bf2f(rr.z); v3 += wv * bf2f(rr.w);
        }
        ushort4 o;
        o.x = f32_to_bf16(v0); o.y = f32_to_bf16(v1);
        o.z = f32_to_bf16(v2); o.w = f32_to_bf16(v3);
        *(ushort4*)(rbar + ((size_t)hh * SEQ + s) * D + c4) = o;
    }
}

// ---------------------------------------------------------------------------
// ctx GEMM: ctx[s, h*64+e] = bf16( rbar[h,s,:] . Wv[h*64+e,:]
//                                  + bv[h*64+e]*Pmem[s,h] + tok[s,h*64+e] )
// 128(M)x64(N) tile, BK=32, 4 waves (wave = m-subtile). grid = (16 mt, 16 h).
// ---------------------------------------------------------------------------
__global__ __launch_bounds__(256) void gemm_ctx_kernel(
    const unsigned short* __restrict__ rbar, const unsigned short* __restrict__ W4,
    const float* __restrict__ bqkv, const float* __restrict__ Pmem,
    const float* __restrict__ tok, unsigned short* __restrict__ ctx)
{
    const int mt = blockIdx.x;      // 0..15
    const int h  = blockIdx.y;      // 0..15
    const unsigned short* A  = rbar + (size_t)h * SEQ * D + (size_t)mt * 128 * D;
    const unsigned short* Wv = W4 + (size_t)(2 * D + h * HD) * D;   // 64 rows x 1024
    const float* bv = bqkv + 2 * D + h * HD;

    __shared__ unsigned short As[128 * 32];
    __shared__ unsigned short Ws[64 * 32];
    const int t    = threadIdx.x;
    const int wave = t >> 6, lane = t & 63;

    floatx4 acc[2][4];
#pragma unroll
    for (int i = 0; i < 2; i++)
#pragma unroll
        for (int j = 0; j < 4; j++) acc[i][j] = (floatx4)0.f;

    const int lrow = lane >> 2;
    const int lcol = (lane & 3) * 8;
    const unsigned short* Ag = A  + (size_t)(wave * 32 + lrow) * D + lcol;
    const unsigned short* Wg = Wv + (size_t)(wave * 32 + lrow) * D + lcol;  // waves 0,1 only
    unsigned short* Asw = &As[wave * 32 * 32];
    unsigned short* Wsw = &Ws[wave * 32 * 32];
    const size_t rowskip = (size_t)16 * D;

    const int arow  = lane & 15;
    const int aquad = (lane >> 4) * 8;

    for (int k0 = 0; k0 < D; k0 += 32) {
        load_lds16(Ag + k0,           Asw);
        load_lds16(Ag + k0 + rowskip, Asw + 16 * 32);
        if (wave < 2) {
            load_lds16(Wg + k0,           Wsw);
            load_lds16(Wg + k0 + rowskip, Wsw + 16 * 32);
        }
        __syncthreads();

        bf16x8 af[2], wf[4];
#pragma unroll
        for (int mi = 0; mi < 2; mi++)
            af[mi] = *(const bf16x8*)&As[(wave * 32 + mi * 16 + arow) * 32 + aquad];
#pragma unroll
        for (int ni = 0; ni < 4; ni++)
            wf[ni] = *(const bf16x8*)&Ws[(ni * 16 + arow) * 32 + aquad];
#pragma unroll
        for (int mi = 0; mi < 2; mi++)
#pragma unroll
            for (int ni = 0; ni < 4; ni++)
                acc[mi][ni] = __builtin_amdgcn_mfma_f32_16x16x32_bf16(
                    af[mi], wf[ni], acc[mi][ni], 0, 0, 0);
        __syncthreads();
    }

    const int crow = (lane >> 4) * 4, ccol = lane & 15;
#pragma unroll
    for (int mi = 0; mi < 2; mi++) {
#pragma unroll
        for (int ni = 0; ni < 4; ni++) {
            const int e  = ni * 16 + ccol;
            const float bb = bv[e];
#pragma unroll
            for (int r = 0; r < 4; r++) {
                const int grow = mt * 128 + wave * 32 + mi * 16 + crow + r;
                float v = acc[mi][ni][r] + bb * Pmem[(size_t)grow * H + h]
                          + tok[(size_t)grow * D + h * HD + e];
                ctx[(size_t)grow * D + h * HD + e] = f32_to_bf16(v);
            }
        }
    }
}

// ---------------------------------------------------------------------------
extern "C" void kernel_launch(void* const* d_in, const int* in_sizes, int n_in,
                              void* d_out, int out_size, void* d_ws, size_t ws_size,
                              hipStream_t stream)
{
    const float* x    = (const float*)d_in[0];
    const float* pv   = (const float*)d_in[1];
    const float* Wqkv = (const float*)d_in[2];
    const float* bqkv = (const float*)d_in[3];
    const float* Wcol = (const float*)d_in[4];
    const float* bcol = (const float*)d_in[5];
    const float* Wout = (const float*)d_in[6];
    const float* bout = (const float*)d_in[7];
    float* out = (float*)d_out;

    char* p = (char*)d_ws;
    unsigned short* x_bf    = (unsigned short*)p; p += (size_t)2048 * 1024 * 2;
    unsigned short* W4_bf   = (unsigned short*)p; p += (size_t)4096 * 1024 * 2;   // Wqkv | Wcol
    unsigned short* Wout_bf = (unsigned short*)p; p += (size_t)1024 * 1024 * 2;
    float*          b4      = (float*)p;          p += (size_t)4096 * 4;
    unsigned short* ri_bf   = (unsigned short*)p; p += (size_t)16384 * 1024 * 2;
    unsigned short* qkv4_bf = (unsigned short*)p; p += (size_t)2048 * 4096 * 2;   // Q|K|V|Qcol
    unsigned short* WkT_bf  = (unsigned short*)p; p += (size_t)16 * 1024 * 64 * 2;
    unsigned short* VT_bf   = (unsigned short*)p; p += (size_t)16 * 64 * 2048 * 2; // V transposed per head
    float*          scores  = (float*)p;          p += (size_t)2048 * 16 * 8 * 4;
    float*          mwf     = (float*)p;          p += (size_t)2048 * 16 * 8 * 4;
    float*          Pmem    = (float*)p;          p += (size_t)2048 * 16 * 4;
    float*          tok     = (float*)p;          p += (size_t)2048 * 1024 * 4;
    unsigned short* ctx_bf  = (unsigned short*)p; p += (size_t)2048 * 1024 * 2;
    float*          Opart   = (float*)p;          p += (size_t)2048 * 64 * 64 * 4;
    float2*         mlpart  = (float2*)p;         p += (size_t)2048 * 64 * 8;
    // U and rbar have disjoint lifetimes (U dead after memsc) -> share buffer
    unsigned short* Urb     = (unsigned short*)p; p += (size_t)16 * 2048 * 1024 * 2;
    // ~182 MB total

    // LN + all bf16 casts + bias concat
    prep_kernel<<<PREP_GRID, 256, 0, stream>>>(pv, x, Wqkv, Wcol, Wout, bqkv, bcol,
                                               ri_bf, x_bf, W4_bf, Wout_bf, b4);
    // per-head transposed Wk for the U GEMM
    wkt_kernel<<<256, 256, 0, stream>>>(Wqkv, WkT_bf);
    // qkv4 = x @ [Wqkv|Wcol]^T + [bqkv|bcol]   (fused, N=4096)
    gemm_bf16_kernel<unsigned short, true><<<dim3(32, 16, 1), 256, 0, stream>>>(
        x_bf, W4_bf, b4, qkv4_bf, 1024, 4096, 1024, 1024, 4096, 0, 0, 0);
    // global V transpose: VT[h][e][key]
    vtr_kernel<<<128, 256, 0, stream>>>(qkv4_bf, VT_bf);
    // U[h] = Qcol[h] @ Wk[h]   (K=64 head-batched; replaces the rk GEMM)
    gemm_bf16_kernel<unsigned short, false><<<dim3(8, 16, 16), 256, 0, stream>>>(
        qkv4_bf + 3 * D, WkT_bf, nullptr, Urb, 64, 1024, 4096, 64, 1024,
        (size_t)HD, (size_t)D * HD, (size_t)SEQ * D);
    // mem_scores = (U . ri + qcol.bk) * scale
    memsc_kernel<<<2048, 256, 0, stream>>>(Urb, ri_bf, qkv4_bf, bqkv, scores);
    // attention split (barrier-free, 4-way, LPT) + merge (incl. mem-key fold)
    attn_split_kernel<<<2048, 256, 0, stream>>>(qkv4_bf, VT_bf, Opart, mlpart);
    attn_merge_kernel<<<512, 256, 0, stream>>>(Opart, mlpart, scores, tok, mwf, Pmem);
    // rbar = sum_l mwf * ri   (reuses U's buffer)
    rbar_kernel<<<2048, 256, 0, stream>>>(mwf, ri_bf, Urb);
    // ctx = tok + Wv[h] @ rbar[h] + bv*Pmem   (replaces the rv GEMM + fold)
    gemm_ctx_kernel<<<dim3(16, 16), 256, 0, stream>>>(Urb, W4_bf, bqkv, Pmem, tok, ctx_bf);
    // out = ctx @ Wout^T + bout
    gemm_bf16_kernel<float, true><<<dim3(8, 16, 1), 256, 0, stream>>>(
        ctx_bf, Wout_bf, bout, out, 1024, 1024, 1024, 1024, 1024, 0, 0, 0);
}

// Round 5
// 338.404 us; speedup vs baseline: 1.1173x; 1.1173x over previous
//
#include <hip/hip_runtime.h>
#include <math.h>

#define D   1024
#define H   16
#define HD  64
#define SEQ 2048
#define LL  8
#define SCALE 0.125f

typedef __attribute__((ext_vector_type(8))) __bf16 bf16x8;
typedef __attribute__((ext_vector_type(4))) float floatx4;
typedef __attribute__((ext_vector_type(8))) unsigned short ushort8;

__device__ inline unsigned short f32_to_bf16(float f) {
    unsigned int u = __builtin_bit_cast(unsigned int, f);
    u += 0x7FFF + ((u >> 16) & 1);   // round-to-nearest-even
    return (unsigned short)(u >> 16);
}
__device__ inline float bf2f(unsigned short u) {
    unsigned int x = (unsigned int)u << 16;
    return __builtin_bit_cast(float, x);
}
__device__ inline void load_lds16(const void* g, void* l) {
    __builtin_amdgcn_global_load_lds(
        (__attribute__((address_space(1))) void*)g,
        (__attribute__((address_space(3))) void*)l, 16, 0, 0);
}

// XCD-aware swizzle: contiguous grid chunk per XCD -> A-panel L2 reuse.
__device__ inline void xcd_swizzle(int& bx, int& by) {
    const int gx   = gridDim.x;
    const int lin  = blockIdx.y * gx + blockIdx.x;
    const int nblk = gx * gridDim.y;
    const int virt = (lin & 7) * (nblk >> 3) + (lin >> 3);
    bx = virt % gx;
    by = virt / gx;
}

// ---------------------------------------------------------------------------
// prep: LN(reproject(pv)) -> ri_bf  |  f32->bf16 of x, Wqkv|Wcol (->W4), Wout
//       |  bias concat b4 = [bqkv, bcol]
// ---------------------------------------------------------------------------
#define NQ_X    524288
#define NQ_WQKV 786432
#define NQ_WC   262144
#define NQ_WO   262144
#define LN_BLK  16384
#define CVT_BLK 7168          // (NQ_X+NQ_WQKV+NQ_WC+NQ_WO)/256
#define PREP_GRID (LN_BLK + CVT_BLK + 4)

__global__ __launch_bounds__(256) void prep_kernel(
    const float* __restrict__ pv, const float* __restrict__ x,
    const float* __restrict__ Wqkv, const float* __restrict__ Wcol,
    const float* __restrict__ Wout, const float* __restrict__ bqkv,
    const float* __restrict__ bcol,
    unsigned short* __restrict__ ri, unsigned short* __restrict__ xb,
    unsigned short* __restrict__ W4b, unsigned short* __restrict__ Woutb,
    float* __restrict__ b4)
{
    const int b = blockIdx.x;
    const int t = threadIdx.x;
    if (b < LN_BLK) {
        // LayerNorm row r = s*L + l over d=1024
        const int r = b;
        const int s = r >> 3, l = r & 7;
        const int h = t >> 4, e = (t & 15) * 4;
        const size_t src = (size_t)l * (H * SEQ * HD) + (size_t)h * (SEQ * HD)
                         + (size_t)s * HD + e;
        float4 v = *(const float4*)(pv + src);
        float sum = v.x + v.y + v.z + v.w;
        float sq  = v.x * v.x + v.y * v.y + v.z * v.z + v.w * v.w;
#pragma unroll
        for (int off = 32; off; off >>= 1) {
            sum += __shfl_xor(sum, off);
            sq  += __shfl_xor(sq, off);
        }
        __shared__ float red[8];
        if ((t & 63) == 0) { red[(t >> 6) * 2] = sum; red[(t >> 6) * 2 + 1] = sq; }
        __syncthreads();
        sum = red[0] + red[2] + red[4] + red[6];
        sq  = red[1] + red[3] + red[5] + red[7];
        const float mean = sum * (1.f / 1024.f);
        const float var  = sq * (1.f / 1024.f) - mean * mean;
        const float rstd = rsqrtf(var + 1e-5f);
        ushort4 o;
        o.x = f32_to_bf16((v.x - mean) * rstd);
        o.y = f32_to_bf16((v.y - mean) * rstd);
        o.z = f32_to_bf16((v.z - mean) * rstd);
        o.w = f32_to_bf16((v.w - mean) * rstd);
        *(ushort4*)(ri + (size_t)r * D + t * 4) = o;
    } else if (b < LN_BLK + CVT_BLK) {
        const int i = (b - LN_BLK) * 256 + t;
        const float* src; unsigned short* dst; int off;
        if (i < NQ_X)                        { src = x;    dst = xb;    off = i; }
        else if (i < NQ_X + NQ_WQKV)         { src = Wqkv; dst = W4b;   off = i - NQ_X; }
        else if (i < NQ_X + NQ_WQKV + NQ_WC) {
            float4 v = ((const float4*)Wcol)[i - NQ_X - NQ_WQKV];
            ushort4 o;
            o.x = f32_to_bf16(v.x); o.y = f32_to_bf16(v.y);
            o.z = f32_to_bf16(v.z); o.w = f32_to_bf16(v.w);
            ((ushort4*)(W4b))[NQ_WQKV + (i - NQ_X - NQ_WQKV)] = o;
            return;
        }
        else                                 { src = Wout; dst = Woutb; off = i - NQ_X - NQ_WQKV - NQ_WC; }
        float4 v = ((const float4*)src)[off];
        ushort4 o;
        o.x = f32_to_bf16(v.x); o.y = f32_to_bf16(v.y);
        o.z = f32_to_bf16(v.z); o.w = f32_to_bf16(v.w);
        ((ushort4*)dst)[off] = o;
    } else {
        // bias concat: 1024 float4 quads, first 768 from bqkv, rest from bcol
        const int q = (b - LN_BLK - CVT_BLK) * 256 + t;
        float4 v = (q < 768) ? ((const float4*)bqkv)[q] : ((const float4*)bcol)[q - 768];
        ((float4*)b4)[q] = v;
    }
}

// ---------------------------------------------------------------------------
// wkt: WkT[h][c][e] = Wqkv[1024 + h*64 + e][c]  (bf16). Grid 256 = 16h x 16ct.
// ---------------------------------------------------------------------------
__global__ __launch_bounds__(256) void wkt_kernel(
    const float* __restrict__ Wqkv, unsigned short* __restrict__ WkT)
{
    const int h = blockIdx.x >> 4, ct = blockIdx.x & 15;
    const int c0 = ct * 64;
    const int t = threadIdx.x;
    __shared__ float tile[64][68];
    {
        const int e  = t >> 2;            // 0..63
        const int c4 = (t & 3) * 16;      // 0,16,32,48
        const float* src = Wqkv + (size_t)(D + h * HD + e) * D + c0 + c4;
#pragma unroll
        for (int j = 0; j < 4; j++) {
            float4 v = ((const float4*)src)[j];
            *(float4*)&tile[e][c4 + j * 4] = v;
        }
    }
    __syncthreads();
    {
        const int c  = t >> 2;            // local col 0..63
        const int e0 = (t & 3) * 16;      // 0,16,32,48
        ushort8 o0, o1;
#pragma unroll
        for (int j = 0; j < 8; j++) o0[j] = f32_to_bf16(tile[e0 + j][c]);
#pragma unroll
        for (int j = 0; j < 8; j++) o1[j] = f32_to_bf16(tile[e0 + 8 + j][c]);
        unsigned short* dst = WkT + (size_t)h * (D * HD) + (size_t)(c0 + c) * HD + e0;
        *(ushort8*)dst       = o0;
        *(ushort8*)(dst + 8) = o1;
    }
}

// ---------------------------------------------------------------------------
// vtr: VT[h][e][key] = V[key][h*64+e]  (global transpose of the V quarter of
// qkv4). Grid 128 = 16h x 8 key-chunks of 256. LDS-tiled, coalesced both ways.
// ---------------------------------------------------------------------------
__global__ __launch_bounds__(256) void vtr_kernel(
    const unsigned short* __restrict__ qkv4, unsigned short* __restrict__ VT)
{
    const int h = blockIdx.x & 15, kt = blockIdx.x >> 4;
    const int t = threadIdx.x;
    __shared__ unsigned short Vt[64][264];
    const int pr = t & 31, eg = t >> 5;   // key-pair 0..31, e-octet 0..7
#pragma unroll
    for (int sub = 0; sub < 4; sub++) {
        const int j0 = kt * 256 + sub * 64;
        const unsigned short* v0 = qkv4 + (size_t)(j0 + 2 * pr) * 4096 + 2 * D + h * HD + eg * 8;
        ushort8 va = *(const ushort8*)v0;
        ushort8 vb = *(const ushort8*)(v0 + 4096);
#pragma unroll
        for (int j = 0; j < 8; j++) {
            unsigned int pk = (unsigned int)va[j] | ((unsigned int)vb[j] << 16);
            *(unsigned int*)&Vt[eg * 8 + j][sub * 64 + 2 * pr] = pk;
        }
    }
    __syncthreads();
#pragma unroll
    for (int it = 0; it < 8; it++) {
        const int idx = it * 256 + t;
        const int e = idx >> 5, ch = idx & 31;
        ushort8 v = *(const ushort8*)&Vt[e][ch * 8];
        *(ushort8*)(VT + (size_t)h * (HD * SEQ) + (size_t)e * SEQ + kt * 256 + ch * 8) = v;
    }
}

// ---------------------------------------------------------------------------
// bf16 MFMA GEMM: C[M,N] = A[M,K] @ W[N,K]^T (+ bias[N]). CT = float or ushort.
// 128x128 tile, BK=32, 4 waves, 4x4 16x16x32 MFMAs per wave. XCD-swizzled.
// Generalized: lda/ldw/ldc row strides, blockIdx.z batching via element strides.
// ---------------------------------------------------------------------------
template <typename CT, bool HAS_BIAS>
__global__ __launch_bounds__(256) void gemm_bf16_kernel(
    const unsigned short* __restrict__ A, const unsigned short* __restrict__ W,
    const float* __restrict__ bias, CT* __restrict__ C,
    int K, int N, int lda, int ldw, int ldc,
    size_t zsA, size_t zsW, size_t zsC)
{
    A += (size_t)blockIdx.z * zsA;
    W += (size_t)blockIdx.z * zsW;
    C += (size_t)blockIdx.z * zsC;

    __shared__ unsigned short As[128 * 32];
    __shared__ unsigned short Ws[128 * 32];
    const int t    = threadIdx.x;
    const int wave = t >> 6, lane = t & 63;
    const int wm   = wave >> 1, wn = wave & 1;
    int bx, by;
    xcd_swizzle(bx, by);
    const int m0 = by * 128, n0 = bx * 128;

    floatx4 acc[4][4];
#pragma unroll
    for (int i = 0; i < 4; i++)
#pragma unroll
        for (int j = 0; j < 4; j++) acc[i][j] = (floatx4)0.f;

    const int lrow = lane >> 2;
    const int lcol = (lane & 3) * 8;
    const unsigned short* Ag = A + (size_t)(m0 + wave * 32 + lrow) * lda + lcol;
    const unsigned short* Wg = W + (size_t)(n0 + wave * 32 + lrow) * ldw + lcol;
    unsigned short* Asw = &As[wave * 32 * 32];
    unsigned short* Wsw = &Ws[wave * 32 * 32];
    const size_t rowskipA = (size_t)16 * lda;
    const size_t rowskipW = (size_t)16 * ldw;

    const int arow  = lane & 15;
    const int aquad = (lane >> 4) * 8;

    for (int k0 = 0; k0 < K; k0 += 32) {
        load_lds16(Ag + k0,             Asw);
        load_lds16(Ag + k0 + rowskipA,  Asw + 16 * 32);
        load_lds16(Wg + k0,             Wsw);
        load_lds16(Wg + k0 + rowskipW,  Wsw + 16 * 32);
        __syncthreads();

        bf16x8 af[4], wf[4];
#pragma unroll
        for (int mi = 0; mi < 4; mi++)
            af[mi] = *(const bf16x8*)&As[(wm * 64 + mi * 16 + arow) * 32 + aquad];
#pragma unroll
        for (int ni = 0; ni < 4; ni++)
            wf[ni] = *(const bf16x8*)&Ws[(wn * 64 + ni * 16 + arow) * 32 + aquad];
#pragma unroll
        for (int mi = 0; mi < 4; mi++)
#pragma unroll
            for (int ni = 0; ni < 4; ni++)
                acc[mi][ni] = __builtin_amdgcn_mfma_f32_16x16x32_bf16(
                    af[mi], wf[ni], acc[mi][ni], 0, 0, 0);
        __syncthreads();
    }

    const int crow = (lane >> 4) * 4, ccol = lane & 15;
#pragma unroll
    for (int mi = 0; mi < 4; mi++) {
#pragma unroll
        for (int ni = 0; ni < 4; ni++) {
            const int gm = m0 + wm * 64 + mi * 16 + crow;
            const int gn = n0 + wn * 64 + ni * 16 + ccol;
            float bb = 0.f;
            if constexpr (HAS_BIAS) bb = bias[gn];
#pragma unroll
            for (int r = 0; r < 4; r++) {
                float v = acc[mi][ni][r] + bb;
                if constexpr (sizeof(CT) == 2)
                    C[(size_t)(gm + r) * ldc + gn] = (CT)f32_to_bf16(v);
                else
                    C[(size_t)(gm + r) * ldc + gn] = v;
            }
        }
    }
}

// ---------------------------------------------------------------------------
// memsc: mem_scores[s,h,l] = ( U[h,s,:].ri[s,l,:] + qcol[s,h,:].bk[h,:] )*SCALE
// grid = 2048 (one block per s).
// ---------------------------------------------------------------------------
#define RI_STRIDE 1032    // padded ushort row stride: spreads l over banks

__global__ __launch_bounds__(256) void memsc_kernel(
    const unsigned short* __restrict__ U, const unsigned short* __restrict__ ri,
    const unsigned short* __restrict__ qkv4, const float* __restrict__ bqkv,
    float* __restrict__ scores)
{
    const int s = blockIdx.x;
    const int t = threadIdx.x;
    __shared__ unsigned short riS[LL * RI_STRIDE];
    __shared__ float qbS[H];
    // stage ri[s] : 8 rows x 1024
    {
        const unsigned short* src = ri + (size_t)s * (LL * D);
#pragma unroll
        for (int j = 0; j < 4; j++) {
            const int off = (j * 256 + t) * 8;        // 0..8191
            const int l = off >> 10, c = off & 1023;
            ushort8 v = *(const ushort8*)(src + off);
            *(ushort8*)&riS[l * RI_STRIDE + c] = v;
        }
    }
    // qb[h] = qcol[s,h,:] . bk[h,:]
    {
        const int h = t >> 4, sub = t & 15;
        const unsigned short* qc = qkv4 + (size_t)s * 4096 + 3 * D + h * HD + sub * 4;
        const float* bk = bqkv + D + h * HD + sub * 4;
        float acc = 0.f;
#pragma unroll
        for (int j = 0; j < 4; j++) acc += bf2f(qc[j]) * bk[j];
#pragma unroll
        for (int off = 1; off < 16; off <<= 1) acc += __shfl_xor(acc, off);
        if (sub == 0) qbS[h] = acc;
    }
    __syncthreads();
    // 128 (h,l) pairs x 2 half-threads each, 512-wide dot per thread
    const int p = t >> 1, half = t & 1;
    const int h = p >> 3, l = p & 7;
    const unsigned short* Up = U + ((size_t)h * SEQ + s) * D + half * 512;
    const unsigned short* rp = &riS[l * RI_STRIDE + half * 512];
    float acc = 0.f;
#pragma unroll 4
    for (int j = 0; j < 64; j++) {
        ushort8 u = *(const ushort8*)(Up + j * 8);
        ushort8 r = *(const ushort8*)(rp + j * 8);
#pragma unroll
        for (int k = 0; k < 8; k++) acc += bf2f(u[k]) * bf2f(r[k]);
    }
    acc += __shfl_xor(acc, 1);
    if (half == 0)
        scores[((size_t)s * H + h) * LL + l] = (acc + qbS[h]) * SCALE;
}

// ---------------------------------------------------------------------------
// Split-K MFMA flash attention (token keys only), 4-way split, LPT order.
// Double-buffered K/V staging (coalesced global->reg->LDS, ONE barrier/tile):
// iteration i writes buf i&1 then barriers; a wave entering iter i+1's write
// phase has passed iter i's barrier, which guarantees all waves finished
// iter i-1's compute on buf (i+1)&1 -> no second barrier needed.
// V staged from the pre-transposed VT (cheap 16B copies, no in-kernel pack).
// Q pre-scaled in regs; Pb is wave-local; mem-key fold lives in merge.
// ---------------------------------------------------------------------------
__global__ __launch_bounds__(256, 3) void attn_split_kernel(
    const unsigned short* __restrict__ qkv4, const unsigned short* __restrict__ VT,
    float* __restrict__ Opart, float2* __restrict__ mlpart)
{
    const int t    = threadIdx.x;
    const int w    = t >> 6, lane = t & 63;
    const int lrow = lane & 15;
    const int lk   = (lane >> 4) * 8;
    const int rrow = (lane >> 4) * 4;
    const int lin  = blockIdx.x;
    const int hsp  = lin & 63, g = lin >> 6;
    const int s    = hsp >> 4, h = hsp & 15;
    const int qt   = 31 - g;               // LPT: longest first
    const int q0   = qt * 64;
    const int n    = qt + 1;
    const int lo   = (s * n) >> 2, hi = ((s + 1) * n) >> 2;
    const int part = (h * 32 + qt) * 4 + s;

    __shared__ unsigned short Ks[2][64 * 72];   // [key][e], dbuf
    __shared__ unsigned short Vs[2][64 * 72];   // [e][key], dbuf
    __shared__ unsigned short Pb[4][16 * 72];   // per-wave P slice (wave-local)
    unsigned short* Pw = Pb[w];

    // Q fragments in registers, pre-scaled by 1/8 (exact pow-2 in bf16)
    bf16x8 qreg[2];
#pragma unroll
    for (int kst = 0; kst < 2; kst++) {
        ushort8 qu = *(const ushort8*)(qkv4 + (size_t)(q0 + w * 16 + lrow) * 4096
                                       + h * HD + kst * 32 + lk);
        ushort8 qs;
#pragma unroll
        for (int j = 0; j < 8; j++) qs[j] = f32_to_bf16(bf2f(qu[j]) * SCALE);
        qreg[kst] = __builtin_bit_cast(bf16x8, qs);
    }

    // staging map: thread covers rows {srow, srow+32}, 16B at column scol
    const int srow = t >> 3;            // 0..31
    const int scol = (t & 7) * 8;       // 0..56
    const unsigned short* Kg = qkv4 + D + h * HD;              // + key*4096
    const unsigned short* Vg = VT + (size_t)h * (HD * SEQ);    // + e*SEQ + key

    bf16x8 kr0, kr1, vr0, vr1;
    float m_i[4], l_i[4];
    floatx4 Oacc[4];
#pragma unroll
    for (int r = 0; r < 4; r++) { m_i[r] = -1e30f; l_i[r] = 0.f; }
#pragma unroll
    for (int et = 0; et < 4; et++) Oacc[et] = (floatx4)0.f;

    // prologue: load tile 'lo' into regs
    if (lo < hi) {
        const int j0 = lo * 64;
        kr0 = *(const bf16x8*)(Kg + (size_t)(j0 + srow) * 4096 + scol);
        kr1 = *(const bf16x8*)(Kg + (size_t)(j0 + 32 + srow) * 4096 + scol);
        vr0 = *(const bf16x8*)(Vg + (size_t)srow * SEQ + j0 + scol);
        vr1 = *(const bf16x8*)(Vg + (size_t)(srow + 32) * SEQ + j0 + scol);
    }

    int cur = 0;
    for (int jt = lo; jt < hi; jt++) {
        const int j0 = jt * 64;
        // write current tile's regs into buf[cur]
        *(bf16x8*)&Ks[cur][srow * 72 + scol]        = kr0;
        *(bf16x8*)&Ks[cur][(srow + 32) * 72 + scol] = kr1;
        *(bf16x8*)&Vs[cur][srow * 72 + scol]        = vr0;
        *(bf16x8*)&Vs[cur][(srow + 32) * 72 + scol] = vr1;
        // issue next tile's loads (hide under this tile's compute)
        if (jt + 1 < hi) {
            const int j0n = (jt + 1) * 64;
            kr0 = *(const bf16x8*)(Kg + (size_t)(j0n + srow) * 4096 + scol);
            kr1 = *(const bf16x8*)(Kg + (size_t)(j0n + 32 + srow) * 4096 + scol);
            vr0 = *(const bf16x8*)(Vg + (size_t)srow * SEQ + j0n + scol);
            vr1 = *(const bf16x8*)(Vg + (size_t)(srow + 32) * SEQ + j0n + scol);
        }
        __syncthreads();                 // staging of buf[cur] visible

        // S = Q K^T
        floatx4 S[4];
#pragma unroll
        for (int nt = 0; nt < 4; nt++) S[nt] = (floatx4)0.f;
        __builtin_amdgcn_s_setprio(1);
#pragma unroll
        for (int kst = 0; kst < 2; kst++) {
#pragma unroll
            for (int nt = 0; nt < 4; nt++) {
                bf16x8 bk = *(const bf16x8*)&Ks[cur][(nt * 16 + lrow) * 72 + kst * 32 + lk];
                S[nt] = __builtin_amdgcn_mfma_f32_16x16x32_bf16(qreg[kst], bk, S[nt], 0, 0, 0);
            }
        }
        __builtin_amdgcn_s_setprio(0);

        // online softmax; P -> Pw (wave-local, no barrier)
        if (jt != qt) {
            // fully-unmasked tile: no causal mask, defer-max (T13)
#pragma unroll
            for (int r = 0; r < 4; r++) {
                float sc[4];
#pragma unroll
                for (int nt = 0; nt < 4; nt++) sc[nt] = S[nt][r];
                float mx = fmaxf(fmaxf(sc[0], sc[1]), fmaxf(sc[2], sc[3]));
#pragma unroll
                for (int off = 1; off < 16; off <<= 1)
                    mx = fmaxf(mx, __shfl_xor(mx, off));
                const bool keep = __all(mx <= m_i[r] + 8.f);
                const float newm = keep ? m_i[r] : fmaxf(m_i[r], mx);
                float ps = 0.f;
#pragma unroll
                for (int nt = 0; nt < 4; nt++) {
                    float pe = __expf(sc[nt] - newm);
                    ps += pe;
                    Pw[(rrow + r) * 72 + nt * 16 + lrow] = f32_to_bf16(pe);
                }
#pragma unroll
                for (int off = 1; off < 16; off <<= 1)
                    ps += __shfl_xor(ps, off);
                if (keep) {
                    l_i[r] += ps;
                } else {
                    const float alpha = __expf(m_i[r] - newm);
                    m_i[r] = newm;
                    l_i[r] = l_i[r] * alpha + ps;
#pragma unroll
                    for (int et = 0; et < 4; et++) Oacc[et][r] *= alpha;
                }
            }
        } else {
            // diagonal tile: causal masking (every row has >=1 valid key)
#pragma unroll
            for (int r = 0; r < 4; r++) {
                const int qg = q0 + w * 16 + rrow + r;
                float sc[4];
                float mx = -1e30f;
#pragma unroll
                for (int nt = 0; nt < 4; nt++) {
                    sc[nt] = S[nt][r];
                    if (j0 + nt * 16 + lrow > qg) sc[nt] = -1e30f;
                    mx = fmaxf(mx, sc[nt]);
                }
#pragma unroll
                for (int off = 1; off < 16; off <<= 1)
                    mx = fmaxf(mx, __shfl_xor(mx, off));
                const float newm  = fmaxf(m_i[r], mx);
                const float alpha = __expf(m_i[r] - newm);
                m_i[r] = newm;
                float ps = 0.f;
#pragma unroll
                for (int nt = 0; nt < 4; nt++) {
                    float pe = __expf(sc[nt] - newm);
                    ps += pe;
                    Pw[(rrow + r) * 72 + nt * 16 + lrow] = f32_to_bf16(pe);
                }
#pragma unroll
                for (int off = 1; off < 16; off <<= 1)
                    ps += __shfl_xor(ps, off);
                l_i[r] = l_i[r] * alpha + ps;
#pragma unroll
                for (int et = 0; et < 4; et++) Oacc[et][r] *= alpha;
            }
        }

        // O += P @ V   (Pw read back by the wave that wrote it)
        __builtin_amdgcn_s_setprio(1);
#pragma unroll
        for (int kst = 0; kst < 2; kst++) {
            bf16x8 ap = *(const bf16x8*)&Pw[lrow * 72 + kst * 32 + lk];
#pragma unroll
            for (int et = 0; et < 4; et++) {
                bf16x8 bv = *(const bf16x8*)&Vs[cur][(et * 16 + lrow) * 72 + kst * 32 + lk];
                Oacc[et] = __builtin_amdgcn_mfma_f32_16x16x32_bf16(ap, bv, Oacc[et], 0, 0, 0);
            }
        }
        __builtin_amdgcn_s_setprio(0);
        cur ^= 1;
    }

    // write partials (uniform for all splits; empty split -> m=-1e30, l=0, O=0)
#pragma unroll
    for (int r = 0; r < 4; r++) {
        const int ql = w * 16 + rrow + r;
        if (lrow == 0) mlpart[(size_t)part * 64 + ql] = make_float2(m_i[r], l_i[r]);
#pragma unroll
        for (int et = 0; et < 4; et++)
            Opart[((size_t)part * 64 + ql) * 64 + et * 16 + lrow] = Oacc[et][r];
    }
}

// ---------------------------------------------------------------------------
// merge: combine the four key-split partials per (h, qt) AND the 8 memory-key
// scores in one exact softmax; normalize. Writes token context (f32), final
// normalized mem weights mwf, and Pmem[s,h] = sum_l mwf.
// ---------------------------------------------------------------------------
__global__ __launch_bounds__(256) void attn_merge_kernel(
    const float* __restrict__ Opart, const float2* __restrict__ mlpart,
    const float* __restrict__ scores,
    float* __restrict__ tok, float* __restrict__ mwf, float* __restrict__ Pmem)
{
    const int blk = blockIdx.x;            // h*32 + qt
    const int h = blk >> 5, qt = blk & 31;
    const int q0 = qt * 64;
    const int t = threadIdx.x, tx = t & 15, ty = t >> 4;
    const size_t pb = (size_t)blk * 4;
#pragma unroll
    for (int i = 0; i < 4; i++) {
        const int qi = ty * 4 + i, qg = q0 + qi;
        float2 ml[4];
#pragma unroll
        for (int ps = 0; ps < 4; ps++) ml[ps] = mlpart[(pb + ps) * 64 + qi];
        const float* msp = scores + ((size_t)qg * H + h) * LL;
        float ms[LL];
#pragma unroll
        for (int l = 0; l < LL; l++) ms[l] = msp[l];
        float M = ml[0].x;
#pragma unroll
        for (int ps = 1; ps < 4; ps++) M = fmaxf(M, ml[ps].x);
#pragma unroll
        for (int l = 0; l < LL; l++) M = fmaxf(M, ms[l]);
        float f[4], L = 0.f;
#pragma unroll
        for (int ps = 0; ps < 4; ps++) { f[ps] = __expf(ml[ps].x - M); L += ml[ps].y * f[ps]; }
        float pm[LL];
#pragma unroll
        for (int l = 0; l < LL; l++) { pm[l] = __expf(ms[l] - M); L += pm[l]; }
        const float rl = 1.f / L;
        float4 o = make_float4(0.f, 0.f, 0.f, 0.f);
#pragma unroll
        for (int ps = 0; ps < 4; ps++) {
            const float fs = f[ps] * rl;
            float4 op = *(const float4*)&Opart[((pb + ps) * 64 + qi) * 64 + tx * 4];
            o.x += op.x * fs; o.y += op.y * fs; o.z += op.z * fs; o.w += op.w * fs;
        }
        *(float4*)&tok[(size_t)qg * D + h * HD + tx * 4] = o;
        if (tx == 0) {
            float* mw = mwf + ((size_t)qg * H + h) * LL;
            float psum = 0.f;
#pragma unroll
            for (int l = 0; l < LL; l++) { float v = pm[l] * rl; mw[l] = v; psum += v; }
            Pmem[(size_t)qg * H + h] = psum;
        }
    }
}

// ---------------------------------------------------------------------------
// rbar[h,s,:] = sum_l mwf[s,h,l] * ri[s*8+l,:]   (bf16 out). grid = 2048 (s).
// ---------------------------------------------------------------------------
__global__ __launch_bounds__(256) void rbar_kernel(
    const float* __restrict__ mwf, const unsigned short* __restrict__ ri,
    unsigned short* __restrict__ rbar)
{
    const int s = blockIdx.x, t = threadIdx.x;
    __shared__ unsigned short riS[LL * D];
    __shared__ float wS[H * LL];
    {
        const unsigned short* src = ri + (size_t)s * (LL * D);
#pragma unroll
        for (int j = 0; j < 4; j++) {
            const int off = (j * 256 + t) * 8;
            *(ushort8*)&riS[off] = *(const ushort8*)(src + off);
        }
    }
    if (t < H * LL) wS[t] = mwf[(size_t)s * (H * LL) + t];
    __syncthreads();
    const int c4 = t * 4;
#pragma unroll
    for (int hh = 0; hh < H; hh++) {
        float v0 = 0.f, v1 = 0.f, v2 = 0.f, v3 = 0.f;
#pragma unroll
        for (int l = 0; l < LL; l++) {
            const float wv = wS[hh * LL + l];
            ushort4 rr = *(const ushort4*)&riS[l * D + c4];
            v0 += wv * bf2f(rr.x); v1 += wv * bf2f(rr.y);
            v2 += wv * bf2f(rr.z); v3 += wv * bf2f(rr.w);
        }
        ushort4 o;
        o.x = f32_to_bf16(v0); o.y = f32_to_bf16(v1);
        o.z = f32_to_bf16(v2); o.w = f32_to_bf16(v3);
        *(ushort4*)(rbar + ((size_t)hh * SEQ + s) * D + c4) = o;
    }
}

// ---------------------------------------------------------------------------
// ctx GEMM: ctx[s, h*64+e] = bf16( rbar[h,s,:] . Wv[h*64+e,:]
//                                  + bv[h*64+e]*Pmem[s,h] + tok[s,h*64+e] )
// 128(M)x64(N) tile, BK=32, 4 waves (wave = m-subtile). grid = (16 mt, 16 h).
// ---------------------------------------------------------------------------
__global__ __launch_bounds__(256) void gemm_ctx_kernel(
    const unsigned short* __restrict__ rbar, const unsigned short* __restrict__ W4,
    const float* __restrict__ bqkv, const float* __restrict__ Pmem,
    const float* __restrict__ tok, unsigned short* __restrict__ ctx)
{
    const int mt = blockIdx.x;      // 0..15
    const int h  = blockIdx.y;      // 0..15
    const unsigned short* A  = rbar + (size_t)h * SEQ * D + (size_t)mt * 128 * D;
    const unsigned short* Wv = W4 + (size_t)(2 * D + h * HD) * D;   // 64 rows x 1024
    const float* bv = bqkv + 2 * D + h * HD;

    __shared__ unsigned short As[128 * 32];
    __shared__ unsigned short Ws[64 * 32];
    const int t    = threadIdx.x;
    const int wave = t >> 6, lane = t & 63;

    floatx4 acc[2][4];
#pragma unroll
    for (int i = 0; i < 2; i++)
#pragma unroll
        for (int j = 0; j < 4; j++) acc[i][j] = (floatx4)0.f;

    const int lrow = lane >> 2;
    const int lcol = (lane & 3) * 8;
    const unsigned short* Ag = A  + (size_t)(wave * 32 + lrow) * D + lcol;
    const unsigned short* Wg = Wv + (size_t)(wave * 32 + lrow) * D + lcol;  // waves 0,1 only
    unsigned short* Asw = &As[wave * 32 * 32];
    unsigned short* Wsw = &Ws[wave * 32 * 32];
    const size_t rowskip = (size_t)16 * D;

    const int arow  = lane & 15;
    const int aquad = (lane >> 4) * 8;

    for (int k0 = 0; k0 < D; k0 += 32) {
        load_lds16(Ag + k0,           Asw);
        load_lds16(Ag + k0 + rowskip, Asw + 16 * 32);
        if (wave < 2) {
            load_lds16(Wg + k0,           Wsw);
            load_lds16(Wg + k0 + rowskip, Wsw + 16 * 32);
        }
        __syncthreads();

        bf16x8 af[2], wf[4];
#pragma unroll
        for (int mi = 0; mi < 2; mi++)
            af[mi] = *(const bf16x8*)&As[(wave * 32 + mi * 16 + arow) * 32 + aquad];
#pragma unroll
        for (int ni = 0; ni < 4; ni++)
            wf[ni] = *(const bf16x8*)&Ws[(ni * 16 + arow) * 32 + aquad];
#pragma unroll
        for (int mi = 0; mi < 2; mi++)
#pragma unroll
            for (int ni = 0; ni < 4; ni++)
                acc[mi][ni] = __builtin_amdgcn_mfma_f32_16x16x32_bf16(
                    af[mi], wf[ni], acc[mi][ni], 0, 0, 0);
        __syncthreads();
    }

    const int crow = (lane >> 4) * 4, ccol = lane & 15;
#pragma unroll
    for (int mi = 0; mi < 2; mi++) {
#pragma unroll
        for (int ni = 0; ni < 4; ni++) {
            const int e  = ni * 16 + ccol;
            const float bb = bv[e];
#pragma unroll
            for (int r = 0; r < 4; r++) {
                const int grow = mt * 128 + wave * 32 + mi * 16 + crow + r;
                float v = acc[mi][ni][r] + bb * Pmem[(size_t)grow * H + h]
                          + tok[(size_t)grow * D + h * HD + e];
                ctx[(size_t)grow * D + h * HD + e] = f32_to_bf16(v);
            }
        }
    }
}

// ---------------------------------------------------------------------------
extern "C" void kernel_launch(void* const* d_in, const int* in_sizes, int n_in,
                              void* d_out, int out_size, void* d_ws, size_t ws_size,
                              hipStream_t stream)
{
    const float* x    = (const float*)d_in[0];
    const float* pv   = (const float*)d_in[1];
    const float* Wqkv = (const float*)d_in[2];
    const float* bqkv = (const float*)d_in[3];
    const float* Wcol = (const float*)d_in[4];
    const float* bcol = (const float*)d_in[5];
    const float* Wout = (const float*)d_in[6];
    const float* bout = (const float*)d_in[7];
    float* out = (float*)d_out;

    char* p = (char*)d_ws;
    unsigned short* x_bf    = (unsigned short*)p; p += (size_t)2048 * 1024 * 2;
    unsigned short* W4_bf   = (unsigned short*)p; p += (size_t)4096 * 1024 * 2;   // Wqkv | Wcol
    unsigned short* Wout_bf = (unsigned short*)p; p += (size_t)1024 * 1024 * 2;
    float*          b4      = (float*)p;          p += (size_t)4096 * 4;
    unsigned short* ri_bf   = (unsigned short*)p; p += (size_t)16384 * 1024 * 2;
    unsigned short* qkv4_bf = (unsigned short*)p; p += (size_t)2048 * 4096 * 2;   // Q|K|V|Qcol
    unsigned short* WkT_bf  = (unsigned short*)p; p += (size_t)16 * 1024 * 64 * 2;
    unsigned short* VT_bf   = (unsigned short*)p; p += (size_t)16 * 64 * 2048 * 2; // V transposed per head
    float*          scores  = (float*)p;          p += (size_t)2048 * 16 * 8 * 4;
    float*          mwf     = (float*)p;          p += (size_t)2048 * 16 * 8 * 4;
    float*          Pmem    = (float*)p;          p += (size_t)2048 * 16 * 4;
    float*          tok     = (float*)p;          p += (size_t)2048 * 1024 * 4;
    unsigned short* ctx_bf  = (unsigned short*)p; p += (size_t)2048 * 1024 * 2;
    float*          Opart   = (float*)p;          p += (size_t)2048 * 64 * 64 * 4;
    float2*         mlpart  = (float2*)p;         p += (size_t)2048 * 64 * 8;
    // U and rbar have disjoint lifetimes (U dead after memsc) -> share buffer
    unsigned short* Urb     = (unsigned short*)p; p += (size_t)16 * 2048 * 1024 * 2;
    // ~182 MB total

    // LN + all bf16 casts + bias concat
    prep_kernel<<<PREP_GRID, 256, 0, stream>>>(pv, x, Wqkv, Wcol, Wout, bqkv, bcol,
                                               ri_bf, x_bf, W4_bf, Wout_bf, b4);
    // per-head transposed Wk for the U GEMM
    wkt_kernel<<<256, 256, 0, stream>>>(Wqkv, WkT_bf);
    // qkv4 = x @ [Wqkv|Wcol]^T + [bqkv|bcol]   (fused, N=4096)
    gemm_bf16_kernel<unsigned short, true><<<dim3(32, 16, 1), 256, 0, stream>>>(
        x_bf, W4_bf, b4, qkv4_bf, 1024, 4096, 1024, 1024, 4096, 0, 0, 0);
    // global V transpose: VT[h][e][key]
    vtr_kernel<<<128, 256, 0, stream>>>(qkv4_bf, VT_bf);
    // U[h] = Qcol[h] @ Wk[h]   (K=64 head-batched; replaces the rk GEMM)
    gemm_bf16_kernel<unsigned short, false><<<dim3(8, 16, 16), 256, 0, stream>>>(
        qkv4_bf + 3 * D, WkT_bf, nullptr, Urb, 64, 1024, 4096, 64, 1024,
        (size_t)HD, (size_t)D * HD, (size_t)SEQ * D);
    // mem_scores = (U . ri + qcol.bk) * scale
    memsc_kernel<<<2048, 256, 0, stream>>>(Urb, ri_bf, qkv4_bf, bqkv, scores);
    // attention split (dbuf, 1 barrier/tile, 4-way, LPT) + merge (mem fold)
    attn_split_kernel<<<2048, 256, 0, stream>>>(qkv4_bf, VT_bf, Opart, mlpart);
    attn_merge_kernel<<<512, 256, 0, stream>>>(Opart, mlpart, scores, tok, mwf, Pmem);
    // rbar = sum_l mwf * ri   (reuses U's buffer)
    rbar_kernel<<<2048, 256, 0, stream>>>(mwf, ri_bf, Urb);
    // ctx = tok + Wv[h] @ rbar[h] + bv*Pmem   (replaces the rv GEMM + fold)
    gemm_ctx_kernel<<<dim3(16, 16), 256, 0, stream>>>(Urb, W4_bf, bqkv, Pmem, tok, ctx_bf);
    // out = ctx @ Wout^T + bout
    gemm_bf16_kernel<float, true><<<dim3(8, 16, 1), 256, 0, stream>>>(
        ctx_bf, Wout_bf, bout, out, 1024, 1024, 1024, 1024, 1024, 0, 0, 0);
}

// Round 6
// 319.442 us; speedup vs baseline: 1.1837x; 1.0594x over previous
//
#include <hip/hip_runtime.h>
#include <math.h>

#define D   1024
#define H   16
#define HD  64
#define SEQ 2048
#define LL  8
#define SCALE 0.125f

typedef __attribute__((ext_vector_type(8))) __bf16 bf16x8;
typedef __attribute__((ext_vector_type(4))) float floatx4;
typedef __attribute__((ext_vector_type(8))) unsigned short ushort8;

__device__ inline unsigned short f32_to_bf16(float f) {
    unsigned int u = __builtin_bit_cast(unsigned int, f);
    u += 0x7FFF + ((u >> 16) & 1);   // round-to-nearest-even
    return (unsigned short)(u >> 16);
}
__device__ inline float bf2f(unsigned short u) {
    unsigned int x = (unsigned int)u << 16;
    return __builtin_bit_cast(float, x);
}
__device__ inline void load_lds16(const void* g, void* l) {
    __builtin_amdgcn_global_load_lds(
        (__attribute__((address_space(1))) void*)g,
        (__attribute__((address_space(3))) void*)l, 16, 0, 0);
}

// XCD-aware swizzle: contiguous grid chunk per XCD -> A-panel L2 reuse.
__device__ inline void xcd_swizzle(int& bx, int& by) {
    const int gx   = gridDim.x;
    const int lin  = blockIdx.y * gx + blockIdx.x;
    const int nblk = gx * gridDim.y;
    const int virt = (lin & 7) * (nblk >> 3) + (lin >> 3);
    bx = virt % gx;
    by = virt / gx;
}

// ---------------------------------------------------------------------------
// prep: LN(reproject(pv)) -> ri_bf  |  f32->bf16 of x, Wqkv|Wcol (->W4), Wout
//       |  bias concat b4 = [bqkv, bcol]
// ---------------------------------------------------------------------------
#define NQ_X    524288
#define NQ_WQKV 786432
#define NQ_WC   262144
#define NQ_WO   262144
#define LN_BLK  16384
#define CVT_BLK 7168          // (NQ_X+NQ_WQKV+NQ_WC+NQ_WO)/256
#define PREP_GRID (LN_BLK + CVT_BLK + 4)

__global__ __launch_bounds__(256) void prep_kernel(
    const float* __restrict__ pv, const float* __restrict__ x,
    const float* __restrict__ Wqkv, const float* __restrict__ Wcol,
    const float* __restrict__ Wout, const float* __restrict__ bqkv,
    const float* __restrict__ bcol,
    unsigned short* __restrict__ ri, unsigned short* __restrict__ xb,
    unsigned short* __restrict__ W4b, unsigned short* __restrict__ Woutb,
    float* __restrict__ b4)
{
    const int b = blockIdx.x;
    const int t = threadIdx.x;
    if (b < LN_BLK) {
        // LayerNorm row r = s*L + l over d=1024
        const int r = b;
        const int s = r >> 3, l = r & 7;
        const int h = t >> 4, e = (t & 15) * 4;
        const size_t src = (size_t)l * (H * SEQ * HD) + (size_t)h * (SEQ * HD)
                         + (size_t)s * HD + e;
        float4 v = *(const float4*)(pv + src);
        float sum = v.x + v.y + v.z + v.w;
        float sq  = v.x * v.x + v.y * v.y + v.z * v.z + v.w * v.w;
#pragma unroll
        for (int off = 32; off; off >>= 1) {
            sum += __shfl_xor(sum, off);
            sq  += __shfl_xor(sq, off);
        }
        __shared__ float red[8];
        if ((t & 63) == 0) { red[(t >> 6) * 2] = sum; red[(t >> 6) * 2 + 1] = sq; }
        __syncthreads();
        sum = red[0] + red[2] + red[4] + red[6];
        sq  = red[1] + red[3] + red[5] + red[7];
        const float mean = sum * (1.f / 1024.f);
        const float var  = sq * (1.f / 1024.f) - mean * mean;
        const float rstd = rsqrtf(var + 1e-5f);
        ushort4 o;
        o.x = f32_to_bf16((v.x - mean) * rstd);
        o.y = f32_to_bf16((v.y - mean) * rstd);
        o.z = f32_to_bf16((v.z - mean) * rstd);
        o.w = f32_to_bf16((v.w - mean) * rstd);
        *(ushort4*)(ri + (size_t)r * D + t * 4) = o;
    } else if (b < LN_BLK + CVT_BLK) {
        const int i = (b - LN_BLK) * 256 + t;
        const float* src; unsigned short* dst; int off;
        if (i < NQ_X)                        { src = x;    dst = xb;    off = i; }
        else if (i < NQ_X + NQ_WQKV)         { src = Wqkv; dst = W4b;   off = i - NQ_X; }
        else if (i < NQ_X + NQ_WQKV + NQ_WC) {
            float4 v = ((const float4*)Wcol)[i - NQ_X - NQ_WQKV];
            ushort4 o;
            o.x = f32_to_bf16(v.x); o.y = f32_to_bf16(v.y);
            o.z = f32_to_bf16(v.z); o.w = f32_to_bf16(v.w);
            ((ushort4*)(W4b))[NQ_WQKV + (i - NQ_X - NQ_WQKV)] = o;
            return;
        }
        else                                 { src = Wout; dst = Woutb; off = i - NQ_X - NQ_WQKV - NQ_WC; }
        float4 v = ((const float4*)src)[off];
        ushort4 o;
        o.x = f32_to_bf16(v.x); o.y = f32_to_bf16(v.y);
        o.z = f32_to_bf16(v.z); o.w = f32_to_bf16(v.w);
        ((ushort4*)dst)[off] = o;
    } else {
        // bias concat: 1024 float4 quads, first 768 from bqkv, rest from bcol
        const int q = (b - LN_BLK - CVT_BLK) * 256 + t;
        float4 v = (q < 768) ? ((const float4*)bqkv)[q] : ((const float4*)bcol)[q - 768];
        ((float4*)b4)[q] = v;
    }
}

// ---------------------------------------------------------------------------
// wkt: WkT[h][c][e] = Wqkv[1024 + h*64 + e][c]  (bf16). Grid 256 = 16h x 16ct.
// ---------------------------------------------------------------------------
__global__ __launch_bounds__(256) void wkt_kernel(
    const float* __restrict__ Wqkv, unsigned short* __restrict__ WkT)
{
    const int h = blockIdx.x >> 4, ct = blockIdx.x & 15;
    const int c0 = ct * 64;
    const int t = threadIdx.x;
    __shared__ float tile[64][68];
    {
        const int e  = t >> 2;            // 0..63
        const int c4 = (t & 3) * 16;      // 0,16,32,48
        const float* src = Wqkv + (size_t)(D + h * HD + e) * D + c0 + c4;
#pragma unroll
        for (int j = 0; j < 4; j++) {
            float4 v = ((const float4*)src)[j];
            *(float4*)&tile[e][c4 + j * 4] = v;
        }
    }
    __syncthreads();
    {
        const int c  = t >> 2;            // local col 0..63
        const int e0 = (t & 3) * 16;      // 0,16,32,48
        ushort8 o0, o1;
#pragma unroll
        for (int j = 0; j < 8; j++) o0[j] = f32_to_bf16(tile[e0 + j][c]);
#pragma unroll
        for (int j = 0; j < 8; j++) o1[j] = f32_to_bf16(tile[e0 + 8 + j][c]);
        unsigned short* dst = WkT + (size_t)h * (D * HD) + (size_t)(c0 + c) * HD + e0;
        *(ushort8*)dst       = o0;
        *(ushort8*)(dst + 8) = o1;
    }
}

// ---------------------------------------------------------------------------
// vtr: VT[h][e][key] = V[key][h*64+e]  (global transpose of the V quarter of
// qkv4). Grid 128 = 16h x 8 key-chunks of 256. LDS-tiled, coalesced both ways.
// ---------------------------------------------------------------------------
__global__ __launch_bounds__(256) void vtr_kernel(
    const unsigned short* __restrict__ qkv4, unsigned short* __restrict__ VT)
{
    const int h = blockIdx.x & 15, kt = blockIdx.x >> 4;
    const int t = threadIdx.x;
    __shared__ unsigned short Vt[64][264];
    const int pr = t & 31, eg = t >> 5;   // key-pair 0..31, e-octet 0..7
#pragma unroll
    for (int sub = 0; sub < 4; sub++) {
        const int j0 = kt * 256 + sub * 64;
        const unsigned short* v0 = qkv4 + (size_t)(j0 + 2 * pr) * 4096 + 2 * D + h * HD + eg * 8;
        ushort8 va = *(const ushort8*)v0;
        ushort8 vb = *(const ushort8*)(v0 + 4096);
#pragma unroll
        for (int j = 0; j < 8; j++) {
            unsigned int pk = (unsigned int)va[j] | ((unsigned int)vb[j] << 16);
            *(unsigned int*)&Vt[eg * 8 + j][sub * 64 + 2 * pr] = pk;
        }
    }
    __syncthreads();
#pragma unroll
    for (int it = 0; it < 8; it++) {
        const int idx = it * 256 + t;
        const int e = idx >> 5, ch = idx & 31;
        ushort8 v = *(const ushort8*)&Vt[e][ch * 8];
        *(ushort8*)(VT + (size_t)h * (HD * SEQ) + (size_t)e * SEQ + kt * 256 + ch * 8) = v;
    }
}

// ---------------------------------------------------------------------------
// bf16 MFMA GEMM: C[M,N] = A[M,K] @ W[N,K]^T (+ bias[N]). CT = float or ushort.
// 128x128 tile, BK=32, 4 waves, 4x4 16x16x32 MFMAs per wave. XCD-swizzled.
// Generalized: lda/ldw/ldc row strides, blockIdx.z batching via element strides.
// ---------------------------------------------------------------------------
template <typename CT, bool HAS_BIAS>
__global__ __launch_bounds__(256) void gemm_bf16_kernel(
    const unsigned short* __restrict__ A, const unsigned short* __restrict__ W,
    const float* __restrict__ bias, CT* __restrict__ C,
    int K, int N, int lda, int ldw, int ldc,
    size_t zsA, size_t zsW, size_t zsC)
{
    A += (size_t)blockIdx.z * zsA;
    W += (size_t)blockIdx.z * zsW;
    C += (size_t)blockIdx.z * zsC;

    __shared__ unsigned short As[128 * 32];
    __shared__ unsigned short Ws[128 * 32];
    const int t    = threadIdx.x;
    const int wave = t >> 6, lane = t & 63;
    const int wm   = wave >> 1, wn = wave & 1;
    int bx, by;
    xcd_swizzle(bx, by);
    const int m0 = by * 128, n0 = bx * 128;

    floatx4 acc[4][4];
#pragma unroll
    for (int i = 0; i < 4; i++)
#pragma unroll
        for (int j = 0; j < 4; j++) acc[i][j] = (floatx4)0.f;

    const int lrow = lane >> 2;
    const int lcol = (lane & 3) * 8;
    const unsigned short* Ag = A + (size_t)(m0 + wave * 32 + lrow) * lda + lcol;
    const unsigned short* Wg = W + (size_t)(n0 + wave * 32 + lrow) * ldw + lcol;
    unsigned short* Asw = &As[wave * 32 * 32];
    unsigned short* Wsw = &Ws[wave * 32 * 32];
    const size_t rowskipA = (size_t)16 * lda;
    const size_t rowskipW = (size_t)16 * ldw;

    const int arow  = lane & 15;
    const int aquad = (lane >> 4) * 8;

    for (int k0 = 0; k0 < K; k0 += 32) {
        load_lds16(Ag + k0,             Asw);
        load_lds16(Ag + k0 + rowskipA,  Asw + 16 * 32);
        load_lds16(Wg + k0,             Wsw);
        load_lds16(Wg + k0 + rowskipW,  Wsw + 16 * 32);
        __syncthreads();

        bf16x8 af[4], wf[4];
#pragma unroll
        for (int mi = 0; mi < 4; mi++)
            af[mi] = *(const bf16x8*)&As[(wm * 64 + mi * 16 + arow) * 32 + aquad];
#pragma unroll
        for (int ni = 0; ni < 4; ni++)
            wf[ni] = *(const bf16x8*)&Ws[(wn * 64 + ni * 16 + arow) * 32 + aquad];
#pragma unroll
        for (int mi = 0; mi < 4; mi++)
#pragma unroll
            for (int ni = 0; ni < 4; ni++)
                acc[mi][ni] = __builtin_amdgcn_mfma_f32_16x16x32_bf16(
                    af[mi], wf[ni], acc[mi][ni], 0, 0, 0);
        __syncthreads();
    }

    const int crow = (lane >> 4) * 4, ccol = lane & 15;
#pragma unroll
    for (int mi = 0; mi < 4; mi++) {
#pragma unroll
        for (int ni = 0; ni < 4; ni++) {
            const int gm = m0 + wm * 64 + mi * 16 + crow;
            const int gn = n0 + wn * 64 + ni * 16 + ccol;
            float bb = 0.f;
            if constexpr (HAS_BIAS) bb = bias[gn];
#pragma unroll
            for (int r = 0; r < 4; r++) {
                float v = acc[mi][ni][r] + bb;
                if constexpr (sizeof(CT) == 2)
                    C[(size_t)(gm + r) * ldc + gn] = (CT)f32_to_bf16(v);
                else
                    C[(size_t)(gm + r) * ldc + gn] = v;
            }
        }
    }
}

// ---------------------------------------------------------------------------
// memsc (MFMA): scores[s,h,l] = ( U[s,h,:].ri[s,l,:] + qcol[s,h,:].bk[h,:] )*SCALE
// U layout is [s][h][d] (s-major) so each block's U[s] is one contiguous 32 KB.
// Per block s: stage U[s] 16x1024 + ri[s] 8x1024 into padded LDS; 4 waves each
// take a 256-wide K-quarter (8 x mfma 16x16x32, B rows 8..15 zeroed in-reg);
// cross-wave reduce via LDS aliasing the dead ri buffer. grid = 2048.
// ---------------------------------------------------------------------------
#define US_STRIDE 1032    // padded ushort row stride (2064 B): rows 4 banks apart

__global__ __launch_bounds__(256) void memsc_kernel(
    const unsigned short* __restrict__ U, const unsigned short* __restrict__ ri,
    const unsigned short* __restrict__ qkv4, const float* __restrict__ bqkv,
    float* __restrict__ scores)
{
    const int s = blockIdx.x;
    const int t = threadIdx.x;
    const int w = t >> 6, lane = t & 63;
    const int lrow = lane & 15;
    const int lkq  = (lane >> 4) * 8;

    __shared__ unsigned short Us[16 * US_STRIDE];
    __shared__ union {
        unsigned short riS[8 * US_STRIDE];
        float red[4][16][16];
    } R;
    __shared__ float qbS[H];

    // stage U[s]: 16 rows x 1024 (contiguous 32 KB in global)
    {
        const unsigned short* src = U + (size_t)s * (H * D);
#pragma unroll
        for (int j = 0; j < 8; j++) {
            const int c = j * 256 + t;          // 0..2047 ushort8 chunks
            const int row = c >> 7, col = (c & 127) * 8;
            *(ushort8*)&Us[row * US_STRIDE + col] =
                *(const ushort8*)(src + row * D + col);
        }
    }
    // stage ri[s]: 8 rows x 1024
    {
        const unsigned short* src = ri + (size_t)s * (LL * D);
#pragma unroll
        for (int j = 0; j < 4; j++) {
            const int c = j * 256 + t;          // 0..1023
            const int row = c >> 7, col = (c & 127) * 8;
            *(ushort8*)&R.riS[row * US_STRIDE + col] =
                *(const ushort8*)(src + row * D + col);
        }
    }
    // qb[h] = qcol[s,h,:] . bk[h,:]
    {
        const int h = t >> 4, sub = t & 15;
        const unsigned short* qc = qkv4 + (size_t)s * 4096 + 3 * D + h * HD + sub * 4;
        const float* bk = bqkv + D + h * HD + sub * 4;
        float acc = 0.f;
#pragma unroll
        for (int j = 0; j < 4; j++) acc += bf2f(qc[j]) * bk[j];
#pragma unroll
        for (int off = 1; off < 16; off <<= 1) acc += __shfl_xor(acc, off);
        if (sub == 0) qbS[h] = acc;
    }
    __syncthreads();

    // each wave: 8 MFMA k-steps over its 256-wide K-quarter
    floatx4 acc = (floatx4)0.f;
    const int kbase = w * 256;
#pragma unroll
    for (int step = 0; step < 8; step++) {
        const int k0 = kbase + step * 32;
        bf16x8 af = *(const bf16x8*)&Us[lrow * US_STRIDE + k0 + lkq];
        bf16x8 bf = {};
        if (lrow < 8) bf = *(const bf16x8*)&R.riS[lrow * US_STRIDE + k0 + lkq];
        acc = __builtin_amdgcn_mfma_f32_16x16x32_bf16(af, bf, acc, 0, 0, 0);
    }
    __syncthreads();               // all riS reads done -> safe to alias as red

    {
        const int crow = (lane >> 4) * 4, ccol = lane & 15;
#pragma unroll
        for (int r = 0; r < 4; r++) R.red[w][crow + r][ccol] = acc[r];
    }
    __syncthreads();

    if (t < H * LL) {
        const int h = t >> 3, l = t & 7;
        float v = R.red[0][h][l] + R.red[1][h][l] + R.red[2][h][l] + R.red[3][h][l];
        scores[((size_t)s * H + h) * LL + l] = (v + qbS[h]) * SCALE;
    }
}

// ---------------------------------------------------------------------------
// Split-K MFMA flash attention (token keys only), 4-way split, LPT order.
// Double-buffered K/V staging (coalesced global->reg->LDS, ONE barrier/tile):
// iteration i writes buf i&1 then barriers; a wave entering iter i+1's write
// phase has passed iter i's barrier, which guarantees all waves finished
// iter i-1's compute on buf (i+1)&1 -> no second barrier needed.
// V staged from the pre-transposed VT (cheap 16B copies, no in-kernel pack).
// Q pre-scaled in regs; Pb is wave-local; mem-key fold lives in merge.
// ---------------------------------------------------------------------------
__global__ __launch_bounds__(256, 3) void attn_split_kernel(
    const unsigned short* __restrict__ qkv4, const unsigned short* __restrict__ VT,
    float* __restrict__ Opart, float2* __restrict__ mlpart)
{
    const int t    = threadIdx.x;
    const int w    = t >> 6, lane = t & 63;
    const int lrow = lane & 15;
    const int lk   = (lane >> 4) * 8;
    const int rrow = (lane >> 4) * 4;
    const int lin  = blockIdx.x;
    const int hsp  = lin & 63, g = lin >> 6;
    const int s    = hsp >> 4, h = hsp & 15;
    const int qt   = 31 - g;               // LPT: longest first
    const int q0   = qt * 64;
    const int n    = qt + 1;
    const int lo   = (s * n) >> 2, hi = ((s + 1) * n) >> 2;
    const int part = (h * 32 + qt) * 4 + s;

    __shared__ unsigned short Ks[2][64 * 72];   // [key][e], dbuf
    __shared__ unsigned short Vs[2][64 * 72];   // [e][key], dbuf
    __shared__ unsigned short Pb[4][16 * 72];   // per-wave P slice (wave-local)
    unsigned short* Pw = Pb[w];

    // Q fragments in registers, pre-scaled by 1/8 (exact pow-2 in bf16)
    bf16x8 qreg[2];
#pragma unroll
    for (int kst = 0; kst < 2; kst++) {
        ushort8 qu = *(const ushort8*)(qkv4 + (size_t)(q0 + w * 16 + lrow) * 4096
                                       + h * HD + kst * 32 + lk);
        ushort8 qs;
#pragma unroll
        for (int j = 0; j < 8; j++) qs[j] = f32_to_bf16(bf2f(qu[j]) * SCALE);
        qreg[kst] = __builtin_bit_cast(bf16x8, qs);
    }

    // staging map: thread covers rows {srow, srow+32}, 16B at column scol
    const int srow = t >> 3;            // 0..31
    const int scol = (t & 7) * 8;       // 0..56
    const unsigned short* Kg = qkv4 + D + h * HD;              // + key*4096
    const unsigned short* Vg = VT + (size_t)h * (HD * SEQ);    // + e*SEQ + key

    bf16x8 kr0, kr1, vr0, vr1;
    float m_i[4], l_i[4];
    floatx4 Oacc[4];
#pragma unroll
    for (int r = 0; r < 4; r++) { m_i[r] = -1e30f; l_i[r] = 0.f; }
#pragma unroll
    for (int et = 0; et < 4; et++) Oacc[et] = (floatx4)0.f;

    // prologue: load tile 'lo' into regs
    if (lo < hi) {
        const int j0 = lo * 64;
        kr0 = *(const bf16x8*)(Kg + (size_t)(j0 + srow) * 4096 + scol);
        kr1 = *(const bf16x8*)(Kg + (size_t)(j0 + 32 + srow) * 4096 + scol);
        vr0 = *(const bf16x8*)(Vg + (size_t)srow * SEQ + j0 + scol);
        vr1 = *(const bf16x8*)(Vg + (size_t)(srow + 32) * SEQ + j0 + scol);
    }

    int cur = 0;
    for (int jt = lo; jt < hi; jt++) {
        const int j0 = jt * 64;
        // write current tile's regs into buf[cur]
        *(bf16x8*)&Ks[cur][srow * 72 + scol]        = kr0;
        *(bf16x8*)&Ks[cur][(srow + 32) * 72 + scol] = kr1;
        *(bf16x8*)&Vs[cur][srow * 72 + scol]        = vr0;
        *(bf16x8*)&Vs[cur][(srow + 32) * 72 + scol] = vr1;
        // issue next tile's loads (hide under this tile's compute)
        if (jt + 1 < hi) {
            const int j0n = (jt + 1) * 64;
            kr0 = *(const bf16x8*)(Kg + (size_t)(j0n + srow) * 4096 + scol);
            kr1 = *(const bf16x8*)(Kg + (size_t)(j0n + 32 + srow) * 4096 + scol);
            vr0 = *(const bf16x8*)(Vg + (size_t)srow * SEQ + j0n + scol);
            vr1 = *(const bf16x8*)(Vg + (size_t)(srow + 32) * SEQ + j0n + scol);
        }
        __syncthreads();                 // staging of buf[cur] visible

        // S = Q K^T
        floatx4 S[4];
#pragma unroll
        for (int nt = 0; nt < 4; nt++) S[nt] = (floatx4)0.f;
        __builtin_amdgcn_s_setprio(1);
#pragma unroll
        for (int kst = 0; kst < 2; kst++) {
#pragma unroll
            for (int nt = 0; nt < 4; nt++) {
                bf16x8 bk = *(const bf16x8*)&Ks[cur][(nt * 16 + lrow) * 72 + kst * 32 + lk];
                S[nt] = __builtin_amdgcn_mfma_f32_16x16x32_bf16(qreg[kst], bk, S[nt], 0, 0, 0);
            }
        }
        __builtin_amdgcn_s_setprio(0);

        // online softmax; P -> Pw (wave-local, no barrier)
        if (jt != qt) {
            // fully-unmasked tile: no causal mask, defer-max (T13)
#pragma unroll
            for (int r = 0; r < 4; r++) {
                float sc[4];
#pragma unroll
                for (int nt = 0; nt < 4; nt++) sc[nt] = S[nt][r];
                float mx = fmaxf(fmaxf(sc[0], sc[1]), fmaxf(sc[2], sc[3]));
#pragma unroll
                for (int off = 1; off < 16; off <<= 1)
                    mx = fmaxf(mx, __shfl_xor(mx, off));
                const bool keep = __all(mx <= m_i[r] + 8.f);
                const float newm = keep ? m_i[r] : fmaxf(m_i[r], mx);
                float ps = 0.f;
#pragma unroll
                for (int nt = 0; nt < 4; nt++) {
                    float pe = __expf(sc[nt] - newm);
                    ps += pe;
                    Pw[(rrow + r) * 72 + nt * 16 + lrow] = f32_to_bf16(pe);
                }
#pragma unroll
                for (int off = 1; off < 16; off <<= 1)
                    ps += __shfl_xor(ps, off);
                if (keep) {
                    l_i[r] += ps;
                } else {
                    const float alpha = __expf(m_i[r] - newm);
                    m_i[r] = newm;
                    l_i[r] = l_i[r] * alpha + ps;
#pragma unroll
                    for (int et = 0; et < 4; et++) Oacc[et][r] *= alpha;
                }
            }
        } else {
            // diagonal tile: causal masking (every row has >=1 valid key)
#pragma unroll
            for (int r = 0; r < 4; r++) {
                const int qg = q0 + w * 16 + rrow + r;
                float sc[4];
                float mx = -1e30f;
#pragma unroll
                for (int nt = 0; nt < 4; nt++) {
                    sc[nt] = S[nt][r];
                    if (j0 + nt * 16 + lrow > qg) sc[nt] = -1e30f;
                    mx = fmaxf(mx, sc[nt]);
                }
#pragma unroll
                for (int off = 1; off < 16; off <<= 1)
                    mx = fmaxf(mx, __shfl_xor(mx, off));
                const float newm  = fmaxf(m_i[r], mx);
                const float alpha = __expf(m_i[r] - newm);
                m_i[r] = newm;
                float ps = 0.f;
#pragma unroll
                for (int nt = 0; nt < 4; nt++) {
                    float pe = __expf(sc[nt] - newm);
                    ps += pe;
                    Pw[(rrow + r) * 72 + nt * 16 + lrow] = f32_to_bf16(pe);
                }
#pragma unroll
                for (int off = 1; off < 16; off <<= 1)
                    ps += __shfl_xor(ps, off);
                l_i[r] = l_i[r] * alpha + ps;
#pragma unroll
                for (int et = 0; et < 4; et++) Oacc[et][r] *= alpha;
            }
        }

        // O += P @ V   (Pw read back by the wave that wrote it)
        __builtin_amdgcn_s_setprio(1);
#pragma unroll
        for (int kst = 0; kst < 2; kst++) {
            bf16x8 ap = *(const bf16x8*)&Pw[lrow * 72 + kst * 32 + lk];
#pragma unroll
            for (int et = 0; et < 4; et++) {
                bf16x8 bv = *(const bf16x8*)&Vs[cur][(et * 16 + lrow) * 72 + kst * 32 + lk];
                Oacc[et] = __builtin_amdgcn_mfma_f32_16x16x32_bf16(ap, bv, Oacc[et], 0, 0, 0);
            }
        }
        __builtin_amdgcn_s_setprio(0);
        cur ^= 1;
    }

    // write partials (uniform for all splits; empty split -> m=-1e30, l=0, O=0)
#pragma unroll
    for (int r = 0; r < 4; r++) {
        const int ql = w * 16 + rrow + r;
        if (lrow == 0) mlpart[(size_t)part * 64 + ql] = make_float2(m_i[r], l_i[r]);
#pragma unroll
        for (int et = 0; et < 4; et++)
            Opart[((size_t)part * 64 + ql) * 64 + et * 16 + lrow] = Oacc[et][r];
    }
}

// ---------------------------------------------------------------------------
// merge: combine the four key-split partials per (h, qt) AND the 8 memory-key
// scores in one exact softmax; normalize. Writes token context (f32), final
// normalized mem weights mwf, and Pmem[s,h] = sum_l mwf.
// ---------------------------------------------------------------------------
__global__ __launch_bounds__(256) void attn_merge_kernel(
    const float* __restrict__ Opart, const float2* __restrict__ mlpart,
    const float* __restrict__ scores,
    float* __restrict__ tok, float* __restrict__ mwf, float* __restrict__ Pmem)
{
    const int blk = blockIdx.x;            // h*32 + qt
    const int h = blk >> 5, qt = blk & 31;
    const int q0 = qt * 64;
    const int t = threadIdx.x, tx = t & 15, ty = t >> 4;
    const size_t pb = (size_t)blk * 4;
#pragma unroll
    for (int i = 0; i < 4; i++) {
        const int qi = ty * 4 + i, qg = q0 + qi;
        float2 ml[4];
#pragma unroll
        for (int ps = 0; ps < 4; ps++) ml[ps] = mlpart[(pb + ps) * 64 + qi];
        const float* msp = scores + ((size_t)qg * H + h) * LL;
        float ms[LL];
#pragma unroll
        for (int l = 0; l < LL; l++) ms[l] = msp[l];
        float M = ml[0].x;
#pragma unroll
        for (int ps = 1; ps < 4; ps++) M = fmaxf(M, ml[ps].x);
#pragma unroll
        for (int l = 0; l < LL; l++) M = fmaxf(M, ms[l]);
        float f[4], L = 0.f;
#pragma unroll
        for (int ps = 0; ps < 4; ps++) { f[ps] = __expf(ml[ps].x - M); L += ml[ps].y * f[ps]; }
        float pm[LL];
#pragma unroll
        for (int l = 0; l < LL; l++) { pm[l] = __expf(ms[l] - M); L += pm[l]; }
        const float rl = 1.f / L;
        float4 o = make_float4(0.f, 0.f, 0.f, 0.f);
#pragma unroll
        for (int ps = 0; ps < 4; ps++) {
            const float fs = f[ps] * rl;
            float4 op = *(const float4*)&Opart[((pb + ps) * 64 + qi) * 64 + tx * 4];
            o.x += op.x * fs; o.y += op.y * fs; o.z += op.z * fs; o.w += op.w * fs;
        }
        *(float4*)&tok[(size_t)qg * D + h * HD + tx * 4] = o;
        if (tx == 0) {
            float* mw = mwf + ((size_t)qg * H + h) * LL;
            float psum = 0.f;
#pragma unroll
            for (int l = 0; l < LL; l++) { float v = pm[l] * rl; mw[l] = v; psum += v; }
            Pmem[(size_t)qg * H + h] = psum;
        }
    }
}

// ---------------------------------------------------------------------------
// rbar[h,s,:] = sum_l mwf[s,h,l] * ri[s*8+l,:]   (bf16 out). grid = 2048 (s).
// ---------------------------------------------------------------------------
__global__ __launch_bounds__(256) void rbar_kernel(
    const float* __restrict__ mwf, const unsigned short* __restrict__ ri,
    unsigned short* __restrict__ rbar)
{
    const int s = blockIdx.x, t = threadIdx.x;
    __shared__ unsigned short riS[LL * D];
    __shared__ float wS[H * LL];
    {
        const unsigned short* src = ri + (size_t)s * (LL * D);
#pragma unroll
        for (int j = 0; j < 4; j++) {
            const int off = (j * 256 + t) * 8;
            *(ushort8*)&riS[off] = *(const ushort8*)(src + off);
        }
    }
    if (t < H * LL) wS[t] = mwf[(size_t)s * (H * LL) + t];
    __syncthreads();
    const int c4 = t * 4;
#pragma unroll
    for (int hh = 0; hh < H; hh++) {
        float v0 = 0.f, v1 = 0.f, v2 = 0.f, v3 = 0.f;
#pragma unroll
        for (int l = 0; l < LL; l++) {
            const float wv = wS[hh * LL + l];
            ushort4 rr = *(const ushort4*)&riS[l * D + c4];
            v0 += wv * bf2f(rr.x); v1 += wv * bf2f(rr.y);
            v2 += wv * bf2f(rr.z); v3 += wv * bf2f(rr.w);
        }
        ushort4 o;
        o.x = f32_to_bf16(v0); o.y = f32_to_bf16(v1);
        o.z = f32_to_bf16(v2); o.w = f32_to_bf16(v3);
        *(ushort4*)(rbar + ((size_t)hh * SEQ + s) * D + c4) = o;
    }
}

// ---------------------------------------------------------------------------
// ctx GEMM: ctx[s, h*64+e] = bf16( rbar[h,s,:] . Wv[h*64+e,:]
//                                  + bv[h*64+e]*Pmem[s,h] + tok[s,h*64+e] )
// 128(M)x64(N) tile, BK=32, 4 waves (wave = m-subtile). grid = (16 mt, 16 h).
// ---------------------------------------------------------------------------
__global__ __launch_bounds__(256) void gemm_ctx_kernel(
    const unsigned short* __restrict__ rbar, const unsigned short* __restrict__ W4,
    const float* __restrict__ bqkv, const float* __restrict__ Pmem,
    const float* __restrict__ tok, unsigned short* __restrict__ ctx)
{
    const int mt = blockIdx.x;      // 0..15
    const int h  = blockIdx.y;      // 0..15
    const unsigned short* A  = rbar + (size_t)h * SEQ * D + (size_t)mt * 128 * D;
    const unsigned short* Wv = W4 + (size_t)(2 * D + h * HD) * D;   // 64 rows x 1024
    const float* bv = bqkv + 2 * D + h * HD;

    __shared__ unsigned short As[128 * 32];
    __shared__ unsigned short Ws[64 * 32];
    const int t    = threadIdx.x;
    const int wave = t >> 6, lane = t & 63;

    floatx4 acc[2][4];
#pragma unroll
    for (int i = 0; i < 2; i++)
#pragma unroll
        for (int j = 0; j < 4; j++) acc[i][j] = (floatx4)0.f;

    const int lrow = lane >> 2;
    const int lcol = (lane & 3) * 8;
    const unsigned short* Ag = A  + (size_t)(wave * 32 + lrow) * D + lcol;
    const unsigned short* Wg = Wv + (size_t)(wave * 32 + lrow) * D + lcol;  // waves 0,1 only
    unsigned short* Asw = &As[wave * 32 * 32];
    unsigned short* Wsw = &Ws[wave * 32 * 32];
    const size_t rowskip = (size_t)16 * D;

    const int arow  = lane & 15;
    const int aquad = (lane >> 4) * 8;

    for (int k0 = 0; k0 < D; k0 += 32) {
        load_lds16(Ag + k0,           Asw);
        load_lds16(Ag + k0 + rowskip, Asw + 16 * 32);
        if (wave < 2) {
            load_lds16(Wg + k0,           Wsw);
            load_lds16(Wg + k0 + rowskip, Wsw + 16 * 32);
        }
        __syncthreads();

        bf16x8 af[2], wf[4];
#pragma unroll
        for (int mi = 0; mi < 2; mi++)
            af[mi] = *(const bf16x8*)&As[(wave * 32 + mi * 16 + arow) * 32 + aquad];
#pragma unroll
        for (int ni = 0; ni < 4; ni++)
            wf[ni] = *(const bf16x8*)&Ws[(ni * 16 + arow) * 32 + aquad];
#pragma unroll
        for (int mi = 0; mi < 2; mi++)
#pragma unroll
            for (int ni = 0; ni < 4; ni++)
                acc[mi][ni] = __builtin_amdgcn_mfma_f32_16x16x32_bf16(
                    af[mi], wf[ni], acc[mi][ni], 0, 0, 0);
        __syncthreads();
    }

    const int crow = (lane >> 4) * 4, ccol = lane & 15;
#pragma unroll
    for (int mi = 0; mi < 2; mi++) {
#pragma unroll
        for (int ni = 0; ni < 4; ni++) {
            const int e  = ni * 16 + ccol;
            const float bb = bv[e];
#pragma unroll
            for (int r = 0; r < 4; r++) {
                const int grow = mt * 128 + wave * 32 + mi * 16 + crow + r;
                float v = acc[mi][ni][r] + bb * Pmem[(size_t)grow * H + h]
                          + tok[(size_t)grow * D + h * HD + e];
                ctx[(size_t)grow * D + h * HD + e] = f32_to_bf16(v);
            }
        }
    }
}

// ---------------------------------------------------------------------------
extern "C" void kernel_launch(void* const* d_in, const int* in_sizes, int n_in,
                              void* d_out, int out_size, void* d_ws, size_t ws_size,
                              hipStream_t stream)
{
    const float* x    = (const float*)d_in[0];
    const float* pv   = (const float*)d_in[1];
    const float* Wqkv = (const float*)d_in[2];
    const float* bqkv = (const float*)d_in[3];
    const float* Wcol = (const float*)d_in[4];
    const float* bcol = (const float*)d_in[5];
    const float* Wout = (const float*)d_in[6];
    const float* bout = (const float*)d_in[7];
    float* out = (float*)d_out;

    char* p = (char*)d_ws;
    unsigned short* x_bf    = (unsigned short*)p; p += (size_t)2048 * 1024 * 2;
    unsigned short* W4_bf   = (unsigned short*)p; p += (size_t)4096 * 1024 * 2;   // Wqkv | Wcol
    unsigned short* Wout_bf = (unsigned short*)p; p += (size_t)1024 * 1024 * 2;
    float*          b4      = (float*)p;          p += (size_t)4096 * 4;
    unsigned short* ri_bf   = (unsigned short*)p; p += (size_t)16384 * 1024 * 2;
    unsigned short* qkv4_bf = (unsigned short*)p; p += (size_t)2048 * 4096 * 2;   // Q|K|V|Qcol
    unsigned short* WkT_bf  = (unsigned short*)p; p += (size_t)16 * 1024 * 64 * 2;
    unsigned short* VT_bf   = (unsigned short*)p; p += (size_t)16 * 64 * 2048 * 2; // V transposed per head
    float*          scores  = (float*)p;          p += (size_t)2048 * 16 * 8 * 4;
    float*          mwf     = (float*)p;          p += (size_t)2048 * 16 * 8 * 4;
    float*          Pmem    = (float*)p;          p += (size_t)2048 * 16 * 4;
    float*          tok     = (float*)p;          p += (size_t)2048 * 1024 * 4;
    unsigned short* ctx_bf  = (unsigned short*)p; p += (size_t)2048 * 1024 * 2;
    float*          Opart   = (float*)p;          p += (size_t)2048 * 64 * 64 * 4;
    float2*         mlpart  = (float2*)p;         p += (size_t)2048 * 64 * 8;
    // U and rbar have disjoint lifetimes (U dead after memsc) -> share buffer
    unsigned short* Urb     = (unsigned short*)p; p += (size_t)16 * 2048 * 1024 * 2;
    // ~182 MB total

    // LN + all bf16 casts + bias concat
    prep_kernel<<<PREP_GRID, 256, 0, stream>>>(pv, x, Wqkv, Wcol, Wout, bqkv, bcol,
                                               ri_bf, x_bf, W4_bf, Wout_bf, b4);
    // per-head transposed Wk for the U GEMM
    wkt_kernel<<<256, 256, 0, stream>>>(Wqkv, WkT_bf);
    // qkv4 = x @ [Wqkv|Wcol]^T + [bqkv|bcol]   (fused, N=4096)
    gemm_bf16_kernel<unsigned short, true><<<dim3(32, 16, 1), 256, 0, stream>>>(
        x_bf, W4_bf, b4, qkv4_bf, 1024, 4096, 1024, 1024, 4096, 0, 0, 0);
    // global V transpose: VT[h][e][key]
    vtr_kernel<<<128, 256, 0, stream>>>(qkv4_bf, VT_bf);
    // U = Qcol @ Wk, written s-major: U[s][h][d] via ldc=H*D, zsC=D
    gemm_bf16_kernel<unsigned short, false><<<dim3(8, 16, 16), 256, 0, stream>>>(
        qkv4_bf + 3 * D, WkT_bf, nullptr, Urb, 64, 1024, 4096, 64, H * D,
        (size_t)HD, (size_t)D * HD, (size_t)D);
    // mem_scores = (U . ri + qcol.bk) * scale   (MFMA, one block per s)
    memsc_kernel<<<2048, 256, 0, stream>>>(Urb, ri_bf, qkv4_bf, bqkv, scores);
    // attention split (dbuf, 1 barrier/tile, 4-way, LPT) + merge (mem fold)
    attn_split_kernel<<<2048, 256, 0, stream>>>(qkv4_bf, VT_bf, Opart, mlpart);
    attn_merge_kernel<<<512, 256, 0, stream>>>(Opart, mlpart, scores, tok, mwf, Pmem);
    // rbar = sum_l mwf * ri   (reuses U's buffer)
    rbar_kernel<<<2048, 256, 0, stream>>>(mwf, ri_bf, Urb);
    // ctx = tok + Wv[h] @ rbar[h] + bv*Pmem   (replaces the rv GEMM + fold)
    gemm_ctx_kernel<<<dim3(16, 16), 256, 0, stream>>>(Urb, W4_bf, bqkv, Pmem, tok, ctx_bf);
    // out = ctx @ Wout^T + bout
    gemm_bf16_kernel<float, true><<<dim3(8, 16, 1), 256, 0, stream>>>(
        ctx_bf, Wout_bf, bout, out, 1024, 1024, 1024, 1024, 1024, 0, 0, 0);
}

// Round 7
// 304.695 us; speedup vs baseline: 1.2409x; 1.0484x over previous
//
#include <hip/hip_runtime.h>
#include <math.h>

#define D   1024
#define H   16
#define HD  64
#define SEQ 2048
#define LL  8
#define SCALE 0.125f

typedef __attribute__((ext_vector_type(8))) __bf16 bf16x8;
typedef __attribute__((ext_vector_type(4))) float floatx4;
typedef __attribute__((ext_vector_type(8))) unsigned short ushort8;
typedef __attribute__((ext_vector_type(4))) unsigned int uintx4;

__device__ inline unsigned short f32_to_bf16(float f) {
    unsigned int u = __builtin_bit_cast(unsigned int, f);
    u += 0x7FFF + ((u >> 16) & 1);   // round-to-nearest-even
    return (unsigned short)(u >> 16);
}
__device__ inline float bf2f(unsigned short u) {
    unsigned int x = (unsigned int)u << 16;
    return __builtin_bit_cast(float, x);
}
__device__ inline unsigned int cvt_pk_bf16(float lo, float hi) {
    unsigned int r;
    asm("v_cvt_pk_bf16_f32 %0, %1, %2" : "=v"(r) : "v"(lo), "v"(hi));
    return r;
}
__device__ inline void load_lds16(const void* g, void* l) {
    __builtin_amdgcn_global_load_lds(
        (__attribute__((address_space(1))) void*)g,
        (__attribute__((address_space(3))) void*)l, 16, 0, 0);
}

// XCD-aware swizzle: contiguous grid chunk per XCD -> A-panel L2 reuse.
__device__ inline void xcd_swizzle(int& bx, int& by) {
    const int gx   = gridDim.x;
    const int lin  = blockIdx.y * gx + blockIdx.x;
    const int nblk = gx * gridDim.y;
    const int virt = (lin & 7) * (nblk >> 3) + (lin >> 3);
    bx = virt % gx;
    by = virt / gx;
}

// ---------------------------------------------------------------------------
// prep: LN(reproject(pv)) -> ri_bf  |  f32->bf16 of x, Wqkv|Wcol (->W4), Wout
//       |  bias concat b4 = [bqkv, bcol]
// ---------------------------------------------------------------------------
#define NQ_X    524288
#define NQ_WQKV 786432
#define NQ_WC   262144
#define NQ_WO   262144
#define LN_BLK  16384
#define CVT_BLK 7168          // (NQ_X+NQ_WQKV+NQ_WC+NQ_WO)/256
#define PREP_GRID (LN_BLK + CVT_BLK + 4)

__global__ __launch_bounds__(256) void prep_kernel(
    const float* __restrict__ pv, const float* __restrict__ x,
    const float* __restrict__ Wqkv, const float* __restrict__ Wcol,
    const float* __restrict__ Wout, const float* __restrict__ bqkv,
    const float* __restrict__ bcol,
    unsigned short* __restrict__ ri, unsigned short* __restrict__ xb,
    unsigned short* __restrict__ W4b, unsigned short* __restrict__ Woutb,
    float* __restrict__ b4)
{
    const int b = blockIdx.x;
    const int t = threadIdx.x;
    if (b < LN_BLK) {
        // LayerNorm row r = s*L + l over d=1024
        const int r = b;
        const int s = r >> 3, l = r & 7;
        const int h = t >> 4, e = (t & 15) * 4;
        const size_t src = (size_t)l * (H * SEQ * HD) + (size_t)h * (SEQ * HD)
                         + (size_t)s * HD + e;
        float4 v = *(const float4*)(pv + src);
        float sum = v.x + v.y + v.z + v.w;
        float sq  = v.x * v.x + v.y * v.y + v.z * v.z + v.w * v.w;
#pragma unroll
        for (int off = 32; off; off >>= 1) {
            sum += __shfl_xor(sum, off);
            sq  += __shfl_xor(sq, off);
        }
        __shared__ float red[8];
        if ((t & 63) == 0) { red[(t >> 6) * 2] = sum; red[(t >> 6) * 2 + 1] = sq; }
        __syncthreads();
        sum = red[0] + red[2] + red[4] + red[6];
        sq  = red[1] + red[3] + red[5] + red[7];
        const float mean = sum * (1.f / 1024.f);
        const float var  = sq * (1.f / 1024.f) - mean * mean;
        const float rstd = rsqrtf(var + 1e-5f);
        ushort4 o;
        o.x = f32_to_bf16((v.x - mean) * rstd);
        o.y = f32_to_bf16((v.y - mean) * rstd);
        o.z = f32_to_bf16((v.z - mean) * rstd);
        o.w = f32_to_bf16((v.w - mean) * rstd);
        *(ushort4*)(ri + (size_t)r * D + t * 4) = o;
    } else if (b < LN_BLK + CVT_BLK) {
        const int i = (b - LN_BLK) * 256 + t;
        const float* src; unsigned short* dst; int off;
        if (i < NQ_X)                        { src = x;    dst = xb;    off = i; }
        else if (i < NQ_X + NQ_WQKV)         { src = Wqkv; dst = W4b;   off = i - NQ_X; }
        else if (i < NQ_X + NQ_WQKV + NQ_WC) {
            float4 v = ((const float4*)Wcol)[i - NQ_X - NQ_WQKV];
            ushort4 o;
            o.x = f32_to_bf16(v.x); o.y = f32_to_bf16(v.y);
            o.z = f32_to_bf16(v.z); o.w = f32_to_bf16(v.w);
            ((ushort4*)(W4b))[NQ_WQKV + (i - NQ_X - NQ_WQKV)] = o;
            return;
        }
        else                                 { src = Wout; dst = Woutb; off = i - NQ_X - NQ_WQKV - NQ_WC; }
        float4 v = ((const float4*)src)[off];
        ushort4 o;
        o.x = f32_to_bf16(v.x); o.y = f32_to_bf16(v.y);
        o.z = f32_to_bf16(v.z); o.w = f32_to_bf16(v.w);
        ((ushort4*)dst)[off] = o;
    } else {
        // bias concat: 1024 float4 quads, first 768 from bqkv, rest from bcol
        const int q = (b - LN_BLK - CVT_BLK) * 256 + t;
        float4 v = (q < 768) ? ((const float4*)bqkv)[q] : ((const float4*)bcol)[q - 768];
        ((float4*)b4)[q] = v;
    }
}

// ---------------------------------------------------------------------------
// wkt: WkT[h][c][e] = Wqkv[1024 + h*64 + e][c]  (bf16). Grid 256 = 16h x 16ct.
// ---------------------------------------------------------------------------
__global__ __launch_bounds__(256) void wkt_kernel(
    const float* __restrict__ Wqkv, unsigned short* __restrict__ WkT)
{
    const int h = blockIdx.x >> 4, ct = blockIdx.x & 15;
    const int c0 = ct * 64;
    const int t = threadIdx.x;
    __shared__ float tile[64][68];
    {
        const int e  = t >> 2;            // 0..63
        const int c4 = (t & 3) * 16;      // 0,16,32,48
        const float* src = Wqkv + (size_t)(D + h * HD + e) * D + c0 + c4;
#pragma unroll
        for (int j = 0; j < 4; j++) {
            float4 v = ((const float4*)src)[j];
            *(float4*)&tile[e][c4 + j * 4] = v;
        }
    }
    __syncthreads();
    {
        const int c  = t >> 2;            // local col 0..63
        const int e0 = (t & 3) * 16;      // 0,16,32,48
        ushort8 o0, o1;
#pragma unroll
        for (int j = 0; j < 8; j++) o0[j] = f32_to_bf16(tile[e0 + j][c]);
#pragma unroll
        for (int j = 0; j < 8; j++) o1[j] = f32_to_bf16(tile[e0 + 8 + j][c]);
        unsigned short* dst = WkT + (size_t)h * (D * HD) + (size_t)(c0 + c) * HD + e0;
        *(ushort8*)dst       = o0;
        *(ushort8*)(dst + 8) = o1;
    }
}

// ---------------------------------------------------------------------------
// vtr: VT[h][e][key] = V[key][h*64+e]  (global transpose of the V quarter of
// qkv4). Grid 128 = 16h x 8 key-chunks of 256. LDS-tiled, coalesced both ways.
// ---------------------------------------------------------------------------
__global__ __launch_bounds__(256) void vtr_kernel(
    const unsigned short* __restrict__ qkv4, unsigned short* __restrict__ VT)
{
    const int h = blockIdx.x & 15, kt = blockIdx.x >> 4;
    const int t = threadIdx.x;
    __shared__ unsigned short Vt[64][264];
    const int pr = t & 31, eg = t >> 5;   // key-pair 0..31, e-octet 0..7
#pragma unroll
    for (int sub = 0; sub < 4; sub++) {
        const int j0 = kt * 256 + sub * 64;
        const unsigned short* v0 = qkv4 + (size_t)(j0 + 2 * pr) * 4096 + 2 * D + h * HD + eg * 8;
        ushort8 va = *(const ushort8*)v0;
        ushort8 vb = *(const ushort8*)(v0 + 4096);
#pragma unroll
        for (int j = 0; j < 8; j++) {
            unsigned int pk = (unsigned int)va[j] | ((unsigned int)vb[j] << 16);
            *(unsigned int*)&Vt[eg * 8 + j][sub * 64 + 2 * pr] = pk;
        }
    }
    __syncthreads();
#pragma unroll
    for (int it = 0; it < 8; it++) {
        const int idx = it * 256 + t;
        const int e = idx >> 5, ch = idx & 31;
        ushort8 v = *(const ushort8*)&Vt[e][ch * 8];
        *(ushort8*)(VT + (size_t)h * (HD * SEQ) + (size_t)e * SEQ + kt * 256 + ch * 8) = v;
    }
}

// ---------------------------------------------------------------------------
// bf16 MFMA GEMM: C[M,N] = A[M,K] @ W[N,K]^T (+ bias[N]). CT = float or ushort.
// 128x128 tile, BK=32, 4 waves, 4x4 16x16x32 MFMAs per wave. XCD-swizzled.
// Generalized: lda/ldw/ldc row strides, blockIdx.z batching via element strides.
// ---------------------------------------------------------------------------
template <typename CT, bool HAS_BIAS>
__global__ __launch_bounds__(256) void gemm_bf16_kernel(
    const unsigned short* __restrict__ A, const unsigned short* __restrict__ W,
    const float* __restrict__ bias, CT* __restrict__ C,
    int K, int N, int lda, int ldw, int ldc,
    size_t zsA, size_t zsW, size_t zsC)
{
    A += (size_t)blockIdx.z * zsA;
    W += (size_t)blockIdx.z * zsW;
    C += (size_t)blockIdx.z * zsC;

    __shared__ unsigned short As[128 * 32];
    __shared__ unsigned short Ws[128 * 32];
    const int t    = threadIdx.x;
    const int wave = t >> 6, lane = t & 63;
    const int wm   = wave >> 1, wn = wave & 1;
    int bx, by;
    xcd_swizzle(bx, by);
    const int m0 = by * 128, n0 = bx * 128;

    floatx4 acc[4][4];
#pragma unroll
    for (int i = 0; i < 4; i++)
#pragma unroll
        for (int j = 0; j < 4; j++) acc[i][j] = (floatx4)0.f;

    const int lrow = lane >> 2;
    const int lcol = (lane & 3) * 8;
    const unsigned short* Ag = A + (size_t)(m0 + wave * 32 + lrow) * lda + lcol;
    const unsigned short* Wg = W + (size_t)(n0 + wave * 32 + lrow) * ldw + lcol;
    unsigned short* Asw = &As[wave * 32 * 32];
    unsigned short* Wsw = &Ws[wave * 32 * 32];
    const size_t rowskipA = (size_t)16 * lda;
    const size_t rowskipW = (size_t)16 * ldw;

    const int arow  = lane & 15;
    const int aquad = (lane >> 4) * 8;

    for (int k0 = 0; k0 < K; k0 += 32) {
        load_lds16(Ag + k0,             Asw);
        load_lds16(Ag + k0 + rowskipA,  Asw + 16 * 32);
        load_lds16(Wg + k0,             Wsw);
        load_lds16(Wg + k0 + rowskipW,  Wsw + 16 * 32);
        __syncthreads();

        bf16x8 af[4], wf[4];
#pragma unroll
        for (int mi = 0; mi < 4; mi++)
            af[mi] = *(const bf16x8*)&As[(wm * 64 + mi * 16 + arow) * 32 + aquad];
#pragma unroll
        for (int ni = 0; ni < 4; ni++)
            wf[ni] = *(const bf16x8*)&Ws[(wn * 64 + ni * 16 + arow) * 32 + aquad];
#pragma unroll
        for (int mi = 0; mi < 4; mi++)
#pragma unroll
            for (int ni = 0; ni < 4; ni++)
                acc[mi][ni] = __builtin_amdgcn_mfma_f32_16x16x32_bf16(
                    af[mi], wf[ni], acc[mi][ni], 0, 0, 0);
        __syncthreads();
    }

    const int crow = (lane >> 4) * 4, ccol = lane & 15;
#pragma unroll
    for (int mi = 0; mi < 4; mi++) {
#pragma unroll
        for (int ni = 0; ni < 4; ni++) {
            const int gm = m0 + wm * 64 + mi * 16 + crow;
            const int gn = n0 + wn * 64 + ni * 16 + ccol;
            float bb = 0.f;
            if constexpr (HAS_BIAS) bb = bias[gn];
#pragma unroll
            for (int r = 0; r < 4; r++) {
                float v = acc[mi][ni][r] + bb;
                if constexpr (sizeof(CT) == 2)
                    C[(size_t)(gm + r) * ldc + gn] = (CT)f32_to_bf16(v);
                else
                    C[(size_t)(gm + r) * ldc + gn] = v;
            }
        }
    }
}

// ---------------------------------------------------------------------------
// memsc (MFMA): scores[s,h,l] = ( U[s,h,:].ri[s,l,:] + qcol[s,h,:].bk[h,:] )*SCALE
// U layout is [s][h][d] (s-major) so each block's U[s] is one contiguous 32 KB.
// ---------------------------------------------------------------------------
#define US_STRIDE 1032    // padded ushort row stride (2064 B): rows 4 banks apart

__global__ __launch_bounds__(256) void memsc_kernel(
    const unsigned short* __restrict__ U, const unsigned short* __restrict__ ri,
    const unsigned short* __restrict__ qkv4, const float* __restrict__ bqkv,
    float* __restrict__ scores)
{
    const int s = blockIdx.x;
    const int t = threadIdx.x;
    const int w = t >> 6, lane = t & 63;
    const int lrow = lane & 15;
    const int lkq  = (lane >> 4) * 8;

    __shared__ unsigned short Us[16 * US_STRIDE];
    __shared__ union {
        unsigned short riS[8 * US_STRIDE];
        float red[4][16][16];
    } R;
    __shared__ float qbS[H];

    // stage U[s]: 16 rows x 1024 (contiguous 32 KB in global)
    {
        const unsigned short* src = U + (size_t)s * (H * D);
#pragma unroll
        for (int j = 0; j < 8; j++) {
            const int c = j * 256 + t;          // 0..2047 ushort8 chunks
            const int row = c >> 7, col = (c & 127) * 8;
            *(ushort8*)&Us[row * US_STRIDE + col] =
                *(const ushort8*)(src + row * D + col);
        }
    }
    // stage ri[s]: 8 rows x 1024
    {
        const unsigned short* src = ri + (size_t)s * (LL * D);
#pragma unroll
        for (int j = 0; j < 4; j++) {
            const int c = j * 256 + t;          // 0..1023
            const int row = c >> 7, col = (c & 127) * 8;
            *(ushort8*)&R.riS[row * US_STRIDE + col] =
                *(const ushort8*)(src + row * D + col);
        }
    }
    // qb[h] = qcol[s,h,:] . bk[h,:]
    {
        const int h = t >> 4, sub = t & 15;
        const unsigned short* qc = qkv4 + (size_t)s * 4096 + 3 * D + h * HD + sub * 4;
        const float* bk = bqkv + D + h * HD + sub * 4;
        float acc = 0.f;
#pragma unroll
        for (int j = 0; j < 4; j++) acc += bf2f(qc[j]) * bk[j];
#pragma unroll
        for (int off = 1; off < 16; off <<= 1) acc += __shfl_xor(acc, off);
        if (sub == 0) qbS[h] = acc;
    }
    __syncthreads();

    // each wave: 8 MFMA k-steps over its 256-wide K-quarter
    floatx4 acc = (floatx4)0.f;
    const int kbase = w * 256;
#pragma unroll
    for (int step = 0; step < 8; step++) {
        const int k0 = kbase + step * 32;
        bf16x8 af = *(const bf16x8*)&Us[lrow * US_STRIDE + k0 + lkq];
        bf16x8 bf = {};
        if (lrow < 8) bf = *(const bf16x8*)&R.riS[lrow * US_STRIDE + k0 + lkq];
        acc = __builtin_amdgcn_mfma_f32_16x16x32_bf16(af, bf, acc, 0, 0, 0);
    }
    __syncthreads();               // all riS reads done -> safe to alias as red

    {
        const int crow = (lane >> 4) * 4, ccol = lane & 15;
#pragma unroll
        for (int r = 0; r < 4; r++) R.red[w][crow + r][ccol] = acc[r];
    }
    __syncthreads();

    if (t < H * LL) {
        const int h = t >> 3, l = t & 7;
        float v = R.red[0][h][l] + R.red[1][h][l] + R.red[2][h][l] + R.red[3][h][l];
        scores[((size_t)s * H + h) * LL + l] = (v + qbS[h]) * SCALE;
    }
}

// ---------------------------------------------------------------------------
// Split-K MFMA flash attention, 4-way split, LPT order. Swapped-QK^T (T12):
// S^T = mfma(K,Q) so each lane owns q = lane&15 -> softmax reduce = 2 shfls,
// m/l are per-lane scalars. P->bf16 via v_cvt_pk_bf16_f32 + 2-round lane
// butterfly (xor32 then xor16) assembles PV B-frags fully in registers -- no
// P LDS buffer. PV = mfma(V^T, P) -> O^T; epilogue = 4x float4 stores.
// Double-buffered K/V staging, ONE barrier per tile (proof in R4 notes).
// LDS 36864 -> 4 blocks/CU.
// ---------------------------------------------------------------------------
__global__ __launch_bounds__(256, 4) void attn_split_kernel(
    const unsigned short* __restrict__ qkv4, const unsigned short* __restrict__ VT,
    float* __restrict__ Opart, float2* __restrict__ mlpart)
{
    const int t    = threadIdx.x;
    const int w    = t >> 6, lane = t & 63;
    const int lrow = lane & 15;           // q-row / e-row / key-col of fragments
    const int lk   = (lane >> 4) * 8;
    const int qd   = lane >> 4;           // lane quarter 0..3
    const int hi2  = qd >> 1, lo2 = qd & 1;
    const int lin  = blockIdx.x;
    const int hsp  = lin & 63, g = lin >> 6;
    const int s    = hsp >> 4, h = hsp & 15;
    const int qt   = 31 - g;              // LPT: longest first
    const int q0   = qt * 64;
    const int n    = qt + 1;
    const int lo   = (s * n) >> 2, hi = ((s + 1) * n) >> 2;
    const int part = (h * 32 + qt) * 4 + s;

    __shared__ unsigned short Ks[2][64 * 72];   // [key][e], dbuf
    __shared__ unsigned short Vs[2][64 * 72];   // [e][key], dbuf

    // Q fragments in registers, pre-scaled by 1/8 (exact pow-2 in bf16)
    bf16x8 qreg[2];
#pragma unroll
    for (int kst = 0; kst < 2; kst++) {
        ushort8 qu = *(const ushort8*)(qkv4 + (size_t)(q0 + w * 16 + lrow) * 4096
                                       + h * HD + kst * 32 + lk);
        ushort8 qs;
#pragma unroll
        for (int j = 0; j < 8; j++) qs[j] = f32_to_bf16(bf2f(qu[j]) * SCALE);
        qreg[kst] = __builtin_bit_cast(bf16x8, qs);
    }
    const int qg = q0 + w * 16 + lrow;    // this lane's global q row

    // staging map: thread covers rows {srow, srow+32}, 16B at column scol
    const int srow = t >> 3;            // 0..31
    const int scol = (t & 7) * 8;       // 0..56
    const unsigned short* Kg = qkv4 + D + h * HD;              // + key*4096
    const unsigned short* Vg = VT + (size_t)h * (HD * SEQ);    // + e*SEQ + key

    bf16x8 kr0, kr1, vr0, vr1;
    float m_i = -1e30f, l_i = 0.f;
    floatx4 Oacc[4];
#pragma unroll
    for (int et = 0; et < 4; et++) Oacc[et] = (floatx4)0.f;

    // prologue: load tile 'lo' into regs
    if (lo < hi) {
        const int j0 = lo * 64;
        kr0 = *(const bf16x8*)(Kg + (size_t)(j0 + srow) * 4096 + scol);
        kr1 = *(const bf16x8*)(Kg + (size_t)(j0 + 32 + srow) * 4096 + scol);
        vr0 = *(const bf16x8*)(Vg + (size_t)srow * SEQ + j0 + scol);
        vr1 = *(const bf16x8*)(Vg + (size_t)(srow + 32) * SEQ + j0 + scol);
    }

    int cur = 0;
    for (int jt = lo; jt < hi; jt++) {
        const int j0 = jt * 64;
        // write current tile's regs into buf[cur]
        *(bf16x8*)&Ks[cur][srow * 72 + scol]        = kr0;
        *(bf16x8*)&Ks[cur][(srow + 32) * 72 + scol] = kr1;
        *(bf16x8*)&Vs[cur][srow * 72 + scol]        = vr0;
        *(bf16x8*)&Vs[cur][(srow + 32) * 72 + scol] = vr1;
        // issue next tile's loads (hide under this tile's compute)
        if (jt + 1 < hi) {
            const int j0n = (jt + 1) * 64;
            kr0 = *(const bf16x8*)(Kg + (size_t)(j0n + srow) * 4096 + scol);
            kr1 = *(const bf16x8*)(Kg + (size_t)(j0n + 32 + srow) * 4096 + scol);
            vr0 = *(const bf16x8*)(Vg + (size_t)srow * SEQ + j0n + scol);
            vr1 = *(const bf16x8*)(Vg + (size_t)(srow + 32) * SEQ + j0n + scol);
        }
        __syncthreads();                 // staging of buf[cur] visible

        // S^T = K Q^T : lane holds q = lane&15, keys nt*16 + qd*4 + r
        floatx4 S[4];
#pragma unroll
        for (int nt = 0; nt < 4; nt++) S[nt] = (floatx4)0.f;
        __builtin_amdgcn_s_setprio(1);
#pragma unroll
        for (int kst = 0; kst < 2; kst++) {
#pragma unroll
            for (int nt = 0; nt < 4; nt++) {
                bf16x8 bk = *(const bf16x8*)&Ks[cur][(nt * 16 + lrow) * 72 + kst * 32 + lk];
                S[nt] = __builtin_amdgcn_mfma_f32_16x16x32_bf16(bk, qreg[kst], S[nt], 0, 0, 0);
            }
        }
        __builtin_amdgcn_s_setprio(0);

        const bool diag = (jt == qt);
        if (diag) {
#pragma unroll
            for (int nt = 0; nt < 4; nt++)
#pragma unroll
                for (int r = 0; r < 4; r++)
                    if (j0 + nt * 16 + qd * 4 + r > qg) S[nt][r] = -1e30f;
        }
        float mx = -1e30f;
#pragma unroll
        for (int nt = 0; nt < 4; nt++)
            mx = fmaxf(mx, fmaxf(fmaxf(S[nt][0], S[nt][1]), fmaxf(S[nt][2], S[nt][3])));
        mx = fmaxf(mx, __shfl_xor(mx, 16));
        mx = fmaxf(mx, __shfl_xor(mx, 32));
        const bool keep = !diag && __all(mx <= m_i + 8.f);
        if (!keep) {
            const float newm = fmaxf(m_i, mx);
            const float a = __expf(m_i - newm);
            m_i = newm;
            l_i *= a;
#pragma unroll
            for (int et = 0; et < 4; et++) Oacc[et] *= a;
        }

        // P = exp(S - m); pack to bf16 pairs per tile (up[t][pair])
        float ps = 0.f;
        unsigned int up[4][2];
#pragma unroll
        for (int nt = 0; nt < 4; nt++) {
            float p0 = __expf(S[nt][0] - m_i);
            float p1 = __expf(S[nt][1] - m_i);
            float p2 = __expf(S[nt][2] - m_i);
            float p3 = __expf(S[nt][3] - m_i);
            ps += (p0 + p1) + (p2 + p3);
            up[nt][0] = cvt_pk_bf16(p0, p1);
            up[nt][1] = cvt_pk_bf16(p2, p3);
        }
        ps += __shfl_xor(ps, 16);
        ps += __shfl_xor(ps, 32);
        l_i += ps;

        // --- 2-round butterfly: redistribute P^T into PV B-fragments ---
        // Round 1 (xor32): send tiles with (t&1) != hi2.
        unsigned int s0 = hi2 ? up[0][0] : up[1][0];
        unsigned int s1 = hi2 ? up[0][1] : up[1][1];
        unsigned int s2 = hi2 ? up[2][0] : up[3][0];
        unsigned int s3 = hi2 ? up[2][1] : up[3][1];
        s0 = __shfl_xor(s0, 32); s1 = __shfl_xor(s1, 32);
        s2 = __shfl_xor(s2, 32); s3 = __shfl_xor(s3, 32);
        const unsigned int ownA0 = hi2 ? up[1][0] : up[0][0];   // tile tA = hi2
        const unsigned int ownA1 = hi2 ? up[1][1] : up[0][1];
        const unsigned int ownB0 = hi2 ? up[3][0] : up[2][0];   // tile tB = hi2+2
        const unsigned int ownB1 = hi2 ? up[3][1] : up[2][1];
        // Round 2 (xor16): keep source with s>>1 == lo2 (own iff hi2==lo2).
        const bool keepOwn = (hi2 == lo2);
        unsigned int eA0 = keepOwn ? s0 : ownA0;
        unsigned int eA1 = keepOwn ? s1 : ownA1;
        unsigned int eB0 = keepOwn ? s2 : ownB0;
        unsigned int eB1 = keepOwn ? s3 : ownB1;
        eA0 = __shfl_xor(eA0, 16); eA1 = __shfl_xor(eA1, 16);
        eB0 = __shfl_xor(eB0, 16); eB1 = __shfl_xor(eB1, 16);
        const unsigned int kA0 = keepOwn ? ownA0 : s0;
        const unsigned int kA1 = keepOwn ? ownA1 : s1;
        const unsigned int kB0 = keepOwn ? ownB0 : s2;
        const unsigned int kB1 = keepOwn ? ownB1 : s3;
        // final order: [sLo.p0, sLo.p1, sHi.p0, sHi.p1]; kept has s&1==lo2
        uintx4 fA = { lo2 ? eA0 : kA0, lo2 ? eA1 : kA1,
                      lo2 ? kA0 : eA0, lo2 ? kA1 : eA1 };
        uintx4 fB = { lo2 ? eB0 : kB0, lo2 ? eB1 : kB1,
                      lo2 ? kB0 : eB0, lo2 ? kB1 : eB1 };
        bf16x8 apA = __builtin_bit_cast(bf16x8, fA);   // kst=0 keys
        bf16x8 apB = __builtin_bit_cast(bf16x8, fB);   // kst=1 keys

        // O^T += V^T P : mfma(V^T_frag, P_frag) -> D[m=e][n=q]
        __builtin_amdgcn_s_setprio(1);
#pragma unroll
        for (int et = 0; et < 4; et++) {
            bf16x8 bv = *(const bf16x8*)&Vs[cur][(et * 16 + lrow) * 72 + lk];
            Oacc[et] = __builtin_amdgcn_mfma_f32_16x16x32_bf16(bv, apA, Oacc[et], 0, 0, 0);
        }
#pragma unroll
        for (int et = 0; et < 4; et++) {
            bf16x8 bv = *(const bf16x8*)&Vs[cur][(et * 16 + lrow) * 72 + 32 + lk];
            Oacc[et] = __builtin_amdgcn_mfma_f32_16x16x32_bf16(bv, apB, Oacc[et], 0, 0, 0);
        }
        __builtin_amdgcn_s_setprio(0);
        cur ^= 1;
    }

    // write partials: q = w*16+lrow, e = et*16 + qd*4 + r  -> float4 stores
#pragma unroll
    for (int et = 0; et < 4; et++) {
        float4 o = make_float4(Oacc[et][0], Oacc[et][1], Oacc[et][2], Oacc[et][3]);
        *(float4*)&Opart[((size_t)part * 64 + w * 16 + lrow) * 64 + et * 16 + qd * 4] = o;
    }
    if (qd == 0)
        mlpart[(size_t)part * 64 + w * 16 + lrow] = make_float2(m_i, l_i);
}

// ---------------------------------------------------------------------------
// merge: combine the four key-split partials per (h, qt) AND the 8 memory-key
// scores in one exact softmax; normalize. Writes token context (f32), final
// normalized mem weights mwf, and Pmem[s,h] = sum_l mwf.
// ---------------------------------------------------------------------------
__global__ __launch_bounds__(256) void attn_merge_kernel(
    const float* __restrict__ Opart, const float2* __restrict__ mlpart,
    const float* __restrict__ scores,
    float* __restrict__ tok, float* __restrict__ mwf, float* __restrict__ Pmem)
{
    const int blk = blockIdx.x;            // h*32 + qt
    const int h = blk >> 5, qt = blk & 31;
    const int q0 = qt * 64;
    const int t = threadIdx.x, tx = t & 15, ty = t >> 4;
    const size_t pb = (size_t)blk * 4;
#pragma unroll
    for (int i = 0; i < 4; i++) {
        const int qi = ty * 4 + i, qg = q0 + qi;
        float2 ml[4];
#pragma unroll
        for (int ps = 0; ps < 4; ps++) ml[ps] = mlpart[(pb + ps) * 64 + qi];
        const float* msp = scores + ((size_t)qg * H + h) * LL;
        float ms[LL];
#pragma unroll
        for (int l = 0; l < LL; l++) ms[l] = msp[l];
        float M = ml[0].x;
#pragma unroll
        for (int ps = 1; ps < 4; ps++) M = fmaxf(M, ml[ps].x);
#pragma unroll
        for (int l = 0; l < LL; l++) M = fmaxf(M, ms[l]);
        float f[4], L = 0.f;
#pragma unroll
        for (int ps = 0; ps < 4; ps++) { f[ps] = __expf(ml[ps].x - M); L += ml[ps].y * f[ps]; }
        float pm[LL];
#pragma unroll
        for (int l = 0; l < LL; l++) { pm[l] = __expf(ms[l] - M); L += pm[l]; }
        const float rl = 1.f / L;
        float4 o = make_float4(0.f, 0.f, 0.f, 0.f);
#pragma unroll
        for (int ps = 0; ps < 4; ps++) {
            const float fs = f[ps] * rl;
            float4 op = *(const float4*)&Opart[((pb + ps) * 64 + qi) * 64 + tx * 4];
            o.x += op.x * fs; o.y += op.y * fs; o.z += op.z * fs; o.w += op.w * fs;
        }
        *(float4*)&tok[(size_t)qg * D + h * HD + tx * 4] = o;
        if (tx == 0) {
            float* mw = mwf + ((size_t)qg * H + h) * LL;
            float psum = 0.f;
#pragma unroll
            for (int l = 0; l < LL; l++) { float v = pm[l] * rl; mw[l] = v; psum += v; }
            Pmem[(size_t)qg * H + h] = psum;
        }
    }
}

// ---------------------------------------------------------------------------
// rbar[h,s,:] = sum_l mwf[s,h,l] * ri[s*8+l,:]   (bf16 out). grid = 2048 (s).
// ---------------------------------------------------------------------------
__global__ __launch_bounds__(256) void rbar_kernel(
    const float* __restrict__ mwf, const unsigned short* __restrict__ ri,
    unsigned short* __restrict__ rbar)
{
    const int s = blockIdx.x, t = threadIdx.x;
    __shared__ unsigned short riS[LL * D];
    __shared__ float wS[H * LL];
    {
        const unsigned short* src = ri + (size_t)s * (LL * D);
#pragma unroll
        for (int j = 0; j < 4; j++) {
            const int off = (j * 256 + t) * 8;
            *(ushort8*)&riS[off] = *(const ushort8*)(src + off);
        }
    }
    if (t < H * LL) wS[t] = mwf[(size_t)s * (H * LL) + t];
    __syncthreads();
    const int c4 = t * 4;
#pragma unroll
    for (int hh = 0; hh < H; hh++) {
        float v0 = 0.f, v1 = 0.f, v2 = 0.f, v3 = 0.f;
#pragma unroll
        for (int l = 0; l < LL; l++) {
            const float wv = wS[hh * LL + l];
            ushort4 rr = *(const ushort4*)&riS[l * D + c4];
            v0 += wv * bf2f(rr.x); v1 += wv * bf2f(rr.y);
            v2 += wv * bf2f(rr.z); v3 += wv * bf2f(rr.w);
        }
        ushort4 o;
        o.x = f32_to_bf16(v0); o.y = f32_to_bf16(v1);
        o.z = f32_to_bf16(v2); o.w = f32_to_bf16(v3);
        *(ushort4*)(rbar + ((size_t)hh * SEQ + s) * D + c4) = o;
    }
}

// ---------------------------------------------------------------------------
// ctx GEMM: ctx[s, h*64+e] = bf16( rbar[h,s,:] . Wv[h*64+e,:]
//                                  + bv[h*64+e]*Pmem[s,h] + tok[s,h*64+e] )
// 128(M)x64(N) tile, BK=32, 4 waves (wave = m-subtile). grid = (16 mt, 16 h).
// ---------------------------------------------------------------------------
__global__ __launch_bounds__(256) void gemm_ctx_kernel(
    const unsigned short* __restrict__ rbar, const unsigned short* __restrict__ W4,
    const float* __restrict__ bqkv, const float* __restrict__ Pmem,
    const float* __restrict__ tok, unsigned short* __restrict__ ctx)
{
    const int mt = blockIdx.x;      // 0..15
    const int h  = blockIdx.y;      // 0..15
    const unsigned short* A  = rbar + (size_t)h * SEQ * D + (size_t)mt * 128 * D;
    const unsigned short* Wv = W4 + (size_t)(2 * D + h * HD) * D;   // 64 rows x 1024
    const float* bv = bqkv + 2 * D + h * HD;

    __shared__ unsigned short As[128 * 32];
    __shared__ unsigned short Ws[64 * 32];
    const int t    = threadIdx.x;
    const int wave = t >> 6, lane = t & 63;

    floatx4 acc[2][4];
#pragma unroll
    for (int i = 0; i < 2; i++)
#pragma unroll
        for (int j = 0; j < 4; j++) acc[i][j] = (floatx4)0.f;

    const int lrow = lane >> 2;
    const int lcol = (lane & 3) * 8;
    const unsigned short* Ag = A  + (size_t)(wave * 32 + lrow) * D + lcol;
    const unsigned short* Wg = Wv + (size_t)(wave * 32 + lrow) * D + lcol;  // waves 0,1 only
    unsigned short* Asw = &As[wave * 32 * 32];
    unsigned short* Wsw = &Ws[wave * 32 * 32];
    const size_t rowskip = (size_t)16 * D;

    const int arow  = lane & 15;
    const int aquad = (lane >> 4) * 8;

    for (int k0 = 0; k0 < D; k0 += 32) {
        load_lds16(Ag + k0,           Asw);
        load_lds16(Ag + k0 + rowskip, Asw + 16 * 32);
        if (wave < 2) {
            load_lds16(Wg + k0,           Wsw);
            load_lds16(Wg + k0 + rowskip, Wsw + 16 * 32);
        }
        __syncthreads();

        bf16x8 af[2], wf[4];
#pragma unroll
        for (int mi = 0; mi < 2; mi++)
            af[mi] = *(const bf16x8*)&As[(wave * 32 + mi * 16 + arow) * 32 + aquad];
#pragma unroll
        for (int ni = 0; ni < 4; ni++)
            wf[ni] = *(const bf16x8*)&Ws[(ni * 16 + arow) * 32 + aquad];
#pragma unroll
        for (int mi = 0; mi < 2; mi++)
#pragma unroll
            for (int ni = 0; ni < 4; ni++)
                acc[mi][ni] = __builtin_amdgcn_mfma_f32_16x16x32_bf16(
                    af[mi], wf[ni], acc[mi][ni], 0, 0, 0);
        __syncthreads();
    }

    const int crow = (lane >> 4) * 4, ccol = lane & 15;
#pragma unroll
    for (int mi = 0; mi < 2; mi++) {
#pragma unroll
        for (int ni = 0; ni < 4; ni++) {
            const int e  = ni * 16 + ccol;
            const float bb = bv[e];
#pragma unroll
            for (int r = 0; r < 4; r++) {
                const int grow = mt * 128 + wave * 32 + mi * 16 + crow + r;
                float v = acc[mi][ni][r] + bb * Pmem[(size_t)grow * H + h]
                          + tok[(size_t)grow * D + h * HD + e];
                ctx[(size_t)grow * D + h * HD + e] = f32_to_bf16(v);
            }
        }
    }
}

// ---------------------------------------------------------------------------
extern "C" void kernel_launch(void* const* d_in, const int* in_sizes, int n_in,
                              void* d_out, int out_size, void* d_ws, size_t ws_size,
                              hipStream_t stream)
{
    const float* x    = (const float*)d_in[0];
    const float* pv   = (const float*)d_in[1];
    const float* Wqkv = (const float*)d_in[2];
    const float* bqkv = (const float*)d_in[3];
    const float* Wcol = (const float*)d_in[4];
    const float* bcol = (const float*)d_in[5];
    const float* Wout = (const float*)d_in[6];
    const float* bout = (const float*)d_in[7];
    float* out = (float*)d_out;

    char* p = (char*)d_ws;
    unsigned short* x_bf    = (unsigned short*)p; p += (size_t)2048 * 1024 * 2;
    unsigned short* W4_bf   = (unsigned short*)p; p += (size_t)4096 * 1024 * 2;   // Wqkv | Wcol
    unsigned short* Wout_bf = (unsigned short*)p; p += (size_t)1024 * 1024 * 2;
    float*          b4      = (float*)p;          p += (size_t)4096 * 4;
    unsigned short* ri_bf   = (unsigned short*)p; p += (size_t)16384 * 1024 * 2;
    unsigned short* qkv4_bf = (unsigned short*)p; p += (size_t)2048 * 4096 * 2;   // Q|K|V|Qcol
    unsigned short* WkT_bf  = (unsigned short*)p; p += (size_t)16 * 1024 * 64 * 2;
    unsigned short* VT_bf   = (unsigned short*)p; p += (size_t)16 * 64 * 2048 * 2; // V transposed per head
    float*          scores  = (float*)p;          p += (size_t)2048 * 16 * 8 * 4;
    float*          mwf     = (float*)p;          p += (size_t)2048 * 16 * 8 * 4;
    float*          Pmem    = (float*)p;          p += (size_t)2048 * 16 * 4;
    float*          tok     = (float*)p;          p += (size_t)2048 * 1024 * 4;
    unsigned short* ctx_bf  = (unsigned short*)p; p += (size_t)2048 * 1024 * 2;
    float*          Opart   = (float*)p;          p += (size_t)2048 * 64 * 64 * 4;
    float2*         mlpart  = (float2*)p;         p += (size_t)2048 * 64 * 8;
    // U and rbar have disjoint lifetimes (U dead after memsc) -> share buffer
    unsigned short* Urb     = (unsigned short*)p; p += (size_t)16 * 2048 * 1024 * 2;
    // ~182 MB total

    // LN + all bf16 casts + bias concat
    prep_kernel<<<PREP_GRID, 256, 0, stream>>>(pv, x, Wqkv, Wcol, Wout, bqkv, bcol,
                                               ri_bf, x_bf, W4_bf, Wout_bf, b4);
    // per-head transposed Wk for the U GEMM
    wkt_kernel<<<256, 256, 0, stream>>>(Wqkv, WkT_bf);
    // qkv4 = x @ [Wqkv|Wcol]^T + [bqkv|bcol]   (fused, N=4096)
    gemm_bf16_kernel<unsigned short, true><<<dim3(32, 16, 1), 256, 0, stream>>>(
        x_bf, W4_bf, b4, qkv4_bf, 1024, 4096, 1024, 1024, 4096, 0, 0, 0);
    // global V transpose: VT[h][e][key]
    vtr_kernel<<<128, 256, 0, stream>>>(qkv4_bf, VT_bf);
    // U = Qcol @ Wk, written s-major: U[s][h][d] via ldc=H*D, zsC=D
    gemm_bf16_kernel<unsigned short, false><<<dim3(8, 16, 16), 256, 0, stream>>>(
        qkv4_bf + 3 * D, WkT_bf, nullptr, Urb, 64, 1024, 4096, 64, H * D,
        (size_t)HD, (size_t)D * HD, (size_t)D);
    // mem_scores = (U . ri + qcol.bk) * scale   (MFMA, one block per s)
    memsc_kernel<<<2048, 256, 0, stream>>>(Urb, ri_bf, qkv4_bf, bqkv, scores);
    // attention split (swapped-QK, dbuf, 1 barrier/tile, 4-way, LPT) + merge
    attn_split_kernel<<<2048, 256, 0, stream>>>(qkv4_bf, VT_bf, Opart, mlpart);
    attn_merge_kernel<<<512, 256, 0, stream>>>(Opart, mlpart, scores, tok, mwf, Pmem);
    // rbar = sum_l mwf * ri   (reuses U's buffer)
    rbar_kernel<<<2048, 256, 0, stream>>>(mwf, ri_bf, Urb);
    // ctx = tok + Wv[h] @ rbar[h] + bv*Pmem   (replaces the rv GEMM + fold)
    gemm_ctx_kernel<<<dim3(16, 16), 256, 0, stream>>>(Urb, W4_bf, bqkv, Pmem, tok, ctx_bf);
    // out = ctx @ Wout^T + bout
    gemm_bf16_kernel<float, true><<<dim3(8, 16, 1), 256, 0, stream>>>(
        ctx_bf, Wout_bf, bout, out, 1024, 1024, 1024, 1024, 1024, 0, 0, 0);
}

// Round 8
// 297.535 us; speedup vs baseline: 1.2708x; 1.0241x over previous
//
#include <hip/hip_runtime.h>
#include <math.h>

#define D   1024
#define H   16
#define HD  64
#define SEQ 2048
#define LL  8
#define SCALE 0.125f

typedef __attribute__((ext_vector_type(8))) __bf16 bf16x8;
typedef __attribute__((ext_vector_type(4))) float floatx4;
typedef __attribute__((ext_vector_type(8))) unsigned short ushort8;
typedef __attribute__((ext_vector_type(4))) unsigned int uintx4;

__device__ inline unsigned short f32_to_bf16(float f) {
    unsigned int u = __builtin_bit_cast(unsigned int, f);
    u += 0x7FFF + ((u >> 16) & 1);   // round-to-nearest-even
    return (unsigned short)(u >> 16);
}
__device__ inline float bf2f(unsigned short u) {
    unsigned int x = (unsigned int)u << 16;
    return __builtin_bit_cast(float, x);
}
__device__ inline unsigned int cvt_pk_bf16(float lo, float hi) {
    unsigned int r;
    asm("v_cvt_pk_bf16_f32 %0, %1, %2" : "=v"(r) : "v"(lo), "v"(hi));
    return r;
}
__device__ inline void load_lds16(const void* g, void* l) {
    __builtin_amdgcn_global_load_lds(
        (__attribute__((address_space(1))) void*)g,
        (__attribute__((address_space(3))) void*)l, 16, 0, 0);
}

// XCD-aware swizzle: contiguous grid chunk per XCD -> A-panel L2 reuse.
__device__ inline void xcd_swizzle(int& bx, int& by) {
    const int gx   = gridDim.x;
    const int lin  = blockIdx.y * gx + blockIdx.x;
    const int nblk = gx * gridDim.y;
    const int virt = (lin & 7) * (nblk >> 3) + (lin >> 3);
    bx = virt % gx;
    by = virt / gx;
}

// ---------------------------------------------------------------------------
// prep: LN(reproject(pv)) -> ri_bf (wave-per-row, no LDS/barrier)
//       | f32->bf16 of x, Wqkv|Wcol (->W4), Wout (4 quads/thread)
//       | bias concat b4 = [bqkv, bcol]
// ---------------------------------------------------------------------------
#define NQ_X    524288
#define NQ_WQKV 786432
#define NQ_WC   262144
#define NQ_WO   262144
#define LN_BLK  4096          // 4 waves/block x 1 row/wave = 16384 rows
#define CVT_BLK 1792          // 1835008 quads / (256 thr * 4 quads)
#define PREP_GRID (LN_BLK + CVT_BLK + 4)

__global__ __launch_bounds__(256) void prep_kernel(
    const float* __restrict__ pv, const float* __restrict__ x,
    const float* __restrict__ Wqkv, const float* __restrict__ Wcol,
    const float* __restrict__ Wout, const float* __restrict__ bqkv,
    const float* __restrict__ bcol,
    unsigned short* __restrict__ ri, unsigned short* __restrict__ xb,
    unsigned short* __restrict__ W4b, unsigned short* __restrict__ Woutb,
    float* __restrict__ b4)
{
    const int b = blockIdx.x;
    const int t = threadIdx.x;
    if (b < LN_BLK) {
        // LayerNorm row r = s*L + l over d=1024; one wave per row.
        const int w = t >> 6, lane = t & 63;
        const int r = b * 4 + w;
        const int s = r >> 3, l = r & 7;
        const int e4 = (lane & 15) * 4;
        const int hq = lane >> 4;
        const float* base = pv + (size_t)l * (H * SEQ * HD) + (size_t)s * HD;
        float4 v[4];
#pragma unroll
        for (int j = 0; j < 4; j++)
            v[j] = *(const float4*)(base + (size_t)(j * 4 + hq) * (SEQ * HD) + e4);
        float sum = 0.f, sq = 0.f;
#pragma unroll
        for (int j = 0; j < 4; j++) {
            sum += (v[j].x + v[j].y) + (v[j].z + v[j].w);
            sq  += (v[j].x * v[j].x + v[j].y * v[j].y)
                 + (v[j].z * v[j].z + v[j].w * v[j].w);
        }
#pragma unroll
        for (int off = 1; off < 64; off <<= 1) {
            sum += __shfl_xor(sum, off);
            sq  += __shfl_xor(sq, off);
        }
        const float mean = sum * (1.f / 1024.f);
        const float var  = sq * (1.f / 1024.f) - mean * mean;
        const float rstd = rsqrtf(var + 1e-5f);
#pragma unroll
        for (int j = 0; j < 4; j++) {
            ushort4 o;
            o.x = f32_to_bf16((v[j].x - mean) * rstd);
            o.y = f32_to_bf16((v[j].y - mean) * rstd);
            o.z = f32_to_bf16((v[j].z - mean) * rstd);
            o.w = f32_to_bf16((v[j].w - mean) * rstd);
            *(ushort4*)(ri + (size_t)r * D + (j * 4 + hq) * 64 + e4) = o;
        }
    } else if (b < LN_BLK + CVT_BLK) {
        const int base = (b - LN_BLK) * 1024;
#pragma unroll
        for (int j = 0; j < 4; j++) {
            const int i = base + j * 256 + t;
            const float* src; unsigned short* dst; int soff, doff;
            if (i < NQ_X)                        { src = x;    dst = xb;    soff = i;                          doff = soff; }
            else if (i < NQ_X + NQ_WQKV)         { src = Wqkv; dst = W4b;   soff = i - NQ_X;                   doff = soff; }
            else if (i < NQ_X + NQ_WQKV + NQ_WC) { src = Wcol; dst = W4b;   soff = i - NQ_X - NQ_WQKV;         doff = i - NQ_X; }
            else                                 { src = Wout; dst = Woutb; soff = i - NQ_X - NQ_WQKV - NQ_WC; doff = soff; }
            float4 v = ((const float4*)src)[soff];
            ushort4 o;
            o.x = f32_to_bf16(v.x); o.y = f32_to_bf16(v.y);
            o.z = f32_to_bf16(v.z); o.w = f32_to_bf16(v.w);
            ((ushort4*)dst)[doff] = o;
        }
    } else {
        // bias concat: 1024 float4 quads, first 768 from bqkv, rest from bcol
        const int q = (b - LN_BLK - CVT_BLK) * 256 + t;
        float4 v = (q < 768) ? ((const float4*)bqkv)[q] : ((const float4*)bcol)[q - 768];
        ((float4*)b4)[q] = v;
    }
}

// ---------------------------------------------------------------------------
// wkt: WkT[h][c][e] = Wqkv[1024 + h*64 + e][c]  (bf16). Grid 256 = 16h x 16ct.
// ---------------------------------------------------------------------------
__global__ __launch_bounds__(256) void wkt_kernel(
    const float* __restrict__ Wqkv, unsigned short* __restrict__ WkT)
{
    const int h = blockIdx.x >> 4, ct = blockIdx.x & 15;
    const int c0 = ct * 64;
    const int t = threadIdx.x;
    __shared__ float tile[64][68];
    {
        const int e  = t >> 2;            // 0..63
        const int c4 = (t & 3) * 16;      // 0,16,32,48
        const float* src = Wqkv + (size_t)(D + h * HD + e) * D + c0 + c4;
#pragma unroll
        for (int j = 0; j < 4; j++) {
            float4 v = ((const float4*)src)[j];
            *(float4*)&tile[e][c4 + j * 4] = v;
        }
    }
    __syncthreads();
    {
        const int c  = t >> 2;            // local col 0..63
        const int e0 = (t & 3) * 16;      // 0,16,32,48
        ushort8 o0, o1;
#pragma unroll
        for (int j = 0; j < 8; j++) o0[j] = f32_to_bf16(tile[e0 + j][c]);
#pragma unroll
        for (int j = 0; j < 8; j++) o1[j] = f32_to_bf16(tile[e0 + 8 + j][c]);
        unsigned short* dst = WkT + (size_t)h * (D * HD) + (size_t)(c0 + c) * HD + e0;
        *(ushort8*)dst       = o0;
        *(ushort8*)(dst + 8) = o1;
    }
}

// ---------------------------------------------------------------------------
// vtr: VT[h][e][key] = V[key][h*64+e]  (global transpose of the V quarter of
// qkv4). Grid 128 = 16h x 8 key-chunks of 256. LDS-tiled, coalesced both ways.
// ---------------------------------------------------------------------------
__global__ __launch_bounds__(256) void vtr_kernel(
    const unsigned short* __restrict__ qkv4, unsigned short* __restrict__ VT)
{
    const int h = blockIdx.x & 15, kt = blockIdx.x >> 4;
    const int t = threadIdx.x;
    __shared__ unsigned short Vt[64][264];
    const int pr = t & 31, eg = t >> 5;   // key-pair 0..31, e-octet 0..7
#pragma unroll
    for (int sub = 0; sub < 4; sub++) {
        const int j0 = kt * 256 + sub * 64;
        const unsigned short* v0 = qkv4 + (size_t)(j0 + 2 * pr) * 4096 + 2 * D + h * HD + eg * 8;
        ushort8 va = *(const ushort8*)v0;
        ushort8 vb = *(const ushort8*)(v0 + 4096);
#pragma unroll
        for (int j = 0; j < 8; j++) {
            unsigned int pk = (unsigned int)va[j] | ((unsigned int)vb[j] << 16);
            *(unsigned int*)&Vt[eg * 8 + j][sub * 64 + 2 * pr] = pk;
        }
    }
    __syncthreads();
#pragma unroll
    for (int it = 0; it < 8; it++) {
        const int idx = it * 256 + t;
        const int e = idx >> 5, ch = idx & 31;
        ushort8 v = *(const ushort8*)&Vt[e][ch * 8];
        *(ushort8*)(VT + (size_t)h * (HD * SEQ) + (size_t)e * SEQ + kt * 256 + ch * 8) = v;
    }
}

// ---------------------------------------------------------------------------
// bf16 MFMA GEMM: C[M,N] = A[M,K] @ W[N,K]^T (+ bias[N]). CT = float or ushort.
// BMx128 tile (BM = 128 or 64), BK=32, 4 waves. XCD-swizzled.
// BM=128: waves 2x2, acc[4][4]. BM=64: waves 2x2 over 32-row halves, acc[2][4]
// (grid-starved shapes -> 2x more blocks). lda/ldw/ldc strides + z batching.
// ---------------------------------------------------------------------------
template <typename CT, bool HAS_BIAS, int BM>
__global__ __launch_bounds__(256) void gemm_bf16_kernel(
    const unsigned short* __restrict__ A, const unsigned short* __restrict__ W,
    const float* __restrict__ bias, CT* __restrict__ C,
    int K, int N, int lda, int ldw, int ldc,
    size_t zsA, size_t zsW, size_t zsC)
{
    A += (size_t)blockIdx.z * zsA;
    W += (size_t)blockIdx.z * zsW;
    C += (size_t)blockIdx.z * zsC;

    constexpr int MR = BM / 32;              // acc m-fragments per wave
    __shared__ unsigned short As[BM * 32];
    __shared__ unsigned short Ws[128 * 32];
    const int t    = threadIdx.x;
    const int wave = t >> 6, lane = t & 63;
    const int wm   = wave >> 1, wn = wave & 1;
    int bx, by;
    xcd_swizzle(bx, by);
    const int m0 = by * BM, n0 = bx * 128;

    floatx4 acc[MR][4];
#pragma unroll
    for (int i = 0; i < MR; i++)
#pragma unroll
        for (int j = 0; j < 4; j++) acc[i][j] = (floatx4)0.f;

    const int lrow = lane >> 2;
    const int lcol = (lane & 3) * 8;
    const int arows = (BM == 128) ? wave * 32 : wave * 16;
    const unsigned short* Ag = A + (size_t)(m0 + arows + lrow) * lda + lcol;
    const unsigned short* Wg = W + (size_t)(n0 + wave * 32 + lrow) * ldw + lcol;
    unsigned short* Asw = &As[arows * 32];
    unsigned short* Wsw = &Ws[wave * 32 * 32];
    const size_t rowskipA = (size_t)16 * lda;
    const size_t rowskipW = (size_t)16 * ldw;

    const int arow  = lane & 15;
    const int aquad = (lane >> 4) * 8;

    for (int k0 = 0; k0 < K; k0 += 32) {
        load_lds16(Ag + k0, Asw);
        if constexpr (BM == 128)
            load_lds16(Ag + k0 + rowskipA, Asw + 16 * 32);
        load_lds16(Wg + k0,             Wsw);
        load_lds16(Wg + k0 + rowskipW,  Wsw + 16 * 32);
        __syncthreads();

        bf16x8 af[MR], wf[4];
#pragma unroll
        for (int mi = 0; mi < MR; mi++)
            af[mi] = *(const bf16x8*)&As[(wm * (BM / 2) + mi * 16 + arow) * 32 + aquad];
#pragma unroll
        for (int ni = 0; ni < 4; ni++)
            wf[ni] = *(const bf16x8*)&Ws[(wn * 64 + ni * 16 + arow) * 32 + aquad];
#pragma unroll
        for (int mi = 0; mi < MR; mi++)
#pragma unroll
            for (int ni = 0; ni < 4; ni++)
                acc[mi][ni] = __builtin_amdgcn_mfma_f32_16x16x32_bf16(
                    af[mi], wf[ni], acc[mi][ni], 0, 0, 0);
        __syncthreads();
    }

    const int crow = (lane >> 4) * 4, ccol = lane & 15;
#pragma unroll
    for (int mi = 0; mi < MR; mi++) {
#pragma unroll
        for (int ni = 0; ni < 4; ni++) {
            const int gm = m0 + wm * (BM / 2) + mi * 16 + crow;
            const int gn = n0 + wn * 64 + ni * 16 + ccol;
            float bb = 0.f;
            if constexpr (HAS_BIAS) bb = bias[gn];
#pragma unroll
            for (int r = 0; r < 4; r++) {
                float v = acc[mi][ni][r] + bb;
                if constexpr (sizeof(CT) == 2)
                    C[(size_t)(gm + r) * ldc + gn] = (CT)f32_to_bf16(v);
                else
                    C[(size_t)(gm + r) * ldc + gn] = v;
            }
        }
    }
}

// ---------------------------------------------------------------------------
// memsc (MFMA): scores[s,h,l] = ( U[s,h,:].ri[s,l,:] + qcol[s,h,:].bk[h,:] )*SCALE
// U layout is [s][h][d] (s-major) so each block's U[s] is one contiguous 32 KB.
// ---------------------------------------------------------------------------
#define US_STRIDE 1032    // padded ushort row stride (2064 B): rows 4 banks apart

__global__ __launch_bounds__(256) void memsc_kernel(
    const unsigned short* __restrict__ U, const unsigned short* __restrict__ ri,
    const unsigned short* __restrict__ qkv4, const float* __restrict__ bqkv,
    float* __restrict__ scores)
{
    const int s = blockIdx.x;
    const int t = threadIdx.x;
    const int w = t >> 6, lane = t & 63;
    const int lrow = lane & 15;
    const int lkq  = (lane >> 4) * 8;

    __shared__ unsigned short Us[16 * US_STRIDE];
    __shared__ union {
        unsigned short riS[8 * US_STRIDE];
        float red[4][16][16];
    } R;
    __shared__ float qbS[H];

    // stage U[s]: 16 rows x 1024 (contiguous 32 KB in global)
    {
        const unsigned short* src = U + (size_t)s * (H * D);
#pragma unroll
        for (int j = 0; j < 8; j++) {
            const int c = j * 256 + t;          // 0..2047 ushort8 chunks
            const int row = c >> 7, col = (c & 127) * 8;
            *(ushort8*)&Us[row * US_STRIDE + col] =
                *(const ushort8*)(src + row * D + col);
        }
    }
    // stage ri[s]: 8 rows x 1024
    {
        const unsigned short* src = ri + (size_t)s * (LL * D);
#pragma unroll
        for (int j = 0; j < 4; j++) {
            const int c = j * 256 + t;          // 0..1023
            const int row = c >> 7, col = (c & 127) * 8;
            *(ushort8*)&R.riS[row * US_STRIDE + col] =
                *(const ushort8*)(src + row * D + col);
        }
    }
    // qb[h] = qcol[s,h,:] . bk[h,:]
    {
        const int h = t >> 4, sub = t & 15;
        const unsigned short* qc = qkv4 + (size_t)s * 4096 + 3 * D + h * HD + sub * 4;
        const float* bk = bqkv + D + h * HD + sub * 4;
        float acc = 0.f;
#pragma unroll
        for (int j = 0; j < 4; j++) acc += bf2f(qc[j]) * bk[j];
#pragma unroll
        for (int off = 1; off < 16; off <<= 1) acc += __shfl_xor(acc, off);
        if (sub == 0) qbS[h] = acc;
    }
    __syncthreads();

    // each wave: 8 MFMA k-steps over its 256-wide K-quarter
    floatx4 acc = (floatx4)0.f;
    const int kbase = w * 256;
#pragma unroll
    for (int step = 0; step < 8; step++) {
        const int k0 = kbase + step * 32;
        bf16x8 af = *(const bf16x8*)&Us[lrow * US_STRIDE + k0 + lkq];
        bf16x8 bf = {};
        if (lrow < 8) bf = *(const bf16x8*)&R.riS[lrow * US_STRIDE + k0 + lkq];
        acc = __builtin_amdgcn_mfma_f32_16x16x32_bf16(af, bf, acc, 0, 0, 0);
    }
    __syncthreads();               // all riS reads done -> safe to alias as red

    {
        const int crow = (lane >> 4) * 4, ccol = lane & 15;
#pragma unroll
        for (int r = 0; r < 4; r++) R.red[w][crow + r][ccol] = acc[r];
    }
    __syncthreads();

    if (t < H * LL) {
        const int h = t >> 3, l = t & 7;
        float v = R.red[0][h][l] + R.red[1][h][l] + R.red[2][h][l] + R.red[3][h][l];
        scores[((size_t)s * H + h) * LL + l] = (v + qbS[h]) * SCALE;
    }
}

// ---------------------------------------------------------------------------
// Split-K MFMA flash attention, 4-way split, LPT order. Swapped-QK^T (T12):
// S^T = mfma(K,Q) so each lane owns q = lane&15 -> softmax reduce = 2 shfls,
// m/l are per-lane scalars. P->bf16 via v_cvt_pk_bf16_f32 + 2-round lane
// butterfly (xor32 then xor16) assembles PV B-frags fully in registers -- no
// P LDS buffer. PV = mfma(V^T, P) -> O^T; epilogue = 4x float4 stores.
// Double-buffered K/V staging, ONE barrier per tile (proof in R4 notes).
// ---------------------------------------------------------------------------
__global__ __launch_bounds__(256, 4) void attn_split_kernel(
    const unsigned short* __restrict__ qkv4, const unsigned short* __restrict__ VT,
    float* __restrict__ Opart, float2* __restrict__ mlpart)
{
    const int t    = threadIdx.x;
    const int w    = t >> 6, lane = t & 63;
    const int lrow = lane & 15;           // q-row / e-row / key-col of fragments
    const int lk   = (lane >> 4) * 8;
    const int qd   = lane >> 4;           // lane quarter 0..3
    const int hi2  = qd >> 1, lo2 = qd & 1;
    const int lin  = blockIdx.x;
    const int hsp  = lin & 63, g = lin >> 6;
    const int s    = hsp >> 4, h = hsp & 15;
    const int qt   = 31 - g;              // LPT: longest first
    const int q0   = qt * 64;
    const int n    = qt + 1;
    const int lo   = (s * n) >> 2, hi = ((s + 1) * n) >> 2;
    const int part = (h * 32 + qt) * 4 + s;

    __shared__ unsigned short Ks[2][64 * 72];   // [key][e], dbuf
    __shared__ unsigned short Vs[2][64 * 72];   // [e][key], dbuf

    // Q fragments in registers, pre-scaled by 1/8 (exact pow-2 in bf16)
    bf16x8 qreg[2];
#pragma unroll
    for (int kst = 0; kst < 2; kst++) {
        ushort8 qu = *(const ushort8*)(qkv4 + (size_t)(q0 + w * 16 + lrow) * 4096
                                       + h * HD + kst * 32 + lk);
        ushort8 qs;
#pragma unroll
        for (int j = 0; j < 8; j++) qs[j] = f32_to_bf16(bf2f(qu[j]) * SCALE);
        qreg[kst] = __builtin_bit_cast(bf16x8, qs);
    }
    const int qg = q0 + w * 16 + lrow;    // this lane's global q row

    // staging map: thread covers rows {srow, srow+32}, 16B at column scol
    const int srow = t >> 3;            // 0..31
    const int scol = (t & 7) * 8;       // 0..56
    const unsigned short* Kg = qkv4 + D + h * HD;              // + key*4096
    const unsigned short* Vg = VT + (size_t)h * (HD * SEQ);    // + e*SEQ + key

    bf16x8 kr0, kr1, vr0, vr1;
    float m_i = -1e30f, l_i = 0.f;
    floatx4 Oacc[4];
#pragma unroll
    for (int et = 0; et < 4; et++) Oacc[et] = (floatx4)0.f;

    // prologue: load tile 'lo' into regs
    if (lo < hi) {
        const int j0 = lo * 64;
        kr0 = *(const bf16x8*)(Kg + (size_t)(j0 + srow) * 4096 + scol);
        kr1 = *(const bf16x8*)(Kg + (size_t)(j0 + 32 + srow) * 4096 + scol);
        vr0 = *(const bf16x8*)(Vg + (size_t)srow * SEQ + j0 + scol);
        vr1 = *(const bf16x8*)(Vg + (size_t)(srow + 32) * SEQ + j0 + scol);
    }

    int cur = 0;
    for (int jt = lo; jt < hi; jt++) {
        const int j0 = jt * 64;
        // write current tile's regs into buf[cur]
        *(bf16x8*)&Ks[cur][srow * 72 + scol]        = kr0;
        *(bf16x8*)&Ks[cur][(srow + 32) * 72 + scol] = kr1;
        *(bf16x8*)&Vs[cur][srow * 72 + scol]        = vr0;
        *(bf16x8*)&Vs[cur][(srow + 32) * 72 + scol] = vr1;
        // issue next tile's loads (hide under this tile's compute)
        if (jt + 1 < hi) {
            const int j0n = (jt + 1) * 64;
            kr0 = *(const bf16x8*)(Kg + (size_t)(j0n + srow) * 4096 + scol);
            kr1 = *(const bf16x8*)(Kg + (size_t)(j0n + 32 + srow) * 4096 + scol);
            vr0 = *(const bf16x8*)(Vg + (size_t)srow * SEQ + j0n + scol);
            vr1 = *(const bf16x8*)(Vg + (size_t)(srow + 32) * SEQ + j0n + scol);
        }
        __syncthreads();                 // staging of buf[cur] visible

        // S^T = K Q^T : lane holds q = lane&15, keys nt*16 + qd*4 + r
        floatx4 S[4];
#pragma unroll
        for (int nt = 0; nt < 4; nt++) S[nt] = (floatx4)0.f;
        __builtin_amdgcn_s_setprio(1);
#pragma unroll
        for (int kst = 0; kst < 2; kst++) {
#pragma unroll
            for (int nt = 0; nt < 4; nt++) {
                bf16x8 bk = *(const bf16x8*)&Ks[cur][(nt * 16 + lrow) * 72 + kst * 32 + lk];
                S[nt] = __builtin_amdgcn_mfma_f32_16x16x32_bf16(bk, qreg[kst], S[nt], 0, 0, 0);
            }
        }
        __builtin_amdgcn_s_setprio(0);

        const bool diag = (jt == qt);
        if (diag) {
#pragma unroll
            for (int nt = 0; nt < 4; nt++)
#pragma unroll
                for (int r = 0; r < 4; r++)
                    if (j0 + nt * 16 + qd * 4 + r > qg) S[nt][r] = -1e30f;
        }
        float mx = -1e30f;
#pragma unroll
        for (int nt = 0; nt < 4; nt++)
            mx = fmaxf(mx, fmaxf(fmaxf(S[nt][0], S[nt][1]), fmaxf(S[nt][2], S[nt][3])));
        mx = fmaxf(mx, __shfl_xor(mx, 16));
        mx = fmaxf(mx, __shfl_xor(mx, 32));
        const bool keep = !diag && __all(mx <= m_i + 8.f);
        if (!keep) {
            const float newm = fmaxf(m_i, mx);
            const float a = __expf(m_i - newm);
            m_i = newm;
            l_i *= a;
#pragma unroll
            for (int et = 0; et < 4; et++) Oacc[et] *= a;
        }

        // P = exp(S - m); pack to bf16 pairs per tile (up[t][pair])
        float ps = 0.f;
        unsigned int up[4][2];
#pragma unroll
        for (int nt = 0; nt < 4; nt++) {
            float p0 = __expf(S[nt][0] - m_i);
            float p1 = __expf(S[nt][1] - m_i);
            float p2 = __expf(S[nt][2] - m_i);
            float p3 = __expf(S[nt][3] - m_i);
            ps += (p0 + p1) + (p2 + p3);
            up[nt][0] = cvt_pk_bf16(p0, p1);
            up[nt][1] = cvt_pk_bf16(p2, p3);
        }
        ps += __shfl_xor(ps, 16);
        ps += __shfl_xor(ps, 32);
        l_i += ps;

        // --- 2-round butterfly: redistribute P^T into PV B-fragments ---
        // Round 1 (xor32): send tiles with (t&1) != hi2.
        unsigned int s0 = hi2 ? up[0][0] : up[1][0];
        unsigned int s1 = hi2 ? up[0][1] : up[1][1];
        unsigned int s2 = hi2 ? up[2][0] : up[3][0];
        unsigned int s3 = hi2 ? up[2][1] : up[3][1];
        s0 = __shfl_xor(s0, 32); s1 = __shfl_xor(s1, 32);
        s2 = __shfl_xor(s2, 32); s3 = __shfl_xor(s3, 32);
        const unsigned int ownA0 = hi2 ? up[1][0] : up[0][0];   // tile tA = hi2
        const unsigned int ownA1 = hi2 ? up[1][1] : up[0][1];
        const unsigned int ownB0 = hi2 ? up[3][0] : up[2][0];   // tile tB = hi2+2
        const unsigned int ownB1 = hi2 ? up[3][1] : up[2][1];
        // Round 2 (xor16): keep source with s>>1 == lo2 (own iff hi2==lo2).
        const bool keepOwn = (hi2 == lo2);
        unsigned int eA0 = keepOwn ? s0 : ownA0;
        unsigned int eA1 = keepOwn ? s1 : ownA1;
        unsigned int eB0 = keepOwn ? s2 : ownB0;
        unsigned int eB1 = keepOwn ? s3 : ownB1;
        eA0 = __shfl_xor(eA0, 16); eA1 = __shfl_xor(eA1, 16);
        eB0 = __shfl_xor(eB0, 16); eB1 = __shfl_xor(eB1, 16);
        const unsigned int kA0 = keepOwn ? ownA0 : s0;
        const unsigned int kA1 = keepOwn ? ownA1 : s1;
        const unsigned int kB0 = keepOwn ? ownB0 : s2;
        const unsigned int kB1 = keepOwn ? ownB1 : s3;
        // final order: [sLo.p0, sLo.p1, sHi.p0, sHi.p1]; kept has s&1==lo2
        uintx4 fA = { lo2 ? eA0 : kA0, lo2 ? eA1 : kA1,
                      lo2 ? kA0 : eA0, lo2 ? kA1 : eA1 };
        uintx4 fB = { lo2 ? eB0 : kB0, lo2 ? eB1 : kB1,
                      lo2 ? kB0 : eB0, lo2 ? kB1 : eB1 };
        bf16x8 apA = __builtin_bit_cast(bf16x8, fA);   // kst=0 keys
        bf16x8 apB = __builtin_bit_cast(bf16x8, fB);   // kst=1 keys

        // O^T += V^T P : mfma(V^T_frag, P_frag) -> D[m=e][n=q]
        __builtin_amdgcn_s_setprio(1);
#pragma unroll
        for (int et = 0; et < 4; et++) {
            bf16x8 bv = *(const bf16x8*)&Vs[cur][(et * 16 + lrow) * 72 + lk];
            Oacc[et] = __builtin_amdgcn_mfma_f32_16x16x32_bf16(bv, apA, Oacc[et], 0, 0, 0);
        }
#pragma unroll
        for (int et = 0; et < 4; et++) {
            bf16x8 bv = *(const bf16x8*)&Vs[cur][(et * 16 + lrow) * 72 + 32 + lk];
            Oacc[et] = __builtin_amdgcn_mfma_f32_16x16x32_bf16(bv, apB, Oacc[et], 0, 0, 0);
        }
        __builtin_amdgcn_s_setprio(0);
        cur ^= 1;
    }

    // write partials: q = w*16+lrow, e = et*16 + qd*4 + r  -> float4 stores
#pragma unroll
    for (int et = 0; et < 4; et++) {
        float4 o = make_float4(Oacc[et][0], Oacc[et][1], Oacc[et][2], Oacc[et][3]);
        *(float4*)&Opart[((size_t)part * 64 + w * 16 + lrow) * 64 + et * 16 + qd * 4] = o;
    }
    if (qd == 0)
        mlpart[(size_t)part * 64 + w * 16 + lrow] = make_float2(m_i, l_i);
}

// ---------------------------------------------------------------------------
// merge: combine the four key-split partials per (h, qt) AND the 8 memory-key
// scores in one exact softmax; normalize. Writes token context (f32), final
// normalized mem weights mwf, and Pmem[s,h] = sum_l mwf.
// ---------------------------------------------------------------------------
__global__ __launch_bounds__(256) void attn_merge_kernel(
    const float* __restrict__ Opart, const float2* __restrict__ mlpart,
    const float* __restrict__ scores,
    float* __restrict__ tok, float* __restrict__ mwf, float* __restrict__ Pmem)
{
    const int blk = blockIdx.x;            // h*32 + qt
    const int h = blk >> 5, qt = blk & 31;
    const int q0 = qt * 64;
    const int t = threadIdx.x, tx = t & 15, ty = t >> 4;
    const size_t pb = (size_t)blk * 4;
#pragma unroll
    for (int i = 0; i < 4; i++) {
        const int qi = ty * 4 + i, qg = q0 + qi;
        float2 ml[4];
#pragma unroll
        for (int ps = 0; ps < 4; ps++) ml[ps] = mlpart[(pb + ps) * 64 + qi];
        const float* msp = scores + ((size_t)qg * H + h) * LL;
        float ms[LL];
#pragma unroll
        for (int l = 0; l < LL; l++) ms[l] = msp[l];
        float M = ml[0].x;
#pragma unroll
        for (int ps = 1; ps < 4; ps++) M = fmaxf(M, ml[ps].x);
#pragma unroll
        for (int l = 0; l < LL; l++) M = fmaxf(M, ms[l]);
        float f[4], L = 0.f;
#pragma unroll
        for (int ps = 0; ps < 4; ps++) { f[ps] = __expf(ml[ps].x - M); L += ml[ps].y * f[ps]; }
        float pm[LL];
#pragma unroll
        for (int l = 0; l < LL; l++) { pm[l] = __expf(ms[l] - M); L += pm[l]; }
        const float rl = 1.f / L;
        float4 o = make_float4(0.f, 0.f, 0.f, 0.f);
#pragma unroll
        for (int ps = 0; ps < 4; ps++) {
            const float fs = f[ps] * rl;
            float4 op = *(const float4*)&Opart[((pb + ps) * 64 + qi) * 64 + tx * 4];
            o.x += op.x * fs; o.y += op.y * fs; o.z += op.z * fs; o.w += op.w * fs;
        }
        *(float4*)&tok[(size_t)qg * D + h * HD + tx * 4] = o;
        if (tx == 0) {
            float* mw = mwf + ((size_t)qg * H + h) * LL;
            float psum = 0.f;
#pragma unroll
            for (int l = 0; l < LL; l++) { float v = pm[l] * rl; mw[l] = v; psum += v; }
            Pmem[(size_t)qg * H + h] = psum;
        }
    }
}

// ---------------------------------------------------------------------------
// rbar[h,s,:] = sum_l mwf[s,h,l] * ri[s*8+l,:]   (bf16 out). grid = 2048 (s).
// ---------------------------------------------------------------------------
__global__ __launch_bounds__(256) void rbar_kernel(
    const float* __restrict__ mwf, const unsigned short* __restrict__ ri,
    unsigned short* __restrict__ rbar)
{
    const int s = blockIdx.x, t = threadIdx.x;
    __shared__ unsigned short riS[LL * D];
    __shared__ float wS[H * LL];
    {
        const unsigned short* src = ri + (size_t)s * (LL * D);
#pragma unroll
        for (int j = 0; j < 4; j++) {
            const int off = (j * 256 + t) * 8;
            *(ushort8*)&riS[off] = *(const ushort8*)(src + off);
        }
    }
    if (t < H * LL) wS[t] = mwf[(size_t)s * (H * LL) + t];
    __syncthreads();
    const int c4 = t * 4;
#pragma unroll
    for (int hh = 0; hh < H; hh++) {
        float v0 = 0.f, v1 = 0.f, v2 = 0.f, v3 = 0.f;
#pragma unroll
        for (int l = 0; l < LL; l++) {
            const float wv = wS[hh * LL + l];
            ushort4 rr = *(const ushort4*)&riS[l * D + c4];
            v0 += wv * bf2f(rr.x); v1 += wv * bf2f(rr.y);
            v2 += wv * bf2f(rr.z); v3 += wv * bf2f(rr.w);
        }
        ushort4 o;
        o.x = f32_to_bf16(v0); o.y = f32_to_bf16(v1);
        o.z = f32_to_bf16(v2); o.w = f32_to_bf16(v3);
        *(ushort4*)(rbar + ((size_t)hh * SEQ + s) * D + c4) = o;
    }
}

// ---------------------------------------------------------------------------
// ctx GEMM: ctx[s, h*64+e] = bf16( rbar[h,s,:] . Wv[h*64+e,:]
//                                  + bv[h*64+e]*Pmem[s,h] + tok[s,h*64+e] )
// 128(M)x64(N) tile, BK=32, 4 waves (wave = m-subtile). grid = (16 mt, 16 h).
// ---------------------------------------------------------------------------
__global__ __launch_bounds__(256) void gemm_ctx_kernel(
    const unsigned short* __restrict__ rbar, const unsigned short* __restrict__ W4,
    const float* __restrict__ bqkv, const float* __restrict__ Pmem,
    const float* __restrict__ tok, unsigned short* __restrict__ ctx)
{
    const int mt = blockIdx.x;      // 0..15
    const int h  = blockIdx.y;      // 0..15
    const unsigned short* A  = rbar + (size_t)h * SEQ * D + (size_t)mt * 128 * D;
    const unsigned short* Wv = W4 + (size_t)(2 * D + h * HD) * D;   // 64 rows x 1024
    const float* bv = bqkv + 2 * D + h * HD;

    __shared__ unsigned short As[128 * 32];
    __shared__ unsigned short Ws[64 * 32];
    const int t    = threadIdx.x;
    const int wave = t >> 6, lane = t & 63;

    floatx4 acc[2][4];
#pragma unroll
    for (int i = 0; i < 2; i++)
#pragma unroll
        for (int j = 0; j < 4; j++) acc[i][j] = (floatx4)0.f;

    const int lrow = lane >> 2;
    const int lcol = (lane & 3) * 8;
    const unsigned short* Ag = A  + (size_t)(wave * 32 + lrow) * D + lcol;
    const unsigned short* Wg = Wv + (size_t)(wave * 32 + lrow) * D + lcol;  // waves 0,1 only
    unsigned short* Asw = &As[wave * 32 * 32];
    unsigned short* Wsw = &Ws[wave * 32 * 32];
    const size_t rowskip = (size_t)16 * D;

    const int arow  = lane & 15;
    const int aquad = (lane >> 4) * 8;

    for (int k0 = 0; k0 < D; k0 += 32) {
        load_lds16(Ag + k0,           Asw);
        load_lds16(Ag + k0 + rowskip, Asw + 16 * 32);
        if (wave < 2) {
            load_lds16(Wg + k0,           Wsw);
            load_lds16(Wg + k0 + rowskip, Wsw + 16 * 32);
        }
        __syncthreads();

        bf16x8 af[2], wf[4];
#pragma unroll
        for (int mi = 0; mi < 2; mi++)
            af[mi] = *(const bf16x8*)&As[(wave * 32 + mi * 16 + arow) * 32 + aquad];
#pragma unroll
        for (int ni = 0; ni < 4; ni++)
            wf[ni] = *(const bf16x8*)&Ws[(ni * 16 + arow) * 32 + aquad];
#pragma unroll
        for (int mi = 0; mi < 2; mi++)
#pragma unroll
            for (int ni = 0; ni < 4; ni++)
                acc[mi][ni] = __builtin_amdgcn_mfma_f32_16x16x32_bf16(
                    af[mi], wf[ni], acc[mi][ni], 0, 0, 0);
        __syncthreads();
    }

    const int crow = (lane >> 4) * 4, ccol = lane & 15;
#pragma unroll
    for (int mi = 0; mi < 2; mi++) {
#pragma unroll
        for (int ni = 0; ni < 4; ni++) {
            const int e  = ni * 16 + ccol;
            const float bb = bv[e];
#pragma unroll
            for (int r = 0; r < 4; r++) {
                const int grow = mt * 128 + wave * 32 + mi * 16 + crow + r;
                float v = acc[mi][ni][r] + bb * Pmem[(size_t)grow * H + h]
                          + tok[(size_t)grow * D + h * HD + e];
                ctx[(size_t)grow * D + h * HD + e] = f32_to_bf16(v);
            }
        }
    }
}

// ---------------------------------------------------------------------------
extern "C" void kernel_launch(void* const* d_in, const int* in_sizes, int n_in,
                              void* d_out, int out_size, void* d_ws, size_t ws_size,
                              hipStream_t stream)
{
    const float* x    = (const float*)d_in[0];
    const float* pv   = (const float*)d_in[1];
    const float* Wqkv = (const float*)d_in[2];
    const float* bqkv = (const float*)d_in[3];
    const float* Wcol = (const float*)d_in[4];
    const float* bcol = (const float*)d_in[5];
    const float* Wout = (const float*)d_in[6];
    const float* bout = (const float*)d_in[7];
    float* out = (float*)d_out;

    char* p = (char*)d_ws;
    unsigned short* x_bf    = (unsigned short*)p; p += (size_t)2048 * 1024 * 2;
    unsigned short* W4_bf   = (unsigned short*)p; p += (size_t)4096 * 1024 * 2;   // Wqkv | Wcol
    unsigned short* Wout_bf = (unsigned short*)p; p += (size_t)1024 * 1024 * 2;
    float*          b4      = (float*)p;          p += (size_t)4096 * 4;
    unsigned short* ri_bf   = (unsigned short*)p; p += (size_t)16384 * 1024 * 2;
    unsigned short* qkv4_bf = (unsigned short*)p; p += (size_t)2048 * 4096 * 2;   // Q|K|V|Qcol
    unsigned short* WkT_bf  = (unsigned short*)p; p += (size_t)16 * 1024 * 64 * 2;
    unsigned short* VT_bf   = (unsigned short*)p; p += (size_t)16 * 64 * 2048 * 2; // V transposed per head
    float*          scores  = (float*)p;          p += (size_t)2048 * 16 * 8 * 4;
    float*          mwf     = (float*)p;          p += (size_t)2048 * 16 * 8 * 4;
    float*          Pmem    = (float*)p;          p += (size_t)2048 * 16 * 4;
    float*          tok     = (float*)p;          p += (size_t)2048 * 1024 * 4;
    unsigned short* ctx_bf  = (unsigned short*)p; p += (size_t)2048 * 1024 * 2;
    float*          Opart   = (float*)p;          p += (size_t)2048 * 64 * 64 * 4;
    float2*         mlpart  = (float2*)p;         p += (size_t)2048 * 64 * 8;
    // U and rbar have disjoint lifetimes (U dead after memsc) -> share buffer
    unsigned short* Urb     = (unsigned short*)p; p += (size_t)16 * 2048 * 1024 * 2;
    // ~182 MB total

    // LN + all bf16 casts + bias concat
    prep_kernel<<<PREP_GRID, 256, 0, stream>>>(pv, x, Wqkv, Wcol, Wout, bqkv, bcol,
                                               ri_bf, x_bf, W4_bf, Wout_bf, b4);
    // per-head transposed Wk for the U GEMM
    wkt_kernel<<<256, 256, 0, stream>>>(Wqkv, WkT_bf);
    // qkv4 = x @ [Wqkv|Wcol]^T + [bqkv|bcol]   (fused, N=4096; 64-row tiles
    // -> 1024 blocks = 4/CU, was 512 = 2/CU grid-starved)
    gemm_bf16_kernel<unsigned short, true, 64><<<dim3(32, 32, 1), 256, 0, stream>>>(
        x_bf, W4_bf, b4, qkv4_bf, 1024, 4096, 1024, 1024, 4096, 0, 0, 0);
    // global V transpose: VT[h][e][key]
    vtr_kernel<<<128, 256, 0, stream>>>(qkv4_bf, VT_bf);
    // U = Qcol @ Wk, written s-major: U[s][h][d] via ldc=H*D, zsC=D
    gemm_bf16_kernel<unsigned short, false, 128><<<dim3(8, 16, 16), 256, 0, stream>>>(
        qkv4_bf + 3 * D, WkT_bf, nullptr, Urb, 64, 1024, 4096, 64, H * D,
        (size_t)HD, (size_t)D * HD, (size_t)D);
    // mem_scores = (U . ri + qcol.bk) * scale   (MFMA, one block per s)
    memsc_kernel<<<2048, 256, 0, stream>>>(Urb, ri_bf, qkv4_bf, bqkv, scores);
    // attention split (swapped-QK, dbuf, 1 barrier/tile, 4-way, LPT) + merge
    attn_split_kernel<<<2048, 256, 0, stream>>>(qkv4_bf, VT_bf, Opart, mlpart);
    attn_merge_kernel<<<512, 256, 0, stream>>>(Opart, mlpart, scores, tok, mwf, Pmem);
    // rbar = sum_l mwf * ri   (reuses U's buffer)
    rbar_kernel<<<2048, 256, 0, stream>>>(mwf, ri_bf, Urb);
    // ctx = tok + Wv[h] @ rbar[h] + bv*Pmem   (replaces the rv GEMM + fold)
    gemm_ctx_kernel<<<dim3(16, 16), 256, 0, stream>>>(Urb, W4_bf, bqkv, Pmem, tok, ctx_bf);
    // out = ctx @ Wout^T + bout   (64-row tiles -> 256 blocks, was 128)
    gemm_bf16_kernel<float, true, 64><<<dim3(8, 32, 1), 256, 0, stream>>>(
        ctx_bf, Wout_bf, bout, out, 1024, 1024, 1024, 1024, 1024, 0, 0, 0);
}

// Round 9
// 296.693 us; speedup vs baseline: 1.2744x; 1.0028x over previous
//
#include <hip/hip_runtime.h>
#include <math.h>

#define D   1024
#define H   16
#define HD  64
#define SEQ 2048
#define LL  8
#define SCALE 0.125f

typedef __attribute__((ext_vector_type(8))) __bf16 bf16x8;
typedef __attribute__((ext_vector_type(4))) float floatx4;
typedef __attribute__((ext_vector_type(8))) unsigned short ushort8;
typedef __attribute__((ext_vector_type(4))) unsigned int uintx4;

__device__ inline unsigned short f32_to_bf16(float f) {
    unsigned int u = __builtin_bit_cast(unsigned int, f);
    u += 0x7FFF + ((u >> 16) & 1);   // round-to-nearest-even
    return (unsigned short)(u >> 16);
}
__device__ inline float bf2f(unsigned short u) {
    unsigned int x = (unsigned int)u << 16;
    return __builtin_bit_cast(float, x);
}
__device__ inline unsigned int cvt_pk_bf16(float lo, float hi) {
    unsigned int r;
    asm("v_cvt_pk_bf16_f32 %0, %1, %2" : "=v"(r) : "v"(lo), "v"(hi));
    return r;
}
__device__ inline void load_lds16(const void* g, void* l) {
    __builtin_amdgcn_global_load_lds(
        (__attribute__((address_space(1))) void*)g,
        (__attribute__((address_space(3))) void*)l, 16, 0, 0);
}

// XCD-aware swizzle: contiguous grid chunk per XCD -> A-panel L2 reuse.
__device__ inline void xcd_swizzle(int& bx, int& by) {
    const int gx   = gridDim.x;
    const int lin  = blockIdx.y * gx + blockIdx.x;
    const int nblk = gx * gridDim.y;
    const int virt = (lin & 7) * (nblk >> 3) + (lin >> 3);
    bx = virt % gx;
    by = virt / gx;
}

// ---------------------------------------------------------------------------
// prep: LN(reproject(pv)) -> ri_bf. Wave handles a ROW-QUAD (l, s0..s0+3):
// per h-plane one 4KB fully-contiguous load (64 lanes x float4 = 4 rows x 64e,
// s_local = lane>>4, e = (lane&15)*4). 16 independent loads/wave -> deep MLP;
// LN reduce = 4-shfl intra-quarter butterfly; data stays in 64 VGPRs.
//       | f32->bf16 of x, Wqkv|Wcol (->W4), Wout (4 quads/thread)
//       | bias concat b4 = [bqkv, bcol]
// ---------------------------------------------------------------------------
#define NQ_X    524288
#define NQ_WQKV 786432
#define NQ_WC   262144
#define NQ_WO   262144
#define LN_BLK  1024          // 4 waves/block x 1 row-quad/wave = 4096 quads
#define CVT_BLK 1792          // 1835008 quads / (256 thr * 4 quads)
#define PREP_GRID (LN_BLK + CVT_BLK + 4)

__global__ __launch_bounds__(256) void prep_kernel(
    const float* __restrict__ pv, const float* __restrict__ x,
    const float* __restrict__ Wqkv, const float* __restrict__ Wcol,
    const float* __restrict__ Wout, const float* __restrict__ bqkv,
    const float* __restrict__ bcol,
    unsigned short* __restrict__ ri, unsigned short* __restrict__ xb,
    unsigned short* __restrict__ W4b, unsigned short* __restrict__ Woutb,
    float* __restrict__ b4)
{
    const int b = blockIdx.x;
    const int t = threadIdx.x;
    if (b < LN_BLK) {
        const int w = t >> 6, lane = t & 63;
        const int qi = b * 4 + w;            // 0..4095 row-quads
        const int l  = qi & 7;
        const int s0 = (qi >> 3) * 4;
        const int sl = lane >> 4;            // s_local 0..3
        const int e  = (lane & 15) * 4;
        const float* base = pv + (size_t)l * (H * SEQ * HD) + (size_t)s0 * HD;
        float4 v[16];
#pragma unroll
        for (int h = 0; h < 16; h++)
            v[h] = *(const float4*)(base + (size_t)h * (SEQ * HD) + lane * 4);
        float sum = 0.f, sq = 0.f;
#pragma unroll
        for (int h = 0; h < 16; h++) {
            sum += (v[h].x + v[h].y) + (v[h].z + v[h].w);
            sq  += (v[h].x * v[h].x + v[h].y * v[h].y)
                 + (v[h].z * v[h].z + v[h].w * v[h].w);
        }
#pragma unroll
        for (int off = 1; off < 16; off <<= 1) {
            sum += __shfl_xor(sum, off);
            sq  += __shfl_xor(sq, off);
        }
        const float mean = sum * (1.f / 1024.f);
        const float var  = sq * (1.f / 1024.f) - mean * mean;
        const float rstd = rsqrtf(var + 1e-5f);
        const int r = (s0 + sl) * 8 + l;
#pragma unroll
        for (int h = 0; h < 16; h++) {
            ushort4 o;
            o.x = f32_to_bf16((v[h].x - mean) * rstd);
            o.y = f32_to_bf16((v[h].y - mean) * rstd);
            o.z = f32_to_bf16((v[h].z - mean) * rstd);
            o.w = f32_to_bf16((v[h].w - mean) * rstd);
            *(ushort4*)(ri + (size_t)r * D + h * 64 + e) = o;
        }
    } else if (b < LN_BLK + CVT_BLK) {
        const int base = (b - LN_BLK) * 1024;
#pragma unroll
        for (int j = 0; j < 4; j++) {
            const int i = base + j * 256 + t;
            const float* src; unsigned short* dst; int soff, doff;
            if (i < NQ_X)                        { src = x;    dst = xb;    soff = i;                          doff = soff; }
            else if (i < NQ_X + NQ_WQKV)         { src = Wqkv; dst = W4b;   soff = i - NQ_X;                   doff = soff; }
            else if (i < NQ_X + NQ_WQKV + NQ_WC) { src = Wcol; dst = W4b;   soff = i - NQ_X - NQ_WQKV;         doff = i - NQ_X; }
            else                                 { src = Wout; dst = Woutb; soff = i - NQ_X - NQ_WQKV - NQ_WC; doff = soff; }
            float4 v = ((const float4*)src)[soff];
            ushort4 o;
            o.x = f32_to_bf16(v.x); o.y = f32_to_bf16(v.y);
            o.z = f32_to_bf16(v.z); o.w = f32_to_bf16(v.w);
            ((ushort4*)dst)[doff] = o;
        }
    } else {
        // bias concat: 1024 float4 quads, first 768 from bqkv, rest from bcol
        const int q = (b - LN_BLK - CVT_BLK) * 256 + t;
        float4 v = (q < 768) ? ((const float4*)bqkv)[q] : ((const float4*)bcol)[q - 768];
        ((float4*)b4)[q] = v;
    }
}

// ---------------------------------------------------------------------------
// wkt: WkT[h][c][e] = Wqkv[1024 + h*64 + e][c]  (bf16). Grid 256 = 16h x 16ct.
// ---------------------------------------------------------------------------
__global__ __launch_bounds__(256) void wkt_kernel(
    const float* __restrict__ Wqkv, unsigned short* __restrict__ WkT)
{
    const int h = blockIdx.x >> 4, ct = blockIdx.x & 15;
    const int c0 = ct * 64;
    const int t = threadIdx.x;
    __shared__ float tile[64][68];
    {
        const int e  = t >> 2;            // 0..63
        const int c4 = (t & 3) * 16;      // 0,16,32,48
        const float* src = Wqkv + (size_t)(D + h * HD + e) * D + c0 + c4;
#pragma unroll
        for (int j = 0; j < 4; j++) {
            float4 v = ((const float4*)src)[j];
            *(float4*)&tile[e][c4 + j * 4] = v;
        }
    }
    __syncthreads();
    {
        const int c  = t >> 2;            // local col 0..63
        const int e0 = (t & 3) * 16;      // 0,16,32,48
        ushort8 o0, o1;
#pragma unroll
        for (int j = 0; j < 8; j++) o0[j] = f32_to_bf16(tile[e0 + j][c]);
#pragma unroll
        for (int j = 0; j < 8; j++) o1[j] = f32_to_bf16(tile[e0 + 8 + j][c]);
        unsigned short* dst = WkT + (size_t)h * (D * HD) + (size_t)(c0 + c) * HD + e0;
        *(ushort8*)dst       = o0;
        *(ushort8*)(dst + 8) = o1;
    }
}

// ---------------------------------------------------------------------------
// vtr: VT[h][e][key] = V[key][h*64+e]  (global transpose of the V quarter of
// qkv4). Grid 128 = 16h x 8 key-chunks of 256. LDS-tiled, coalesced both ways.
// ---------------------------------------------------------------------------
__global__ __launch_bounds__(256) void vtr_kernel(
    const unsigned short* __restrict__ qkv4, unsigned short* __restrict__ VT)
{
    const int h = blockIdx.x & 15, kt = blockIdx.x >> 4;
    const int t = threadIdx.x;
    __shared__ unsigned short Vt[64][264];
    const int pr = t & 31, eg = t >> 5;   // key-pair 0..31, e-octet 0..7
#pragma unroll
    for (int sub = 0; sub < 4; sub++) {
        const int j0 = kt * 256 + sub * 64;
        const unsigned short* v0 = qkv4 + (size_t)(j0 + 2 * pr) * 4096 + 2 * D + h * HD + eg * 8;
        ushort8 va = *(const ushort8*)v0;
        ushort8 vb = *(const ushort8*)(v0 + 4096);
#pragma unroll
        for (int j = 0; j < 8; j++) {
            unsigned int pk = (unsigned int)va[j] | ((unsigned int)vb[j] << 16);
            *(unsigned int*)&Vt[eg * 8 + j][sub * 64 + 2 * pr] = pk;
        }
    }
    __syncthreads();
#pragma unroll
    for (int it = 0; it < 8; it++) {
        const int idx = it * 256 + t;
        const int e = idx >> 5, ch = idx & 31;
        ushort8 v = *(const ushort8*)&Vt[e][ch * 8];
        *(ushort8*)(VT + (size_t)h * (HD * SEQ) + (size_t)e * SEQ + kt * 256 + ch * 8) = v;
    }
}

// ---------------------------------------------------------------------------
// bf16 MFMA GEMM: C[M,N] = A[M,K] @ W[N,K]^T (+ bias[N]). CT = float or ushort.
// BMx128 tile (BM = 128 or 64), BK=32, 4 waves. XCD-swizzled.
// ---------------------------------------------------------------------------
template <typename CT, bool HAS_BIAS, int BM>
__global__ __launch_bounds__(256) void gemm_bf16_kernel(
    const unsigned short* __restrict__ A, const unsigned short* __restrict__ W,
    const float* __restrict__ bias, CT* __restrict__ C,
    int K, int N, int lda, int ldw, int ldc,
    size_t zsA, size_t zsW, size_t zsC)
{
    A += (size_t)blockIdx.z * zsA;
    W += (size_t)blockIdx.z * zsW;
    C += (size_t)blockIdx.z * zsC;

    constexpr int MR = BM / 32;              // acc m-fragments per wave
    __shared__ unsigned short As[BM * 32];
    __shared__ unsigned short Ws[128 * 32];
    const int t    = threadIdx.x;
    const int wave = t >> 6, lane = t & 63;
    const int wm   = wave >> 1, wn = wave & 1;
    int bx, by;
    xcd_swizzle(bx, by);
    const int m0 = by * BM, n0 = bx * 128;

    floatx4 acc[MR][4];
#pragma unroll
    for (int i = 0; i < MR; i++)
#pragma unroll
        for (int j = 0; j < 4; j++) acc[i][j] = (floatx4)0.f;

    const int lrow = lane >> 2;
    const int lcol = (lane & 3) * 8;
    const int arows = (BM == 128) ? wave * 32 : wave * 16;
    const unsigned short* Ag = A + (size_t)(m0 + arows + lrow) * lda + lcol;
    const unsigned short* Wg = W + (size_t)(n0 + wave * 32 + lrow) * ldw + lcol;
    unsigned short* Asw = &As[arows * 32];
    unsigned short* Wsw = &Ws[wave * 32 * 32];
    const size_t rowskipA = (size_t)16 * lda;
    const size_t rowskipW = (size_t)16 * ldw;

    const int arow  = lane & 15;
    const int aquad = (lane >> 4) * 8;

    for (int k0 = 0; k0 < K; k0 += 32) {
        load_lds16(Ag + k0, Asw);
        if constexpr (BM == 128)
            load_lds16(Ag + k0 + rowskipA, Asw + 16 * 32);
        load_lds16(Wg + k0,             Wsw);
        load_lds16(Wg + k0 + rowskipW,  Wsw + 16 * 32);
        __syncthreads();

        bf16x8 af[MR], wf[4];
#pragma unroll
        for (int mi = 0; mi < MR; mi++)
            af[mi] = *(const bf16x8*)&As[(wm * (BM / 2) + mi * 16 + arow) * 32 + aquad];
#pragma unroll
        for (int ni = 0; ni < 4; ni++)
            wf[ni] = *(const bf16x8*)&Ws[(wn * 64 + ni * 16 + arow) * 32 + aquad];
#pragma unroll
        for (int mi = 0; mi < MR; mi++)
#pragma unroll
            for (int ni = 0; ni < 4; ni++)
                acc[mi][ni] = __builtin_amdgcn_mfma_f32_16x16x32_bf16(
                    af[mi], wf[ni], acc[mi][ni], 0, 0, 0);
        __syncthreads();
    }

    const int crow = (lane >> 4) * 4, ccol = lane & 15;
#pragma unroll
    for (int mi = 0; mi < MR; mi++) {
#pragma unroll
        for (int ni = 0; ni < 4; ni++) {
            const int gm = m0 + wm * (BM / 2) + mi * 16 + crow;
            const int gn = n0 + wn * 64 + ni * 16 + ccol;
            float bb = 0.f;
            if constexpr (HAS_BIAS) bb = bias[gn];
#pragma unroll
            for (int r = 0; r < 4; r++) {
                float v = acc[mi][ni][r] + bb;
                if constexpr (sizeof(CT) == 2)
                    C[(size_t)(gm + r) * ldc + gn] = (CT)f32_to_bf16(v);
                else
                    C[(size_t)(gm + r) * ldc + gn] = v;
            }
        }
    }
}

// ---------------------------------------------------------------------------
// memsc (MFMA): scores[s,h,l] = ( U[s,h,:].ri[s,l,:] + qcol[s,h,:].bk[h,:] )*SCALE
// U layout is [s][h][d] (s-major) so each block's U[s] is one contiguous 32 KB.
// ---------------------------------------------------------------------------
#define US_STRIDE 1032    // padded ushort row stride (2064 B): rows 4 banks apart

__global__ __launch_bounds__(256) void memsc_kernel(
    const unsigned short* __restrict__ U, const unsigned short* __restrict__ ri,
    const unsigned short* __restrict__ qkv4, const float* __restrict__ bqkv,
    float* __restrict__ scores)
{
    const int s = blockIdx.x;
    const int t = threadIdx.x;
    const int w = t >> 6, lane = t & 63;
    const int lrow = lane & 15;
    const int lkq  = (lane >> 4) * 8;

    __shared__ unsigned short Us[16 * US_STRIDE];
    __shared__ union {
        unsigned short riS[8 * US_STRIDE];
        float red[4][16][16];
    } R;
    __shared__ float qbS[H];

    // stage U[s]: 16 rows x 1024 (contiguous 32 KB in global)
    {
        const unsigned short* src = U + (size_t)s * (H * D);
#pragma unroll
        for (int j = 0; j < 8; j++) {
            const int c = j * 256 + t;          // 0..2047 ushort8 chunks
            const int row = c >> 7, col = (c & 127) * 8;
            *(ushort8*)&Us[row * US_STRIDE + col] =
                *(const ushort8*)(src + row * D + col);
        }
    }
    // stage ri[s]: 8 rows x 1024
    {
        const unsigned short* src = ri + (size_t)s * (LL * D);
#pragma unroll
        for (int j = 0; j < 4; j++) {
            const int c = j * 256 + t;          // 0..1023
            const int row = c >> 7, col = (c & 127) * 8;
            *(ushort8*)&R.riS[row * US_STRIDE + col] =
                *(const ushort8*)(src + row * D + col);
        }
    }
    // qb[h] = qcol[s,h,:] . bk[h,:]
    {
        const int h = t >> 4, sub = t & 15;
        const unsigned short* qc = qkv4 + (size_t)s * 4096 + 3 * D + h * HD + sub * 4;
        const float* bk = bqkv + D + h * HD + sub * 4;
        float acc = 0.f;
#pragma unroll
        for (int j = 0; j < 4; j++) acc += bf2f(qc[j]) * bk[j];
#pragma unroll
        for (int off = 1; off < 16; off <<= 1) acc += __shfl_xor(acc, off);
        if (sub == 0) qbS[h] = acc;
    }
    __syncthreads();

    // each wave: 8 MFMA k-steps over its 256-wide K-quarter
    floatx4 acc = (floatx4)0.f;
    const int kbase = w * 256;
#pragma unroll
    for (int step = 0; step < 8; step++) {
        const int k0 = kbase + step * 32;
        bf16x8 af = *(const bf16x8*)&Us[lrow * US_STRIDE + k0 + lkq];
        bf16x8 bf = {};
        if (lrow < 8) bf = *(const bf16x8*)&R.riS[lrow * US_STRIDE + k0 + lkq];
        acc = __builtin_amdgcn_mfma_f32_16x16x32_bf16(af, bf, acc, 0, 0, 0);
    }
    __syncthreads();               // all riS reads done -> safe to alias as red

    {
        const int crow = (lane >> 4) * 4, ccol = lane & 15;
#pragma unroll
        for (int r = 0; r < 4; r++) R.red[w][crow + r][ccol] = acc[r];
    }
    __syncthreads();

    if (t < H * LL) {
        const int h = t >> 3, l = t & 7;
        float v = R.red[0][h][l] + R.red[1][h][l] + R.red[2][h][l] + R.red[3][h][l];
        scores[((size_t)s * H + h) * LL + l] = (v + qbS[h]) * SCALE;
    }
}

// ---------------------------------------------------------------------------
// Split-K MFMA flash attention, 4-way split, LPT order. Swapped-QK^T (T12):
// S^T = mfma(K,Q) so each lane owns q = lane&15 -> softmax reduce = 2 shfls,
// m/l are per-lane scalars. P->bf16 via v_cvt_pk_bf16_f32 + 2-round lane
// butterfly (xor32 then xor16) assembles PV B-frags fully in registers -- no
// P LDS buffer. PV = mfma(V^T, P) -> O^T; epilogue = 4x float4 stores.
// Double-buffered K/V staging, ONE barrier per tile (proof in R4 notes).
// ---------------------------------------------------------------------------
__global__ __launch_bounds__(256, 4) void attn_split_kernel(
    const unsigned short* __restrict__ qkv4, const unsigned short* __restrict__ VT,
    float* __restrict__ Opart, float2* __restrict__ mlpart)
{
    const int t    = threadIdx.x;
    const int w    = t >> 6, lane = t & 63;
    const int lrow = lane & 15;           // q-row / e-row / key-col of fragments
    const int lk   = (lane >> 4) * 8;
    const int qd   = lane >> 4;           // lane quarter 0..3
    const int hi2  = qd >> 1, lo2 = qd & 1;
    const int lin  = blockIdx.x;
    const int hsp  = lin & 63, g = lin >> 6;
    const int s    = hsp >> 4, h = hsp & 15;
    const int qt   = 31 - g;              // LPT: longest first
    const int q0   = qt * 64;
    const int n    = qt + 1;
    const int lo   = (s * n) >> 2, hi = ((s + 1) * n) >> 2;
    const int part = (h * 32 + qt) * 4 + s;

    __shared__ unsigned short Ks[2][64 * 72];   // [key][e], dbuf
    __shared__ unsigned short Vs[2][64 * 72];   // [e][key], dbuf

    // Q fragments in registers, pre-scaled by 1/8 (exact pow-2 in bf16)
    bf16x8 qreg[2];
#pragma unroll
    for (int kst = 0; kst < 2; kst++) {
        ushort8 qu = *(const ushort8*)(qkv4 + (size_t)(q0 + w * 16 + lrow) * 4096
                                       + h * HD + kst * 32 + lk);
        ushort8 qs;
#pragma unroll
        for (int j = 0; j < 8; j++) qs[j] = f32_to_bf16(bf2f(qu[j]) * SCALE);
        qreg[kst] = __builtin_bit_cast(bf16x8, qs);
    }
    const int qg = q0 + w * 16 + lrow;    // this lane's global q row

    // staging map: thread covers rows {srow, srow+32}, 16B at column scol
    const int srow = t >> 3;            // 0..31
    const int scol = (t & 7) * 8;       // 0..56
    const unsigned short* Kg = qkv4 + D + h * HD;              // + key*4096
    const unsigned short* Vg = VT + (size_t)h * (HD * SEQ);    // + e*SEQ + key

    bf16x8 kr0, kr1, vr0, vr1;
    float m_i = -1e30f, l_i = 0.f;
    floatx4 Oacc[4];
#pragma unroll
    for (int et = 0; et < 4; et++) Oacc[et] = (floatx4)0.f;

    // prologue: load tile 'lo' into regs
    if (lo < hi) {
        const int j0 = lo * 64;
        kr0 = *(const bf16x8*)(Kg + (size_t)(j0 + srow) * 4096 + scol);
        kr1 = *(const bf16x8*)(Kg + (size_t)(j0 + 32 + srow) * 4096 + scol);
        vr0 = *(const bf16x8*)(Vg + (size_t)srow * SEQ + j0 + scol);
        vr1 = *(const bf16x8*)(Vg + (size_t)(srow + 32) * SEQ + j0 + scol);
    }

    int cur = 0;
    for (int jt = lo; jt < hi; jt++) {
        const int j0 = jt * 64;
        // write current tile's regs into buf[cur]
        *(bf16x8*)&Ks[cur][srow * 72 + scol]        = kr0;
        *(bf16x8*)&Ks[cur][(srow + 32) * 72 + scol] = kr1;
        *(bf16x8*)&Vs[cur][srow * 72 + scol]        = vr0;
        *(bf16x8*)&Vs[cur][(srow + 32) * 72 + scol] = vr1;
        // issue next tile's loads (hide under this tile's compute)
        if (jt + 1 < hi) {
            const int j0n = (jt + 1) * 64;
            kr0 = *(const bf16x8*)(Kg + (size_t)(j0n + srow) * 4096 + scol);
            kr1 = *(const bf16x8*)(Kg + (size_t)(j0n + 32 + srow) * 4096 + scol);
            vr0 = *(const bf16x8*)(Vg + (size_t)srow * SEQ + j0n + scol);
            vr1 = *(const bf16x8*)(Vg + (size_t)(srow + 32) * SEQ + j0n + scol);
        }
        __syncthreads();                 // staging of buf[cur] visible

        // S^T = K Q^T : lane holds q = lane&15, keys nt*16 + qd*4 + r
        floatx4 S[4];
#pragma unroll
        for (int nt = 0; nt < 4; nt++) S[nt] = (floatx4)0.f;
        __builtin_amdgcn_s_setprio(1);
#pragma unroll
        for (int kst = 0; kst < 2; kst++) {
#pragma unroll
            for (int nt = 0; nt < 4; nt++) {
                bf16x8 bk = *(const bf16x8*)&Ks[cur][(nt * 16 + lrow) * 72 + kst * 32 + lk];
                S[nt] = __builtin_amdgcn_mfma_f32_16x16x32_bf16(bk, qreg[kst], S[nt], 0, 0, 0);
            }
        }
        __builtin_amdgcn_s_setprio(0);

        const bool diag = (jt == qt);
        if (diag) {
#pragma unroll
            for (int nt = 0; nt < 4; nt++)
#pragma unroll
                for (int r = 0; r < 4; r++)
                    if (j0 + nt * 16 + qd * 4 + r > qg) S[nt][r] = -1e30f;
        }
        float mx = -1e30f;
#pragma unroll
        for (int nt = 0; nt < 4; nt++)
            mx = fmaxf(mx, fmaxf(fmaxf(S[nt][0], S[nt][1]), fmaxf(S[nt][2], S[nt][3])));
        mx = fmaxf(mx, __shfl_xor(mx, 16));
        mx = fmaxf(mx, __shfl_xor(mx, 32));
        const bool keep = !diag && __all(mx <= m_i + 8.f);
        if (!keep) {
            const float newm = fmaxf(m_i, mx);
            const float a = __expf(m_i - newm);
            m_i = newm;
            l_i *= a;
#pragma unroll
            for (int et = 0; et < 4; et++) Oacc[et] *= a;
        }

        // P = exp(S - m); pack to bf16 pairs per tile (up[t][pair])
        float ps = 0.f;
        unsigned int up[4][2];
#pragma unroll
        for (int nt = 0; nt < 4; nt++) {
            float p0 = __expf(S[nt][0] - m_i);
            float p1 = __expf(S[nt][1] - m_i);
            float p2 = __expf(S[nt][2] - m_i);
            float p3 = __expf(S[nt][3] - m_i);
            ps += (p0 + p1) + (p2 + p3);
            up[nt][0] = cvt_pk_bf16(p0, p1);
            up[nt][1] = cvt_pk_bf16(p2, p3);
        }
        ps += __shfl_xor(ps, 16);
        ps += __shfl_xor(ps, 32);
        l_i += ps;

        // --- 2-round butterfly: redistribute P^T into PV B-fragments ---
        // Round 1 (xor32): send tiles with (t&1) != hi2.
        unsigned int s0 = hi2 ? up[0][0] : up[1][0];
        unsigned int s1 = hi2 ? up[0][1] : up[1][1];
        unsigned int s2 = hi2 ? up[2][0] : up[3][0];
        unsigned int s3 = hi2 ? up[2][1] : up[3][1];
        s0 = __shfl_xor(s0, 32); s1 = __shfl_xor(s1, 32);
        s2 = __shfl_xor(s2, 32); s3 = __shfl_xor(s3, 32);
        const unsigned int ownA0 = hi2 ? up[1][0] : up[0][0];   // tile tA = hi2
        const unsigned int ownA1 = hi2 ? up[1][1] : up[0][1];
        const unsigned int ownB0 = hi2 ? up[3][0] : up[2][0];   // tile tB = hi2+2
        const unsigned int ownB1 = hi2 ? up[3][1] : up[2][1];
        // Round 2 (xor16): keep source with s>>1 == lo2 (own iff hi2==lo2).
        const bool keepOwn = (hi2 == lo2);
        unsigned int eA0 = keepOwn ? s0 : ownA0;
        unsigned int eA1 = keepOwn ? s1 : ownA1;
        unsigned int eB0 = keepOwn ? s2 : ownB0;
        unsigned int eB1 = keepOwn ? s3 : ownB1;
        eA0 = __shfl_xor(eA0, 16); eA1 = __shfl_xor(eA1, 16);
        eB0 = __shfl_xor(eB0, 16); eB1 = __shfl_xor(eB1, 16);
        const unsigned int kA0 = keepOwn ? ownA0 : s0;
        const unsigned int kA1 = keepOwn ? ownA1 : s1;
        const unsigned int kB0 = keepOwn ? ownB0 : s2;
        const unsigned int kB1 = keepOwn ? ownB1 : s3;
        // final order: [sLo.p0, sLo.p1, sHi.p0, sHi.p1]; kept has s&1==lo2
        uintx4 fA = { lo2 ? eA0 : kA0, lo2 ? eA1 : kA1,
                      lo2 ? kA0 : eA0, lo2 ? kA1 : eA1 };
        uintx4 fB = { lo2 ? eB0 : kB0, lo2 ? eB1 : kB1,
                      lo2 ? kB0 : eB0, lo2 ? kB1 : eB1 };
        bf16x8 apA = __builtin_bit_cast(bf16x8, fA);   // kst=0 keys
        bf16x8 apB = __builtin_bit_cast(bf16x8, fB);   // kst=1 keys

        // O^T += V^T P : mfma(V^T_frag, P_frag) -> D[m=e][n=q]
        __builtin_amdgcn_s_setprio(1);
#pragma unroll
        for (int et = 0; et < 4; et++) {
            bf16x8 bv = *(const bf16x8*)&Vs[cur][(et * 16 + lrow) * 72 + lk];
            Oacc[et] = __builtin_amdgcn_mfma_f32_16x16x32_bf16(bv, apA, Oacc[et], 0, 0, 0);
        }
#pragma unroll
        for (int et = 0; et < 4; et++) {
            bf16x8 bv = *(const bf16x8*)&Vs[cur][(et * 16 + lrow) * 72 + 32 + lk];
            Oacc[et] = __builtin_amdgcn_mfma_f32_16x16x32_bf16(bv, apB, Oacc[et], 0, 0, 0);
        }
        __builtin_amdgcn_s_setprio(0);
        cur ^= 1;
    }

    // write partials: q = w*16+lrow, e = et*16 + qd*4 + r  -> float4 stores
#pragma unroll
    for (int et = 0; et < 4; et++) {
        float4 o = make_float4(Oacc[et][0], Oacc[et][1], Oacc[et][2], Oacc[et][3]);
        *(float4*)&Opart[((size_t)part * 64 + w * 16 + lrow) * 64 + et * 16 + qd * 4] = o;
    }
    if (qd == 0)
        mlpart[(size_t)part * 64 + w * 16 + lrow] = make_float2(m_i, l_i);
}

// ---------------------------------------------------------------------------
// merge: combine the four key-split partials per (h, qt) AND the 8 memory-key
// scores in one exact softmax; normalize. Writes token context (f32), final
// normalized mem weights mwf, and Pmem[s,h] = sum_l mwf.
// ---------------------------------------------------------------------------
__global__ __launch_bounds__(256) void attn_merge_kernel(
    const float* __restrict__ Opart, const float2* __restrict__ mlpart,
    const float* __restrict__ scores,
    float* __restrict__ tok, float* __restrict__ mwf, float* __restrict__ Pmem)
{
    const int blk = blockIdx.x;            // h*32 + qt
    const int h = blk >> 5, qt = blk & 31;
    const int q0 = qt * 64;
    const int t = threadIdx.x, tx = t & 15, ty = t >> 4;
    const size_t pb = (size_t)blk * 4;
#pragma unroll
    for (int i = 0; i < 4; i++) {
        const int qi = ty * 4 + i, qg = q0 + qi;
        float2 ml[4];
#pragma unroll
        for (int ps = 0; ps < 4; ps++) ml[ps] = mlpart[(pb + ps) * 64 + qi];
        const float* msp = scores + ((size_t)qg * H + h) * LL;
        float ms[LL];
#pragma unroll
        for (int l = 0; l < LL; l++) ms[l] = msp[l];
        float M = ml[0].x;
#pragma unroll
        for (int ps = 1; ps < 4; ps++) M = fmaxf(M, ml[ps].x);
#pragma unroll
        for (int l = 0; l < LL; l++) M = fmaxf(M, ms[l]);
        float f[4], L = 0.f;
#pragma unroll
        for (int ps = 0; ps < 4; ps++) { f[ps] = __expf(ml[ps].x - M); L += ml[ps].y * f[ps]; }
        float pm[LL];
#pragma unroll
        for (int l = 0; l < LL; l++) { pm[l] = __expf(ms[l] - M); L += pm[l]; }
        const float rl = 1.f / L;
        float4 o = make_float4(0.f, 0.f, 0.f, 0.f);
#pragma unroll
        for (int ps = 0; ps < 4; ps++) {
            const float fs = f[ps] * rl;
            float4 op = *(const float4*)&Opart[((pb + ps) * 64 + qi) * 64 + tx * 4];
            o.x += op.x * fs; o.y += op.y * fs; o.z += op.z * fs; o.w += op.w * fs;
        }
        *(float4*)&tok[(size_t)qg * D + h * HD + tx * 4] = o;
        if (tx == 0) {
            float* mw = mwf + ((size_t)qg * H + h) * LL;
            float psum = 0.f;
#pragma unroll
            for (int l = 0; l < LL; l++) { float v = pm[l] * rl; mw[l] = v; psum += v; }
            Pmem[(size_t)qg * H + h] = psum;
        }
    }
}

// ---------------------------------------------------------------------------
// rbar[h,s,:] = sum_l mwf[s,h,l] * ri[s*8+l,:]   (bf16 out). grid = 2048 (s).
// ---------------------------------------------------------------------------
__global__ __launch_bounds__(256) void rbar_kernel(
    const float* __restrict__ mwf, const unsigned short* __restrict__ ri,
    unsigned short* __restrict__ rbar)
{
    const int s = blockIdx.x, t = threadIdx.x;
    __shared__ unsigned short riS[LL * D];
    __shared__ float wS[H * LL];
    {
        const unsigned short* src = ri + (size_t)s * (LL * D);
#pragma unroll
        for (int j = 0; j < 4; j++) {
            const int off = (j * 256 + t) * 8;
            *(ushort8*)&riS[off] = *(const ushort8*)(src + off);
        }
    }
    if (t < H * LL) wS[t] = mwf[(size_t)s * (H * LL) + t];
    __syncthreads();
    const int c4 = t * 4;
#pragma unroll
    for (int hh = 0; hh < H; hh++) {
        float v0 = 0.f, v1 = 0.f, v2 = 0.f, v3 = 0.f;
#pragma unroll
        for (int l = 0; l < LL; l++) {
            const float wv = wS[hh * LL + l];
            ushort4 rr = *(const ushort4*)&riS[l * D + c4];
            v0 += wv * bf2f(rr.x); v1 += wv * bf2f(rr.y);
            v2 += wv * bf2f(rr.z); v3 += wv * bf2f(rr.w);
        }
        ushort4 o;
        o.x = f32_to_bf16(v0); o.y = f32_to_bf16(v1);
        o.z = f32_to_bf16(v2); o.w = f32_to_bf16(v3);
        *(ushort4*)(rbar + ((size_t)hh * SEQ + s) * D + c4) = o;
    }
}

// ---------------------------------------------------------------------------
// ctx GEMM: ctx[s, h*64+e] = bf16( rbar[h,s,:] . Wv[h*64+e,:]
//                                  + bv[h*64+e]*Pmem[s,h] + tok[s,h*64+e] )
// 128(M)x64(N) tile, BK=32, 4 waves (wave = m-subtile). grid = (16 mt, 16 h).
// ---------------------------------------------------------------------------
__global__ __launch_bounds__(256) void gemm_ctx_kernel(
    const unsigned short* __restrict__ rbar, const unsigned short* __restrict__ W4,
    const float* __restrict__ bqkv, const float* __restrict__ Pmem,
    const float* __restrict__ tok, unsigned short* __restrict__ ctx)
{
    const int mt = blockIdx.x;      // 0..15
    const int h  = blockIdx.y;      // 0..15
    const unsigned short* A  = rbar + (size_t)h * SEQ * D + (size_t)mt * 128 * D;
    const unsigned short* Wv = W4 + (size_t)(2 * D + h * HD) * D;   // 64 rows x 1024
    const float* bv = bqkv + 2 * D + h * HD;

    __shared__ unsigned short As[128 * 32];
    __shared__ unsigned short Ws[64 * 32];
    const int t    = threadIdx.x;
    const int wave = t >> 6, lane = t & 63;

    floatx4 acc[2][4];
#pragma unroll
    for (int i = 0; i < 2; i++)
#pragma unroll
        for (int j = 0; j < 4; j++) acc[i][j] = (floatx4)0.f;

    const int lrow = lane >> 2;
    const int lcol = (lane & 3) * 8;
    const unsigned short* Ag = A  + (size_t)(wave * 32 + lrow) * D + lcol;
    const unsigned short* Wg = Wv + (size_t)(wave * 32 + lrow) * D + lcol;  // waves 0,1 only
    unsigned short* Asw = &As[wave * 32 * 32];
    unsigned short* Wsw = &Ws[wave * 32 * 32];
    const size_t rowskip = (size_t)16 * D;

    const int arow  = lane & 15;
    const int aquad = (lane >> 4) * 8;

    for (int k0 = 0; k0 < D; k0 += 32) {
        load_lds16(Ag + k0,           Asw);
        load_lds16(Ag + k0 + rowskip, Asw + 16 * 32);
        if (wave < 2) {
            load_lds16(Wg + k0,           Wsw);
            load_lds16(Wg + k0 + rowskip, Wsw + 16 * 32);
        }
        __syncthreads();

        bf16x8 af[2], wf[4];
#pragma unroll
        for (int mi = 0; mi < 2; mi++)
            af[mi] = *(const bf16x8*)&As[(wave * 32 + mi * 16 + arow) * 32 + aquad];
#pragma unroll
        for (int ni = 0; ni < 4; ni++)
            wf[ni] = *(const bf16x8*)&Ws[(ni * 16 + arow) * 32 + aquad];
#pragma unroll
        for (int mi = 0; mi < 2; mi++)
#pragma unroll
            for (int ni = 0; ni < 4; ni++)
                acc[mi][ni] = __builtin_amdgcn_mfma_f32_16x16x32_bf16(
                    af[mi], wf[ni], acc[mi][ni], 0, 0, 0);
        __syncthreads();
    }

    const int crow = (lane >> 4) * 4, ccol = lane & 15;
#pragma unroll
    for (int mi = 0; mi < 2; mi++) {
#pragma unroll
        for (int ni = 0; ni < 4; ni++) {
            const int e  = ni * 16 + ccol;
            const float bb = bv[e];
#pragma unroll
            for (int r = 0; r < 4; r++) {
                const int grow = mt * 128 + wave * 32 + mi * 16 + crow + r;
                float v = acc[mi][ni][r] + bb * Pmem[(size_t)grow * H + h]
                          + tok[(size_t)grow * D + h * HD + e];
                ctx[(size_t)grow * D + h * HD + e] = f32_to_bf16(v);
            }
        }
    }
}

// ---------------------------------------------------------------------------
extern "C" void kernel_launch(void* const* d_in, const int* in_sizes, int n_in,
                              void* d_out, int out_size, void* d_ws, size_t ws_size,
                              hipStream_t stream)
{
    const float* x    = (const float*)d_in[0];
    const float* pv   = (const float*)d_in[1];
    const float* Wqkv = (const float*)d_in[2];
    const float* bqkv = (const float*)d_in[3];
    const float* Wcol = (const float*)d_in[4];
    const float* bcol = (const float*)d_in[5];
    const float* Wout = (const float*)d_in[6];
    const float* bout = (const float*)d_in[7];
    float* out = (float*)d_out;

    char* p = (char*)d_ws;
    unsigned short* x_bf    = (unsigned short*)p; p += (size_t)2048 * 1024 * 2;
    unsigned short* W4_bf   = (unsigned short*)p; p += (size_t)4096 * 1024 * 2;   // Wqkv | Wcol
    unsigned short* Wout_bf = (unsigned short*)p; p += (size_t)1024 * 1024 * 2;
    float*          b4      = (float*)p;          p += (size_t)4096 * 4;
    unsigned short* ri_bf   = (unsigned short*)p; p += (size_t)16384 * 1024 * 2;
    unsigned short* qkv4_bf = (unsigned short*)p; p += (size_t)2048 * 4096 * 2;   // Q|K|V|Qcol
    unsigned short* WkT_bf  = (unsigned short*)p; p += (size_t)16 * 1024 * 64 * 2;
    unsigned short* VT_bf   = (unsigned short*)p; p += (size_t)16 * 64 * 2048 * 2; // V transposed per head
    float*          scores  = (float*)p;          p += (size_t)2048 * 16 * 8 * 4;
    float*          mwf     = (float*)p;          p += (size_t)2048 * 16 * 8 * 4;
    float*          Pmem    = (float*)p;          p += (size_t)2048 * 16 * 4;
    float*          tok     = (float*)p;          p += (size_t)2048 * 1024 * 4;
    unsigned short* ctx_bf  = (unsigned short*)p; p += (size_t)2048 * 1024 * 2;
    float*          Opart   = (float*)p;          p += (size_t)2048 * 64 * 64 * 4;
    float2*         mlpart  = (float2*)p;         p += (size_t)2048 * 64 * 8;
    // U and rbar have disjoint lifetimes (U dead after memsc) -> share buffer
    unsigned short* Urb     = (unsigned short*)p; p += (size_t)16 * 2048 * 1024 * 2;
    // ~182 MB total

    // LN + all bf16 casts + bias concat
    prep_kernel<<<PREP_GRID, 256, 0, stream>>>(pv, x, Wqkv, Wcol, Wout, bqkv, bcol,
                                               ri_bf, x_bf, W4_bf, Wout_bf, b4);
    // per-head transposed Wk for the U GEMM
    wkt_kernel<<<256, 256, 0, stream>>>(Wqkv, WkT_bf);
    // qkv4 = x @ [Wqkv|Wcol]^T + [bqkv|bcol]   (fused, N=4096; 64-row tiles)
    gemm_bf16_kernel<unsigned short, true, 64><<<dim3(32, 32, 1), 256, 0, stream>>>(
        x_bf, W4_bf, b4, qkv4_bf, 1024, 4096, 1024, 1024, 4096, 0, 0, 0);
    // global V transpose: VT[h][e][key]
    vtr_kernel<<<128, 256, 0, stream>>>(qkv4_bf, VT_bf);
    // U = Qcol @ Wk, written s-major: U[s][h][d] via ldc=H*D, zsC=D
    gemm_bf16_kernel<unsigned short, false, 128><<<dim3(8, 16, 16), 256, 0, stream>>>(
        qkv4_bf + 3 * D, WkT_bf, nullptr, Urb, 64, 1024, 4096, 64, H * D,
        (size_t)HD, (size_t)D * HD, (size_t)D);
    // mem_scores = (U . ri + qcol.bk) * scale   (MFMA, one block per s)
    memsc_kernel<<<2048, 256, 0, stream>>>(Urb, ri_bf, qkv4_bf, bqkv, scores);
    // attention split (swapped-QK, dbuf, 1 barrier/tile, 4-way, LPT) + merge
    attn_split_kernel<<<2048, 256, 0, stream>>>(qkv4_bf, VT_bf, Opart, mlpart);
    attn_merge_kernel<<<512, 256, 0, stream>>>(Opart, mlpart, scores, tok, mwf, Pmem);
    // rbar = sum_l mwf * ri   (reuses U's buffer)
    rbar_kernel<<<2048, 256, 0, stream>>>(mwf, ri_bf, Urb);
    // ctx = tok + Wv[h] @ rbar[h] + bv*Pmem   (replaces the rv GEMM + fold)
    gemm_ctx_kernel<<<dim3(16, 16), 256, 0, stream>>>(Urb, W4_bf, bqkv, Pmem, tok, ctx_bf);
    // out = ctx @ Wout^T + bout   (64-row tiles -> 256 blocks)
    gemm_bf16_kernel<float, true, 64><<<dim3(8, 32, 1), 256, 0, stream>>>(
        ctx_bf, Wout_bf, bout, out, 1024, 1024, 1024, 1024, 1024, 0, 0, 0);
}